// Round 5
// baseline (5902.727 us; speedup 1.0000x reference)
//
#include <hip/hip_runtime.h>
#include <hip/hip_bf16.h>
#include <math.h>

// Model dims
constexpr int kD = 1024;
constexpr int kH = 16;
constexpr int kV = 32000;
constexpr int kT = 1024;
constexpr int kG = 16;
constexpr int kFF = 4096;
constexpr int kL = 24;
constexpr int kNTRI = 2016;
#define EPSF 1e-6f
#define L2E 1.44269504088896f

typedef __bf16 bf16x8 __attribute__((ext_vector_type(8)));
typedef __bf16 bf16x4 __attribute__((ext_vector_type(4)));
typedef float f32x4 __attribute__((ext_vector_type(4)));

// ---------------------------------------------------------------------------
// Cayley transform: R = (I - A/2)^-1 (I + A/2). One block per (layer,group),
// 256 threads: row r = tid&63, col-chunk q = tid>>6 (16 cols each).
// Gauss-Jordan; per pivot k the row-k slice is snapshotted into registers, and
// normalization is folded into the elimination via beta (row k: beta=1-1/piv).
// ---------------------------------------------------------------------------
__global__ __launch_bounds__(256) void cayley_kernel(const float* __restrict__ skew,
                                                     float* __restrict__ R) {
  int lg = blockIdx.x;
  int tid = threadIdx.x;
  int r = tid & 63, q = tid >> 6;
  __shared__ float Ms[64][65];
  __shared__ float Bs[64][65];
  const float* su = skew + (size_t)lg * kNTRI;
#pragma unroll
  for (int cc = 0; cc < 16; ++cc) {
    int c = q * 16 + cc;
    float a = 0.f;
    if (r < c) a = su[r * (127 - r) / 2 + (c - r - 1)];
    else if (r > c) a = -su[c * (127 - c) / 2 + (r - c - 1)];
    Ms[r][c] = (r == c ? 1.f : 0.f) - 0.5f * a;
    Bs[r][c] = (r == c ? 1.f : 0.f) + 0.5f * a;
  }
  __syncthreads();
  for (int k = 0; k < 64; ++k) {
    float ip = 1.f / Ms[k][k];
    float f = Ms[r][k];
    float beta = (r == k) ? (1.f - ip) : (f * ip);
    float mk[16], bk[16];
#pragma unroll
    for (int cc = 0; cc < 16; ++cc) {
      mk[cc] = Ms[k][q * 16 + cc];
      bk[cc] = Bs[k][q * 16 + cc];
    }
    __syncthreads();
#pragma unroll
    for (int cc = 0; cc < 16; ++cc) {
      int c = q * 16 + cc;
      Ms[r][c] -= beta * mk[cc];
      Bs[r][c] -= beta * bk[cc];
    }
    __syncthreads();
  }
  float* Ro = R + ((size_t)lg * 64 + r) * 64;
#pragma unroll
  for (int cc = 0; cc < 16; ++cc) Ro[q * 16 + cc] = Bs[r][q * 16 + cc];
}

// ---------------------------------------------------------------------------
// Embedding gather, float4-vectorized.
// ---------------------------------------------------------------------------
__global__ __launch_bounds__(256) void embed_kernel(const int* __restrict__ tok,
                                                    const float* __restrict__ ew,
                                                    float* __restrict__ x) {
  int i = blockIdx.x * 256 + threadIdx.x;
  int t = i >> 8;
  int d4 = i & 255;
  int v = tok[t];
  reinterpret_cast<float4*>(x)[i] =
      reinterpret_cast<const float4*>(ew + (size_t)v * kD)[d4];
}

// ---------------------------------------------------------------------------
// Weight convert+transpose: W f32 [K][N] -> WT bf16 [N][K]. 64x64 tiles.
// ---------------------------------------------------------------------------
__global__ __launch_bounds__(256) void convt_kernel(const float* __restrict__ W,
                                                    __bf16* __restrict__ WT,
                                                    int K, int N) {
  __shared__ float tile[64][65];
  int t = threadIdx.x;
  int n0 = blockIdx.x * 64, k0 = blockIdx.y * 64;
#pragma unroll
  for (int r = 0; r < 4; ++r) {
    int kr = r * 16 + (t >> 4);
    int nc = (t & 15) * 4;
    float4 v = *reinterpret_cast<const float4*>(&W[(size_t)(k0 + kr) * N + n0 + nc]);
    tile[kr][nc + 0] = v.x;
    tile[kr][nc + 1] = v.y;
    tile[kr][nc + 2] = v.z;
    tile[kr][nc + 3] = v.w;
  }
  __syncthreads();
#pragma unroll
  for (int r = 0; r < 2; ++r) {
    int idx = r * 256 + t;
    int nrow = idx >> 3, kc = (idx & 7) * 8;
    bf16x8 v;
#pragma unroll
    for (int j = 0; j < 8; ++j) v[j] = (__bf16)tile[kc + j][nrow];
    *reinterpret_cast<bf16x8*>(&WT[(size_t)(n0 + nrow) * K + k0 + kc]) = v;
  }
}

// ---------------------------------------------------------------------------
// RMSNorm -> bf16 out. AFFINE: out = rms(x)*w*gamma + beta
// ---------------------------------------------------------------------------
template <bool AFFINE>
__global__ __launch_bounds__(256) void rms_kernel(const float* __restrict__ x,
                                                  const float* __restrict__ w,
                                                  const float* __restrict__ gamma,
                                                  const float* __restrict__ beta,
                                                  __bf16* __restrict__ out) {
  int t = blockIdx.x, tid = threadIdx.x;
  __shared__ float red[256];
  float4 xv = reinterpret_cast<const float4*>(x + (size_t)t * kD)[tid];
  red[tid] = xv.x * xv.x + xv.y * xv.y + xv.z * xv.z + xv.w * xv.w;
  __syncthreads();
  for (int off = 128; off > 0; off >>= 1) {
    if (tid < off) red[tid] += red[tid + off];
    __syncthreads();
  }
  float rms = rsqrtf(red[0] / (float)kD + EPSF);
  float4 wv = reinterpret_cast<const float4*>(w)[tid];
  float o0 = xv.x * rms * wv.x;
  float o1 = xv.y * rms * wv.y;
  float o2 = xv.z * rms * wv.z;
  float o3 = xv.w * rms * wv.w;
  if (AFFINE) {
    float4 gv = reinterpret_cast<const float4*>(gamma)[tid];
    float4 bv = reinterpret_cast<const float4*>(beta)[tid];
    o0 = o0 * gv.x + bv.x;
    o1 = o1 * gv.y + bv.y;
    o2 = o2 * gv.z + bv.z;
    o3 = o3 * gv.w + bv.w;
  }
  bf16x4 ov;
  ov[0] = (__bf16)o0; ov[1] = (__bf16)o1; ov[2] = (__bf16)o2; ov[3] = (__bf16)o3;
  *reinterpret_cast<bf16x4*>(out + (size_t)t * kD + tid * 4) = ov;
}

// ---------------------------------------------------------------------------
// 64x64-tile bf16 MFMA GEMM: C[M,N] = A[M,K] @ B[N,K]^T (+ epilogue).
// BK=64, 256 threads = 4 waves (2x2), each wave 32x32 via 2x2 frags of
// v_mfma_f32_16x16x32_bf16. High block count for the small per-layer shapes.
// EPI: 0 = f32 store, 1 = f32 acc+res, 2 = gelu(tanh)->bf16, 3 = bf16 store.
// ---------------------------------------------------------------------------
template <int EPI>
__global__ __launch_bounds__(256) void gemm64_kernel(
    const __bf16* __restrict__ A, const __bf16* __restrict__ B,
    const float* res, void* __restrict__ Cv, int M, int N, int K) {
  constexpr int LDT = 72;
  __shared__ __bf16 As[64 * LDT];
  __shared__ __bf16 Bs[64 * LDT];
  int tid = threadIdx.x;
  int bm = blockIdx.y * 64, bn = blockIdx.x * 64;
  int w = tid >> 6, lane = tid & 63;
  int wr = (w >> 1) * 32, wc = (w & 1) * 32;
  int lrow = lane & 15, lkb = (lane >> 4) * 8;
  f32x4 acc[2][2] = {};

  for (int k0 = 0; k0 < K; k0 += 64) {
#pragma unroll
    for (int rep = 0; rep < 2; ++rep) {
      int cid = rep * 256 + tid;
      int row = cid >> 3, kc = (cid & 7) << 3;
      *reinterpret_cast<bf16x8*>(&As[row * LDT + kc]) =
          *reinterpret_cast<const bf16x8*>(&A[(size_t)(bm + row) * K + k0 + kc]);
      *reinterpret_cast<bf16x8*>(&Bs[row * LDT + kc]) =
          *reinterpret_cast<const bf16x8*>(&B[(size_t)(bn + row) * K + k0 + kc]);
    }
    __syncthreads();
#pragma unroll
    for (int ks = 0; ks < 2; ++ks) {
      bf16x8 af[2], bg[2];
#pragma unroll
      for (int i = 0; i < 2; ++i)
        af[i] = *reinterpret_cast<const bf16x8*>(
            &As[(wr + i * 16 + lrow) * LDT + ks * 32 + lkb]);
#pragma unroll
      for (int j = 0; j < 2; ++j)
        bg[j] = *reinterpret_cast<const bf16x8*>(
            &Bs[(wc + j * 16 + lrow) * LDT + ks * 32 + lkb]);
#pragma unroll
      for (int i = 0; i < 2; ++i)
#pragma unroll
        for (int j = 0; j < 2; ++j)
          acc[i][j] = __builtin_amdgcn_mfma_f32_16x16x32_bf16(af[i], bg[j],
                                                              acc[i][j], 0, 0, 0);
    }
    __syncthreads();
  }

  int crow0 = bm + wr + (lane >> 4) * 4;
  int ccol0 = bn + wc + lrow;
#pragma unroll
  for (int i = 0; i < 2; ++i) {
#pragma unroll
    for (int j = 0; j < 2; ++j) {
#pragma unroll
      for (int r = 0; r < 4; ++r) {
        int row = crow0 + i * 16 + r;
        int col = ccol0 + j * 16;
        size_t idx = (size_t)row * N + col;
        float v = acc[i][j][r];
        if (EPI == 1) v += res[idx];
        if (EPI == 2) {
          float u = v;
          v = 0.5f * u * (1.f + tanhf(0.7978845608028654f * (u + 0.044715f * u * u * u)));
        }
        if (EPI == 2 || EPI == 3) ((__bf16*)Cv)[idx] = (__bf16)v;
        else ((float*)Cv)[idx] = v;
      }
    }
  }
}

// ---------------------------------------------------------------------------
// 128x128-tile bf16 MFMA GEMM (lm_head): C = A @ B^T, B f32 [N][K] converted
// during staging. 4 waves (2x2), each 64x64 via 4x4 frags.
// ---------------------------------------------------------------------------
__global__ __launch_bounds__(256) void gemm_head_kernel(
    const __bf16* __restrict__ A, const float* __restrict__ B32,
    float* __restrict__ C, int M, int N, int K) {
  constexpr int LDT = 72;
  __shared__ __bf16 As[128 * LDT];
  __shared__ __bf16 Bs[128 * LDT];
  int tid = threadIdx.x;
  int bm = blockIdx.y * 128, bn = blockIdx.x * 128;
  int w = tid >> 6, lane = tid & 63;
  int wr = (w >> 1) * 64, wc = (w & 1) * 64;
  int lrow = lane & 15, lkb = (lane >> 4) * 8;
  f32x4 acc[4][4] = {};

  for (int k0 = 0; k0 < K; k0 += 64) {
#pragma unroll
    for (int rrep = 0; rrep < 4; ++rrep) {
      int cid = rrep * 256 + tid;
      int row = cid >> 3, kc = (cid & 7) << 3;
      *reinterpret_cast<bf16x8*>(&As[row * LDT + kc]) =
          *reinterpret_cast<const bf16x8*>(&A[(size_t)(bm + row) * K + k0 + kc]);
      const float* src = &B32[(size_t)(bn + row) * K + k0 + kc];
      float4 f0 = *reinterpret_cast<const float4*>(src);
      float4 f1 = *reinterpret_cast<const float4*>(src + 4);
      bf16x8 v;
      v[0] = (__bf16)f0.x; v[1] = (__bf16)f0.y;
      v[2] = (__bf16)f0.z; v[3] = (__bf16)f0.w;
      v[4] = (__bf16)f1.x; v[5] = (__bf16)f1.y;
      v[6] = (__bf16)f1.z; v[7] = (__bf16)f1.w;
      *reinterpret_cast<bf16x8*>(&Bs[row * LDT + kc]) = v;
    }
    __syncthreads();
#pragma unroll
    for (int ks = 0; ks < 2; ++ks) {
      bf16x8 af[4], bg[4];
#pragma unroll
      for (int i = 0; i < 4; ++i)
        af[i] = *reinterpret_cast<const bf16x8*>(
            &As[(wr + i * 16 + lrow) * LDT + ks * 32 + lkb]);
#pragma unroll
      for (int j = 0; j < 4; ++j)
        bg[j] = *reinterpret_cast<const bf16x8*>(
            &Bs[(wc + j * 16 + lrow) * LDT + ks * 32 + lkb]);
#pragma unroll
      for (int i = 0; i < 4; ++i)
#pragma unroll
        for (int j = 0; j < 4; ++j)
          acc[i][j] = __builtin_amdgcn_mfma_f32_16x16x32_bf16(af[i], bg[j],
                                                              acc[i][j], 0, 0, 0);
    }
    __syncthreads();
  }

  int crow0 = bm + wr + (lane >> 4) * 4;
  int ccol0 = bn + wc + lrow;
#pragma unroll
  for (int i = 0; i < 4; ++i)
#pragma unroll
    for (int j = 0; j < 4; ++j)
#pragma unroll
      for (int r = 0; r < 4; ++r)
        C[(size_t)(crow0 + i * 16 + r) * N + ccol0 + j * 16] = acc[i][j][r];
}

// ---------------------------------------------------------------------------
// Flash attention (causal), bf16 MFMA. qkv bf16 [T][3D]; out bf16 [T][D].
// ---------------------------------------------------------------------------
__global__ __launch_bounds__(256) void fattn_kernel(const __bf16* __restrict__ qkv,
                                                    __bf16* __restrict__ out) {
  __shared__ __bf16 Ks[64 * 64];
  __shared__ __bf16 Vt[64 * 64];
  __shared__ __bf16 Ps[4 * 16 * 64];
  int tid = threadIdx.x;
  int bq = blockIdx.x * 64;
  int h = blockIdx.y;
  int w = tid >> 6, lane = tid & 63;
  int g = lane >> 4, lr = lane & 15;

  bf16x8 qf[2];
  const __bf16* qbase = qkv + (size_t)(bq + w * 16 + lr) * (3 * kD) + h * 64;
#pragma unroll
  for (int ks = 0; ks < 2; ++ks) {
    bf16x8 v = *reinterpret_cast<const bf16x8*>(qbase + ks * 32 + g * 8);
#pragma unroll
    for (int j = 0; j < 8; ++j) qf[ks][j] = (__bf16)((float)v[j] * 0.125f);
  }

  f32x4 acc[4] = {};
  float m[4], lsum[4];
#pragma unroll
  for (int r = 0; r < 4; ++r) { m[r] = -1e30f; lsum[r] = 0.f; }

  int srow = tid >> 2, sseg = tid & 3;
  int vk = tid & 63, vd0 = (tid >> 6) * 16;
  char* KsB = (char*)Ks;
  char* VtB = (char*)Vt;
  char* PwB = (char*)(Ps + w * (16 * 64));

  int ntiles = bq / 64 + 1;
  for (int kt = 0; kt < ntiles; ++kt) {
    {
      const __bf16* src = qkv + (size_t)(kt * 64 + srow) * (3 * kD) + kD + h * 64 + sseg * 16;
      bf16x8 a = *reinterpret_cast<const bf16x8*>(src);
      bf16x8 b = *reinterpret_cast<const bf16x8*>(src + 8);
      int bc = sseg * 32, sw = (srow & 7) << 4;
      *reinterpret_cast<bf16x8*>(KsB + srow * 128 + (bc ^ sw)) = a;
      *reinterpret_cast<bf16x8*>(KsB + srow * 128 + ((bc + 16) ^ sw)) = b;
      const __bf16* vsrc = qkv + (size_t)(kt * 64 + vk) * (3 * kD) + 2 * kD + h * 64 + vd0;
      bf16x8 v0 = *reinterpret_cast<const bf16x8*>(vsrc);
      bf16x8 v1 = *reinterpret_cast<const bf16x8*>(vsrc + 8);
#pragma unroll
      for (int i = 0; i < 8; ++i) {
        int d = vd0 + i;
        *((__bf16*)(VtB + d * 128 + ((vk * 2) ^ ((d & 7) << 4)))) = v0[i];
        d = vd0 + 8 + i;
        *((__bf16*)(VtB + d * 128 + ((vk * 2) ^ ((d & 7) << 4)))) = v1[i];
      }
    }
    __syncthreads();

    bool diag = (kt == ntiles - 1);
    int jmax = diag ? w : 3;

    f32x4 s[4];
#pragma unroll
    for (int j = 0; j < 4; ++j) {
      if (j <= jmax) {
        int krow = j * 16 + lr, sw = (krow & 7) << 4;
        bf16x8 kb0 = *reinterpret_cast<const bf16x8*>(KsB + krow * 128 + ((g * 16) ^ sw));
        bf16x8 kb1 = *reinterpret_cast<const bf16x8*>(KsB + krow * 128 + ((64 + g * 16) ^ sw));
        f32x4 z = {};
        z = __builtin_amdgcn_mfma_f32_16x16x32_bf16(qf[0], kb0, z, 0, 0, 0);
        s[j] = __builtin_amdgcn_mfma_f32_16x16x32_bf16(qf[1], kb1, z, 0, 0, 0);
      } else {
        s[j] = f32x4{-1e30f, -1e30f, -1e30f, -1e30f};
      }
    }
    if (diag) {
#pragma unroll
      for (int r = 0; r < 4; ++r)
        if (lr > g * 4 + r) s[w][r] = -1e30f;
    }

    float p[4][4];
#pragma unroll
    for (int r = 0; r < 4; ++r) {
      float mt = fmaxf(fmaxf(s[0][r], s[1][r]), fmaxf(s[2][r], s[3][r]));
#pragma unroll
      for (int o = 1; o < 16; o <<= 1) mt = fmaxf(mt, __shfl_xor(mt, o, 16));
      float mn = fmaxf(m[r], mt);
      float sc = exp2f((m[r] - mn) * L2E);
      float rs = 0.f;
#pragma unroll
      for (int j = 0; j < 4; ++j) {
        float e = exp2f((s[j][r] - mn) * L2E);
        p[j][r] = e;
        rs += e;
      }
#pragma unroll
      for (int o = 1; o < 16; o <<= 1) rs += __shfl_xor(rs, o, 16);
      lsum[r] = lsum[r] * sc + rs;
      m[r] = mn;
#pragma unroll
      for (int dt = 0; dt < 4; ++dt) acc[dt][r] *= sc;
    }

#pragma unroll
    for (int j = 0; j < 4; ++j)
#pragma unroll
      for (int r = 0; r < 4; ++r) {
        int row = g * 4 + r;
        *((__bf16*)(PwB + row * 128 + (((j * 16 + lr) * 2) ^ ((row & 7) << 4)))) =
            (__bf16)p[j][r];
      }

    {
      int sw = (lr & 7) << 4;
      bf16x8 pa0 = *reinterpret_cast<const bf16x8*>(PwB + lr * 128 + ((g * 16) ^ sw));
      bf16x8 pa1 = *reinterpret_cast<const bf16x8*>(PwB + lr * 128 + ((64 + g * 16) ^ sw));
#pragma unroll
      for (int dt = 0; dt < 4; ++dt) {
        int vrow = dt * 16 + lr, vsw = (vrow & 7) << 4;
        bf16x8 vb0 = *reinterpret_cast<const bf16x8*>(VtB + vrow * 128 + ((g * 16) ^ vsw));
        bf16x8 vb1 = *reinterpret_cast<const bf16x8*>(VtB + vrow * 128 + ((64 + g * 16) ^ vsw));
        acc[dt] = __builtin_amdgcn_mfma_f32_16x16x32_bf16(pa0, vb0, acc[dt], 0, 0, 0);
        acc[dt] = __builtin_amdgcn_mfma_f32_16x16x32_bf16(pa1, vb1, acc[dt], 0, 0, 0);
      }
    }
    __syncthreads();
  }

#pragma unroll
  for (int r = 0; r < 4; ++r) {
    float inv = 1.f / lsum[r];
    int row = bq + w * 16 + g * 4 + r;
#pragma unroll
    for (int dt = 0; dt < 4; ++dt)
      out[(size_t)row * kD + h * 64 + dt * 16 + lr] = (__bf16)(acc[dt][r] * inv);
  }
}

// ---------------------------------------------------------------------------
// Fused residual blend + group rotation (f32).
// ---------------------------------------------------------------------------
__global__ __launch_bounds__(256) void blend_rot_kernel(const float* __restrict__ x,
                                                        const float* __restrict__ y,
                                                        const float* __restrict__ iscale,
                                                        int l,
                                                        const float* __restrict__ R,
                                                        float* __restrict__ xout) {
  int t = blockIdx.x, tid = threadIdx.x;
  __shared__ float xb[kD];
  float s = iscale[l];
  float4 xv = reinterpret_cast<const float4*>(x + (size_t)t * kD)[tid];
  float4 yv = reinterpret_cast<const float4*>(y + (size_t)t * kD)[tid];
  xb[4 * tid + 0] = xv.x + (yv.x - xv.x) * s;
  xb[4 * tid + 1] = xv.y + (yv.y - xv.y) * s;
  xb[4 * tid + 2] = xv.z + (yv.z - xv.z) * s;
  xb[4 * tid + 3] = xv.w + (yv.w - xv.w) * s;
  __syncthreads();
  const float* Rl = R + (size_t)l * kG * 64 * 64;
#pragma unroll
  for (int rep = 0; rep < 4; ++rep) {
    int oi = rep * 256 + tid;
    int gr = oi >> 6, j = oi & 63;
    const float* Rg = Rl + ((size_t)gr << 12);
    const float* xg = &xb[gr << 6];
    float acc = 0.f;
#pragma unroll 8
    for (int i = 0; i < 64; ++i) acc += xg[i] * Rg[(i << 6) + j];
    xout[(size_t)t * kD + oi] = acc;
  }
}

// ---------------------------------------------------------------------------
extern "C" void kernel_launch(void* const* d_in, const int* in_sizes, int n_in,
                              void* d_out, int out_size, void* d_ws, size_t ws_size,
                              hipStream_t stream) {
  const int* tokens = (const int*)d_in[0];
  const float* embed_w = (const float*)d_in[1];
  const float* lm_head_w = (const float*)d_in[2];
  const float* norm_w = (const float*)d_in[3];
  const float* layer_gamma = (const float*)d_in[4];
  const float* layer_beta = (const float*)d_in[5];
  const float* iter_scale = (const float*)d_in[6];
  const float* skew_upper = (const float*)d_in[7];
  const float* ln1_w = (const float*)d_in[8];
  const float* ln2_w = (const float*)d_in[9];
  const float* wqkv = (const float*)d_in[10];
  const float* wo = (const float*)d_in[11];
  const float* w1 = (const float*)d_in[12];
  const float* w2 = (const float*)d_in[13];
  float* out = (float*)d_out;

  // ws: x(4MB) y(4MB) hb(2MB) ab(2MB) R(6.3MB)
  float* x = (float*)d_ws;
  float* y = x + (size_t)kT * kD;
  __bf16* hb = (__bf16*)(y + (size_t)kT * kD);
  __bf16* ab = hb + (size_t)kT * kD;
  float* R = (float*)(ab + (size_t)kT * kD);

  // d_out scratch (all dead before final lm_head GEMM writes out):
  __bf16* qkvb = (__bf16*)out;                       // 3.1M bf16 (1572864 f32)
  __bf16* ffb = (__bf16*)(out + 1572864);            // 4.2M bf16 (2097152 f32)
  __bf16* wqkvT = (__bf16*)(out + 3670016);          // [3072][1024]
  __bf16* woT = (__bf16*)(out + 5242880);            // [1024][1024]
  __bf16* w1T = (__bf16*)(out + 5767168);            // [4096][1024]
  __bf16* w2T = (__bf16*)(out + 7864320);            // [1024][4096]

  cayley_kernel<<<kL * kG, 256, 0, stream>>>(skew_upper, R);
  embed_kernel<<<kT * kD / 4 / 256, 256, 0, stream>>>(tokens, embed_w, x);
  convt_kernel<<<dim3(3 * kD / 64, kD / 64), 256, 0, stream>>>(wqkv, wqkvT, kD, 3 * kD);
  convt_kernel<<<dim3(kD / 64, kD / 64), 256, 0, stream>>>(wo, woT, kD, kD);
  convt_kernel<<<dim3(kFF / 64, kD / 64), 256, 0, stream>>>(w1, w1T, kD, kFF);
  convt_kernel<<<dim3(kD / 64, kFF / 64), 256, 0, stream>>>(w2, w2T, kFF, kD);

  for (int l = 0; l < kL; ++l) {
    rms_kernel<true><<<kT, 256, 0, stream>>>(x, ln1_w, layer_gamma + (size_t)l * kD,
                                             layer_beta + (size_t)l * kD, hb);
    gemm64_kernel<3><<<dim3(3 * kD / 64, kT / 64), 256, 0, stream>>>(
        hb, wqkvT, nullptr, qkvb, kT, 3 * kD, kD);
    fattn_kernel<<<dim3(kT / 64, kH), 256, 0, stream>>>(qkvb, ab);
    gemm64_kernel<1><<<dim3(kD / 64, kT / 64), 256, 0, stream>>>(
        ab, woT, x, y, kT, kD, kD);
    rms_kernel<false><<<kT, 256, 0, stream>>>(y, ln2_w, nullptr, nullptr, hb);
    gemm64_kernel<2><<<dim3(kFF / 64, kT / 64), 256, 0, stream>>>(
        hb, w1T, nullptr, ffb, kT, kFF, kD);
    gemm64_kernel<1><<<dim3(kD / 64, kT / 64), 256, 0, stream>>>(
        ffb, w2T, y, y, kT, kD, kFF);
    blend_rot_kernel<<<kT, 256, 0, stream>>>(x, y, iter_scale, l, R, x);
  }

  rms_kernel<false><<<kT, 256, 0, stream>>>(x, norm_w, nullptr, nullptr, hb);
  gemm_head_kernel<<<dim3(kV / 128, kT / 128), 256, 0, stream>>>(
      hb, lm_head_w, out, kT, kV, kD);
}

// Round 6
// 5100.050 us; speedup vs baseline: 1.1574x; 1.1574x over previous
//
#include <hip/hip_runtime.h>
#include <hip/hip_bf16.h>
#include <math.h>

// Model dims
constexpr int kD = 1024;
constexpr int kH = 16;
constexpr int kV = 32000;
constexpr int kT = 1024;
constexpr int kG = 16;
constexpr int kFF = 4096;
constexpr int kL = 24;
constexpr int kNTRI = 2016;
#define EPSF 1e-6f
#define L2E 1.44269504088896f

typedef __bf16 bf16x8 __attribute__((ext_vector_type(8)));
typedef __bf16 bf16x4 __attribute__((ext_vector_type(4)));
typedef float f32x4 __attribute__((ext_vector_type(4)));

// ---------------------------------------------------------------------------
// Cayley transform: R = (I - A/2)^-1 (I + A/2). One block per (layer,group),
// 256 threads: row r = tid&63, col-chunk q = tid>>6.
// ---------------------------------------------------------------------------
__global__ __launch_bounds__(256) void cayley_kernel(const float* __restrict__ skew,
                                                     float* __restrict__ R) {
  int lg = blockIdx.x;
  int tid = threadIdx.x;
  int r = tid & 63, q = tid >> 6;
  __shared__ float Ms[64][65];
  __shared__ float Bs[64][65];
  const float* su = skew + (size_t)lg * kNTRI;
#pragma unroll
  for (int cc = 0; cc < 16; ++cc) {
    int c = q * 16 + cc;
    float a = 0.f;
    if (r < c) a = su[r * (127 - r) / 2 + (c - r - 1)];
    else if (r > c) a = -su[c * (127 - c) / 2 + (r - c - 1)];
    Ms[r][c] = (r == c ? 1.f : 0.f) - 0.5f * a;
    Bs[r][c] = (r == c ? 1.f : 0.f) + 0.5f * a;
  }
  __syncthreads();
  for (int k = 0; k < 64; ++k) {
    float ip = 1.f / Ms[k][k];
    float f = Ms[r][k];
    float beta = (r == k) ? (1.f - ip) : (f * ip);
    float mk[16], bk[16];
#pragma unroll
    for (int cc = 0; cc < 16; ++cc) {
      mk[cc] = Ms[k][q * 16 + cc];
      bk[cc] = Bs[k][q * 16 + cc];
    }
    __syncthreads();
#pragma unroll
    for (int cc = 0; cc < 16; ++cc) {
      int c = q * 16 + cc;
      Ms[r][c] -= beta * mk[cc];
      Bs[r][c] -= beta * bk[cc];
    }
    __syncthreads();
  }
  float* Ro = R + ((size_t)lg * 64 + r) * 64;
#pragma unroll
  for (int cc = 0; cc < 16; ++cc) Ro[q * 16 + cc] = Bs[r][q * 16 + cc];
}

// ---------------------------------------------------------------------------
// Embedding gather, float4-vectorized.
// ---------------------------------------------------------------------------
__global__ __launch_bounds__(256) void embed_kernel(const int* __restrict__ tok,
                                                    const float* __restrict__ ew,
                                                    float* __restrict__ x) {
  int i = blockIdx.x * 256 + threadIdx.x;
  int t = i >> 8;
  int d4 = i & 255;
  int v = tok[t];
  reinterpret_cast<float4*>(x)[i] =
      reinterpret_cast<const float4*>(ew + (size_t)v * kD)[d4];
}

// ---------------------------------------------------------------------------
// Weight convert+transpose: W f32 [K][N] -> WT bf16 [N][K]. 64x64 tiles.
// ---------------------------------------------------------------------------
__global__ __launch_bounds__(256) void convt_kernel(const float* __restrict__ W,
                                                    __bf16* __restrict__ WT,
                                                    int K, int N) {
  __shared__ float tile[64][65];
  int t = threadIdx.x;
  int n0 = blockIdx.x * 64, k0 = blockIdx.y * 64;
#pragma unroll
  for (int r = 0; r < 4; ++r) {
    int kr = r * 16 + (t >> 4);
    int nc = (t & 15) * 4;
    float4 v = *reinterpret_cast<const float4*>(&W[(size_t)(k0 + kr) * N + n0 + nc]);
    tile[kr][nc + 0] = v.x;
    tile[kr][nc + 1] = v.y;
    tile[kr][nc + 2] = v.z;
    tile[kr][nc + 3] = v.w;
  }
  __syncthreads();
#pragma unroll
  for (int r = 0; r < 2; ++r) {
    int idx = r * 256 + t;
    int nrow = idx >> 3, kc = (idx & 7) * 8;
    bf16x8 v;
#pragma unroll
    for (int j = 0; j < 8; ++j) v[j] = (__bf16)tile[kc + j][nrow];
    *reinterpret_cast<bf16x8*>(&WT[(size_t)(n0 + nrow) * K + k0 + kc]) = v;
  }
}

// ---------------------------------------------------------------------------
// RMSNorm -> bf16 out (shuffle-based reduction, 1 barrier).
// ---------------------------------------------------------------------------
template <bool AFFINE>
__global__ __launch_bounds__(256) void rms_kernel(const float* __restrict__ x,
                                                  const float* __restrict__ w,
                                                  const float* __restrict__ gamma,
                                                  const float* __restrict__ beta,
                                                  __bf16* __restrict__ out) {
  int t = blockIdx.x, tid = threadIdx.x;
  __shared__ float red4[4];
  float4 xv = reinterpret_cast<const float4*>(x + (size_t)t * kD)[tid];
  float ss = xv.x * xv.x + xv.y * xv.y + xv.z * xv.z + xv.w * xv.w;
#pragma unroll
  for (int o = 1; o < 64; o <<= 1) ss += __shfl_xor(ss, o);
  if ((tid & 63) == 0) red4[tid >> 6] = ss;
  __syncthreads();
  float tot = red4[0] + red4[1] + red4[2] + red4[3];
  float rms = rsqrtf(tot / (float)kD + EPSF);
  float4 wv = reinterpret_cast<const float4*>(w)[tid];
  float o0 = xv.x * rms * wv.x;
  float o1 = xv.y * rms * wv.y;
  float o2 = xv.z * rms * wv.z;
  float o3 = xv.w * rms * wv.w;
  if (AFFINE) {
    float4 gv = reinterpret_cast<const float4*>(gamma)[tid];
    float4 bv = reinterpret_cast<const float4*>(beta)[tid];
    o0 = o0 * gv.x + bv.x;
    o1 = o1 * gv.y + bv.y;
    o2 = o2 * gv.z + bv.z;
    o3 = o3 * gv.w + bv.w;
  }
  bf16x4 ov;
  ov[0] = (__bf16)o0; ov[1] = (__bf16)o1; ov[2] = (__bf16)o2; ov[3] = (__bf16)o3;
  *reinterpret_cast<bf16x4*>(out + (size_t)t * kD + tid * 4) = ov;
}

// ---------------------------------------------------------------------------
// 128x128-tile bf16 MFMA GEMM: C[M,N] = A[M,K] @ B[N,K]^T (+ epilogue).
// grid.x = bm (fast axis -> concurrent blocks share B slabs, B streams once).
// LDS: linear row*128B with 16B XOR swizzle (conflict-free write & read).
// BF32: B is f32 [N][K], converted during staging (lm_head path).
// EPI: 0 = f32 store, 1 = f32 acc+res, 2 = gelu(tanh)->bf16, 3 = bf16 store.
// ---------------------------------------------------------------------------
template <int EPI, bool BF32>
__global__ __launch_bounds__(256) void gemm_mfma_kernel(
    const __bf16* __restrict__ A, const void* __restrict__ Bv,
    const float* res, void* __restrict__ Cv, int M, int N, int K) {
  __shared__ __bf16 As[128 * 64];
  __shared__ __bf16 Bs[128 * 64];
  char* AsB = (char*)As;
  char* BsB = (char*)Bs;
  int tid = threadIdx.x;
  int bm = blockIdx.x * 128, bn = blockIdx.y * 128;
  int w = tid >> 6, lane = tid & 63;
  int wr = (w >> 1) * 64, wc = (w & 1) * 64;
  int lrow = lane & 15, g = lane >> 4;
  int fsw = (lrow & 7) << 4;
  f32x4 acc[4][4] = {};

  const __bf16* B16 = (const __bf16*)Bv;
  const float* B32 = (const float*)Bv;

  for (int k0 = 0; k0 < K; k0 += 64) {
#pragma unroll
    for (int rrep = 0; rrep < 4; ++rrep) {
      int cid = rrep * 256 + tid;
      int row = cid >> 3, kb = (cid & 7) * 16;  // byte col in 128B row
      int sw = (row & 7) << 4;
      *reinterpret_cast<bf16x8*>(AsB + row * 128 + (kb ^ sw)) =
          *reinterpret_cast<const bf16x8*>(&A[(size_t)(bm + row) * K + k0 + (kb >> 1)]);
      if (!BF32) {
        *reinterpret_cast<bf16x8*>(BsB + row * 128 + (kb ^ sw)) =
            *reinterpret_cast<const bf16x8*>(&B16[(size_t)(bn + row) * K + k0 + (kb >> 1)]);
      } else {
        const float* src = &B32[(size_t)(bn + row) * K + k0 + (kb >> 1)];
        float4 f0 = *reinterpret_cast<const float4*>(src);
        float4 f1 = *reinterpret_cast<const float4*>(src + 4);
        bf16x8 v;
        v[0] = (__bf16)f0.x; v[1] = (__bf16)f0.y;
        v[2] = (__bf16)f0.z; v[3] = (__bf16)f0.w;
        v[4] = (__bf16)f1.x; v[5] = (__bf16)f1.y;
        v[6] = (__bf16)f1.z; v[7] = (__bf16)f1.w;
        *reinterpret_cast<bf16x8*>(BsB + row * 128 + (kb ^ sw)) = v;
      }
    }
    __syncthreads();
#pragma unroll
    for (int ks = 0; ks < 2; ++ks) {
      bf16x8 af[4], bg[4];
#pragma unroll
      for (int i = 0; i < 4; ++i)
        af[i] = *reinterpret_cast<const bf16x8*>(
            AsB + (wr + i * 16 + lrow) * 128 + ((ks * 64 + g * 16) ^ fsw));
#pragma unroll
      for (int j = 0; j < 4; ++j)
        bg[j] = *reinterpret_cast<const bf16x8*>(
            BsB + (wc + j * 16 + lrow) * 128 + ((ks * 64 + g * 16) ^ fsw));
#pragma unroll
      for (int i = 0; i < 4; ++i)
#pragma unroll
        for (int j = 0; j < 4; ++j)
          acc[i][j] = __builtin_amdgcn_mfma_f32_16x16x32_bf16(af[i], bg[j],
                                                              acc[i][j], 0, 0, 0);
    }
    __syncthreads();
  }

  int crow0 = bm + wr + g * 4;
  int ccol0 = bn + wc + lrow;
#pragma unroll
  for (int i = 0; i < 4; ++i) {
#pragma unroll
    for (int j = 0; j < 4; ++j) {
#pragma unroll
      for (int r = 0; r < 4; ++r) {
        int row = crow0 + i * 16 + r;
        int col = ccol0 + j * 16;
        size_t idx = (size_t)row * N + col;
        float v = acc[i][j][r];
        if (EPI == 1) v += res[idx];
        if (EPI == 2) {
          float u = v;
          v = 0.5f * u * (1.f + tanhf(0.7978845608028654f * (u + 0.044715f * u * u * u)));
        }
        if (EPI == 2 || EPI == 3) ((__bf16*)Cv)[idx] = (__bf16)v;
        else ((float*)Cv)[idx] = v;
      }
    }
  }
}

// ---------------------------------------------------------------------------
// Flash attention v2 (causal), bf16 MFMA. Swapped QK^T: S^T = mfma(K, Q) so
// each lane's softmax row (q = lane&15) is lane-local: reduce = 16 in-reg
// values + 2 shfl_xor. P-write = 4x b64 vectorized. K/V double-buffered with
// issue-early global loads / write-late LDS stores (T14).
// ---------------------------------------------------------------------------
__global__ __launch_bounds__(256) void fattn_kernel(const __bf16* __restrict__ qkv,
                                                    __bf16* __restrict__ out) {
  __shared__ __bf16 Ks[2][64 * 64];
  __shared__ __bf16 Vt[2][64 * 64];
  __shared__ __bf16 Ps[4 * 16 * 64];
  int tid = threadIdx.x;
  int bq = blockIdx.x * 64;
  int h = blockIdx.y;
  int w = tid >> 6, lane = tid & 63;
  int g = lane >> 4, lr = lane & 15;

  // Q fragments (B-operand of swapped QK^T): lane holds Q[w*16+lr][ks*32+g*8+j]
  bf16x8 qf[2];
  const __bf16* qbase = qkv + (size_t)(bq + w * 16 + lr) * (3 * kD) + h * 64;
#pragma unroll
  for (int ks = 0; ks < 2; ++ks) {
    bf16x8 v = *reinterpret_cast<const bf16x8*>(qbase + ks * 32 + g * 8);
#pragma unroll
    for (int j = 0; j < 8; ++j) qf[ks][j] = (__bf16)((float)v[j] * 0.125f);
  }

  f32x4 acc[4] = {};
  float m = -1e30f, lsum = 0.f;  // softmax state for q-row = lr (per-lane)

  int srow = tid >> 2, sseg = tid & 3;
  int vk = tid & 63, vd0 = (tid >> 6) * 16;
  char* PwB = (char*)(Ps + w * (16 * 64));
  int psw = (lr & 7) << 4;

  bf16x8 ka, kb2, va, vb;
  int ntiles = bq / 64 + 1;

  // prologue: load+store tile 0
  {
    const __bf16* src = qkv + (size_t)(srow) * (3 * kD) + kD + h * 64 + sseg * 16;
    ka = *reinterpret_cast<const bf16x8*>(src);
    kb2 = *reinterpret_cast<const bf16x8*>(src + 8);
    const __bf16* vsrc = qkv + (size_t)(vk) * (3 * kD) + 2 * kD + h * 64 + vd0;
    va = *reinterpret_cast<const bf16x8*>(vsrc);
    vb = *reinterpret_cast<const bf16x8*>(vsrc + 8);
    char* KsB = (char*)Ks[0];
    char* VtB = (char*)Vt[0];
    int bc = sseg * 32, sw = (srow & 7) << 4;
    *reinterpret_cast<bf16x8*>(KsB + srow * 128 + (bc ^ sw)) = ka;
    *reinterpret_cast<bf16x8*>(KsB + srow * 128 + ((bc + 16) ^ sw)) = kb2;
#pragma unroll
    for (int i = 0; i < 8; ++i) {
      int d = vd0 + i;
      *((__bf16*)(VtB + d * 128 + ((vk * 2) ^ ((d & 7) << 4)))) = va[i];
      d = vd0 + 8 + i;
      *((__bf16*)(VtB + d * 128 + ((vk * 2) ^ ((d & 7) << 4)))) = vb[i];
    }
  }

  int cur = 0;
  for (int kt = 0; kt < ntiles; ++kt) {
    // issue next tile's global loads early (latency hides under compute)
    if (kt + 1 < ntiles) {
      const __bf16* src =
          qkv + (size_t)((kt + 1) * 64 + srow) * (3 * kD) + kD + h * 64 + sseg * 16;
      ka = *reinterpret_cast<const bf16x8*>(src);
      kb2 = *reinterpret_cast<const bf16x8*>(src + 8);
      const __bf16* vsrc =
          qkv + (size_t)((kt + 1) * 64 + vk) * (3 * kD) + 2 * kD + h * 64 + vd0;
      va = *reinterpret_cast<const bf16x8*>(vsrc);
      vb = *reinterpret_cast<const bf16x8*>(vsrc + 8);
    }
    __syncthreads();  // buf[cur] staged & visible

    char* KsB = (char*)Ks[cur];
    char* VtB = (char*)Vt[cur];
    bool diag = (kt == ntiles - 1);
    int jmax = diag ? w : 3;

    // ---- QK^T (swapped): S^T[key][q], A = K rows, B = Q ----
    f32x4 s[4];
#pragma unroll
    for (int jj = 0; jj < 4; ++jj) {
      if (jj <= jmax) {
        int krow = jj * 16 + lr;
        int ksw = (lr & 7) << 4;
        bf16x8 k0 = *reinterpret_cast<const bf16x8*>(KsB + krow * 128 + ((g * 16) ^ ksw));
        bf16x8 k1 = *reinterpret_cast<const bf16x8*>(KsB + krow * 128 + ((64 + g * 16) ^ ksw));
        f32x4 z = {};
        z = __builtin_amdgcn_mfma_f32_16x16x32_bf16(k0, qf[0], z, 0, 0, 0);
        s[jj] = __builtin_amdgcn_mfma_f32_16x16x32_bf16(k1, qf[1], z, 0, 0, 0);
      } else {
        s[jj] = f32x4{-1e30f, -1e30f, -1e30f, -1e30f};
      }
    }
    // diagonal: subtile jj==w partial; lane holds key=jj*16+g*4+r, q=lr
    if (diag) {
#pragma unroll
      for (int r = 0; r < 4; ++r)
        if (g * 4 + r > lr) s[w][r] = -1e30f;
    }

    // ---- per-lane online softmax (q = lr) ----
    float mt = -1e30f;
#pragma unroll
    for (int jj = 0; jj < 4; ++jj)
#pragma unroll
      for (int r = 0; r < 4; ++r) mt = fmaxf(mt, s[jj][r]);
    mt = fmaxf(mt, __shfl_xor(mt, 16));
    mt = fmaxf(mt, __shfl_xor(mt, 32));
    float mn = fmaxf(m, mt);
    float sc = exp2f((m - mn) * L2E);
    float p[4][4];
    float rs = 0.f;
#pragma unroll
    for (int jj = 0; jj < 4; ++jj)
#pragma unroll
      for (int r = 0; r < 4; ++r) {
        float e = exp2f((s[jj][r] - mn) * L2E);
        p[jj][r] = e;
        rs += e;
      }
    rs += __shfl_xor(rs, 16);
    rs += __shfl_xor(rs, 32);
    lsum = lsum * sc + rs;
    m = mn;
    // rescale acc: acc[dt][r] belongs to q-row g*4+r -> fetch that row's sc
#pragma unroll
    for (int r = 0; r < 4; ++r) {
      float s4 = __shfl(sc, 20 * g + r);  // lane g*16 + (g*4+r)
#pragma unroll
      for (int dt = 0; dt < 4; ++dt) acc[dt][r] *= s4;
    }

    // ---- P write: row lr, cols jj*16+g*4+(0..3) -> b64 vectorized ----
#pragma unroll
    for (int jj = 0; jj < 4; ++jj) {
      bf16x4 pv;
#pragma unroll
      for (int r = 0; r < 4; ++r) pv[r] = (__bf16)p[jj][r];
      *reinterpret_cast<bf16x4*>(PwB + lr * 128 + ((jj * 32 + g * 8) ^ psw)) = pv;
    }

    // ---- PV: A = P rows, B = V^T ----
    {
      bf16x8 pa0 = *reinterpret_cast<const bf16x8*>(PwB + lr * 128 + ((g * 16) ^ psw));
      bf16x8 pa1 = *reinterpret_cast<const bf16x8*>(PwB + lr * 128 + ((64 + g * 16) ^ psw));
#pragma unroll
      for (int dt = 0; dt < 4; ++dt) {
        int vrow = dt * 16 + lr;
        int vsw = (lr & 7) << 4;
        bf16x8 vb0 = *reinterpret_cast<const bf16x8*>(VtB + vrow * 128 + ((g * 16) ^ vsw));
        bf16x8 vb1 = *reinterpret_cast<const bf16x8*>(VtB + vrow * 128 + ((64 + g * 16) ^ vsw));
        acc[dt] = __builtin_amdgcn_mfma_f32_16x16x32_bf16(pa0, vb0, acc[dt], 0, 0, 0);
        acc[dt] = __builtin_amdgcn_mfma_f32_16x16x32_bf16(pa1, vb1, acc[dt], 0, 0, 0);
      }
    }
    __syncthreads();  // all waves done reading buf[cur]

    // write-late: stage next tile into the other buffer
    if (kt + 1 < ntiles) {
      char* KsN = (char*)Ks[cur ^ 1];
      char* VtN = (char*)Vt[cur ^ 1];
      int bc = sseg * 32, sw = (srow & 7) << 4;
      *reinterpret_cast<bf16x8*>(KsN + srow * 128 + (bc ^ sw)) = ka;
      *reinterpret_cast<bf16x8*>(KsN + srow * 128 + ((bc + 16) ^ sw)) = kb2;
#pragma unroll
      for (int i = 0; i < 8; ++i) {
        int d = vd0 + i;
        *((__bf16*)(VtN + d * 128 + ((vk * 2) ^ ((d & 7) << 4)))) = va[i];
        d = vd0 + 8 + i;
        *((__bf16*)(VtN + d * 128 + ((vk * 2) ^ ((d & 7) << 4)))) = vb[i];
      }
      cur ^= 1;
    }
  }

  // ---- epilogue: O[q=g*4+r][d=dt*16+lr], normalize by that row's lsum ----
  float linv = 1.f / lsum;
#pragma unroll
  for (int r = 0; r < 4; ++r) {
    float ir = __shfl(linv, 20 * g + r);
    int row = bq + w * 16 + g * 4 + r;
#pragma unroll
    for (int dt = 0; dt < 4; ++dt)
      out[(size_t)row * kD + h * 64 + dt * 16 + lr] = (__bf16)(acc[dt][r] * ir);
  }
}

// ---------------------------------------------------------------------------
// Fused residual blend + group rotation, re-blocked as (token-chunk, group):
// R[g] read once per block (R traffic 268 MB -> 4 MB per layer).
// ---------------------------------------------------------------------------
__global__ __launch_bounds__(256) void blend_rot_kernel(const float* x,
                                                        const float* y,
                                                        const float* iscale,
                                                        int l,
                                                        const float* __restrict__ Rall,
                                                        float* xout) {
  int tc = blockIdx.x, gr = blockIdx.y;
  int tid = threadIdx.x;
  __shared__ float Rs[64 * 64];
  __shared__ float xb[64][65];
  float s = iscale[l];
  const float* Rg = Rall + ((size_t)l * kG + gr) * 4096;
  {
    int off = tid * 16;
#pragma unroll
    for (int q2 = 0; q2 < 4; ++q2) {
      float4 rv = *reinterpret_cast<const float4*>(Rg + off + q2 * 4);
      *reinterpret_cast<float4*>(&Rs[off + q2 * 4]) = rv;
    }
  }
  int tok = tid & 63, seg = (tid >> 6) * 16;
  {
    const float* xr = x + (size_t)(tc * 64 + tok) * kD + gr * 64 + seg;
    const float* yr = y + (size_t)(tc * 64 + tok) * kD + gr * 64 + seg;
#pragma unroll
    for (int q2 = 0; q2 < 4; ++q2) {
      float4 xv = *reinterpret_cast<const float4*>(xr + q2 * 4);
      float4 yv = *reinterpret_cast<const float4*>(yr + q2 * 4);
      xb[tok][seg + q2 * 4 + 0] = xv.x + (yv.x - xv.x) * s;
      xb[tok][seg + q2 * 4 + 1] = xv.y + (yv.y - xv.y) * s;
      xb[tok][seg + q2 * 4 + 2] = xv.z + (yv.z - xv.z) * s;
      xb[tok][seg + q2 * 4 + 3] = xv.w + (yv.w - xv.w) * s;
    }
  }
  __syncthreads();
  float o[16] = {};
  for (int i = 0; i < 64; ++i) {
    float xv = xb[tok][i];  // 2-way bank alias (free); Rs read is broadcast
#pragma unroll
    for (int d = 0; d < 16; ++d) o[d] += xv * Rs[i * 64 + seg + d];
  }
  float* outr = xout + (size_t)(tc * 64 + tok) * kD + gr * 64 + seg;
#pragma unroll
  for (int q2 = 0; q2 < 4; ++q2) {
    float4 ov = {o[q2 * 4 + 0], o[q2 * 4 + 1], o[q2 * 4 + 2], o[q2 * 4 + 3]};
    *reinterpret_cast<float4*>(outr + q2 * 4) = ov;
  }
}

// ---------------------------------------------------------------------------
extern "C" void kernel_launch(void* const* d_in, const int* in_sizes, int n_in,
                              void* d_out, int out_size, void* d_ws, size_t ws_size,
                              hipStream_t stream) {
  const int* tokens = (const int*)d_in[0];
  const float* embed_w = (const float*)d_in[1];
  const float* lm_head_w = (const float*)d_in[2];
  const float* norm_w = (const float*)d_in[3];
  const float* layer_gamma = (const float*)d_in[4];
  const float* layer_beta = (const float*)d_in[5];
  const float* iter_scale = (const float*)d_in[6];
  const float* skew_upper = (const float*)d_in[7];
  const float* ln1_w = (const float*)d_in[8];
  const float* ln2_w = (const float*)d_in[9];
  const float* wqkv = (const float*)d_in[10];
  const float* wo = (const float*)d_in[11];
  const float* w1 = (const float*)d_in[12];
  const float* w2 = (const float*)d_in[13];
  float* out = (float*)d_out;

  // ws: x(4MB) y(4MB) hb(2MB) ab(2MB) R(6.3MB)
  float* x = (float*)d_ws;
  float* y = x + (size_t)kT * kD;
  __bf16* hb = (__bf16*)(y + (size_t)kT * kD);
  __bf16* ab = hb + (size_t)kT * kD;
  float* R = (float*)(ab + (size_t)kT * kD);

  // d_out scratch (all dead before final lm_head GEMM writes out):
  __bf16* qkvb = (__bf16*)out;                       // 3.1M bf16
  __bf16* ffb = (__bf16*)(out + 1572864);            // 4.2M bf16
  __bf16* wqkvT = (__bf16*)(out + 3670016);          // [3072][1024]
  __bf16* woT = (__bf16*)(out + 5242880);            // [1024][1024]
  __bf16* w1T = (__bf16*)(out + 5767168);            // [4096][1024]
  __bf16* w2T = (__bf16*)(out + 7864320);            // [1024][4096]

  cayley_kernel<<<kL * kG, 256, 0, stream>>>(skew_upper, R);
  embed_kernel<<<kT * kD / 4 / 256, 256, 0, stream>>>(tokens, embed_w, x);
  convt_kernel<<<dim3(3 * kD / 64, kD / 64), 256, 0, stream>>>(wqkv, wqkvT, kD, 3 * kD);
  convt_kernel<<<dim3(kD / 64, kD / 64), 256, 0, stream>>>(wo, woT, kD, kD);
  convt_kernel<<<dim3(kFF / 64, kD / 64), 256, 0, stream>>>(w1, w1T, kD, kFF);
  convt_kernel<<<dim3(kD / 64, kFF / 64), 256, 0, stream>>>(w2, w2T, kFF, kD);

  for (int l = 0; l < kL; ++l) {
    rms_kernel<true><<<kT, 256, 0, stream>>>(x, ln1_w, layer_gamma + (size_t)l * kD,
                                             layer_beta + (size_t)l * kD, hb);
    gemm_mfma_kernel<3, false><<<dim3(kT / 128, 3 * kD / 128), 256, 0, stream>>>(
        hb, wqkvT, nullptr, qkvb, kT, 3 * kD, kD);
    fattn_kernel<<<dim3(kT / 64, kH), 256, 0, stream>>>(qkvb, ab);
    gemm_mfma_kernel<1, false><<<dim3(kT / 128, kD / 128), 256, 0, stream>>>(
        ab, woT, x, y, kT, kD, kD);
    rms_kernel<false><<<kT, 256, 0, stream>>>(y, ln2_w, nullptr, nullptr, hb);
    gemm_mfma_kernel<2, false><<<dim3(kT / 128, kFF / 128), 256, 0, stream>>>(
        hb, w1T, nullptr, ffb, kT, kFF, kD);
    gemm_mfma_kernel<1, false><<<dim3(kT / 128, kD / 128), 256, 0, stream>>>(
        ffb, w2T, y, y, kT, kD, kFF);
    blend_rot_kernel<<<dim3(kT / 64, kG), 256, 0, stream>>>(x, y, iter_scale, l, R, x);
  }

  rms_kernel<false><<<kT, 256, 0, stream>>>(x, norm_w, nullptr, nullptr, hb);
  gemm_mfma_kernel<0, true><<<dim3(kT / 128, kV / 128), 256, 0, stream>>>(
      hb, lm_head_w, nullptr, out, kT, kV, kD);
}

// Round 7
// 3611.543 us; speedup vs baseline: 1.6344x; 1.4122x over previous
//
#include <hip/hip_runtime.h>
#include <hip/hip_bf16.h>
#include <math.h>

// Model dims
constexpr int kD = 1024;
constexpr int kH = 16;
constexpr int kV = 32000;
constexpr int kT = 1024;
constexpr int kG = 16;
constexpr int kFF = 4096;
constexpr int kL = 24;
constexpr int kNTRI = 2016;
#define EPSF 1e-6f
#define L2E 1.44269504088896f

typedef __bf16 bf16x8 __attribute__((ext_vector_type(8)));
typedef __bf16 bf16x4 __attribute__((ext_vector_type(4)));
typedef float f32x4 __attribute__((ext_vector_type(4)));

#define GLOAD16(g, l)                                                   \
  __builtin_amdgcn_global_load_lds(                                     \
      (const __attribute__((address_space(1))) void*)(g),               \
      (__attribute__((address_space(3))) void*)(l), 16, 0, 0)

// ---------------------------------------------------------------------------
// Cayley transform: R = (I - A/2)^-1 (I + A/2). One block per (layer,group).
// ---------------------------------------------------------------------------
__global__ __launch_bounds__(256) void cayley_kernel(const float* __restrict__ skew,
                                                     float* __restrict__ R) {
  int lg = blockIdx.x;
  int tid = threadIdx.x;
  int r = tid & 63, q = tid >> 6;
  __shared__ float Ms[64][65];
  __shared__ float Bs[64][65];
  const float* su = skew + (size_t)lg * kNTRI;
#pragma unroll
  for (int cc = 0; cc < 16; ++cc) {
    int c = q * 16 + cc;
    float a = 0.f;
    if (r < c) a = su[r * (127 - r) / 2 + (c - r - 1)];
    else if (r > c) a = -su[c * (127 - c) / 2 + (r - c - 1)];
    Ms[r][c] = (r == c ? 1.f : 0.f) - 0.5f * a;
    Bs[r][c] = (r == c ? 1.f : 0.f) + 0.5f * a;
  }
  __syncthreads();
  for (int k = 0; k < 64; ++k) {
    float ip = 1.f / Ms[k][k];
    float f = Ms[r][k];
    float beta = (r == k) ? (1.f - ip) : (f * ip);
    float mk[16], bk[16];
#pragma unroll
    for (int cc = 0; cc < 16; ++cc) {
      mk[cc] = Ms[k][q * 16 + cc];
      bk[cc] = Bs[k][q * 16 + cc];
    }
    __syncthreads();
#pragma unroll
    for (int cc = 0; cc < 16; ++cc) {
      int c = q * 16 + cc;
      Ms[r][c] -= beta * mk[cc];
      Bs[r][c] -= beta * bk[cc];
    }
    __syncthreads();
  }
  float* Ro = R + ((size_t)lg * 64 + r) * 64;
#pragma unroll
  for (int cc = 0; cc < 16; ++cc) Ro[q * 16 + cc] = Bs[r][q * 16 + cc];
}

// ---------------------------------------------------------------------------
// Embedding gather, float4-vectorized.
// ---------------------------------------------------------------------------
__global__ __launch_bounds__(256) void embed_kernel(const int* __restrict__ tok,
                                                    const float* __restrict__ ew,
                                                    float* __restrict__ x) {
  int i = blockIdx.x * 256 + threadIdx.x;
  int t = i >> 8;
  int d4 = i & 255;
  int v = tok[t];
  reinterpret_cast<float4*>(x)[i] =
      reinterpret_cast<const float4*>(ew + (size_t)v * kD)[d4];
}

// ---------------------------------------------------------------------------
// Weight convert+transpose: W f32 [K][N] -> WT bf16 [N][K]. 64x64 tiles.
// ---------------------------------------------------------------------------
__global__ __launch_bounds__(256) void convt_kernel(const float* __restrict__ W,
                                                    __bf16* __restrict__ WT,
                                                    int K, int N) {
  __shared__ float tile[64][65];
  int t = threadIdx.x;
  int n0 = blockIdx.x * 64, k0 = blockIdx.y * 64;
#pragma unroll
  for (int r = 0; r < 4; ++r) {
    int kr = r * 16 + (t >> 4);
    int nc = (t & 15) * 4;
    float4 v = *reinterpret_cast<const float4*>(&W[(size_t)(k0 + kr) * N + n0 + nc]);
    tile[kr][nc + 0] = v.x;
    tile[kr][nc + 1] = v.y;
    tile[kr][nc + 2] = v.z;
    tile[kr][nc + 3] = v.w;
  }
  __syncthreads();
#pragma unroll
  for (int r = 0; r < 2; ++r) {
    int idx = r * 256 + t;
    int nrow = idx >> 3, kc = (idx & 7) * 8;
    bf16x8 v;
#pragma unroll
    for (int j = 0; j < 8; ++j) v[j] = (__bf16)tile[kc + j][nrow];
    *reinterpret_cast<bf16x8*>(&WT[(size_t)(n0 + nrow) * K + k0 + kc]) = v;
  }
}

// ---------------------------------------------------------------------------
// RMSNorm -> bf16 out (shuffle-based reduction, 1 barrier).
// ---------------------------------------------------------------------------
template <bool AFFINE>
__global__ __launch_bounds__(256) void rms_kernel(const float* __restrict__ x,
                                                  const float* __restrict__ w,
                                                  const float* __restrict__ gamma,
                                                  const float* __restrict__ beta,
                                                  __bf16* __restrict__ out) {
  int t = blockIdx.x, tid = threadIdx.x;
  __shared__ float red4[4];
  float4 xv = reinterpret_cast<const float4*>(x + (size_t)t * kD)[tid];
  float ss = xv.x * xv.x + xv.y * xv.y + xv.z * xv.z + xv.w * xv.w;
#pragma unroll
  for (int o = 1; o < 64; o <<= 1) ss += __shfl_xor(ss, o);
  if ((tid & 63) == 0) red4[tid >> 6] = ss;
  __syncthreads();
  float tot = red4[0] + red4[1] + red4[2] + red4[3];
  float rms = rsqrtf(tot / (float)kD + EPSF);
  float4 wv = reinterpret_cast<const float4*>(w)[tid];
  float o0 = xv.x * rms * wv.x;
  float o1 = xv.y * rms * wv.y;
  float o2 = xv.z * rms * wv.z;
  float o3 = xv.w * rms * wv.w;
  if (AFFINE) {
    float4 gv = reinterpret_cast<const float4*>(gamma)[tid];
    float4 bv = reinterpret_cast<const float4*>(beta)[tid];
    o0 = o0 * gv.x + bv.x;
    o1 = o1 * gv.y + bv.y;
    o2 = o2 * gv.z + bv.z;
    o3 = o3 * gv.w + bv.w;
  }
  bf16x4 ov;
  ov[0] = (__bf16)o0; ov[1] = (__bf16)o1; ov[2] = (__bf16)o2; ov[3] = (__bf16)o3;
  *reinterpret_cast<bf16x4*>(out + (size_t)t * kD + tid * 4) = ov;
}

// ---------------------------------------------------------------------------
// MFMA GEMM, m97 structure: global_load_lds width=16, linear LDS, BK=64,
// 2-barrier K-loop. C[M,N] = A[M,K](bf16) @ B[N,K]^T. 256 thd = 4 waves 2x2.
// 1D grid with XCD-chunked swizzle (grid %8 == 0): all bm-blocks of one
// bn-panel land on the same XCD -> B panel fetched once per chip.
// BF32: B is f32 [N][K], reg-stage converted (lm_head). EPI: 0=f32,
// 1=f32 acc+res, 2=gelu->bf16, 3=bf16.
// ---------------------------------------------------------------------------
template <int BM, int BN, int EPI, bool BF32>
__global__ __launch_bounds__(256) void gemm_kernel(
    const __bf16* __restrict__ A, const void* __restrict__ Bv,
    const float* res, void* __restrict__ Cv, int M, int N, int K) {
  constexpr int AISS = BM / 32;  // gload issues per wave (A)
  constexpr int BISS = BN / 32;
  constexpr int FM = BM / 32;    // frags per wave (2x2 wave grid)
  constexpr int FN = BN / 32;
  __shared__ __bf16 As[BM * 64];
  __shared__ __bf16 Bs[BN * 64];
  int tid = threadIdx.x;
  int w = tid >> 6, lane = tid & 63;
  int mt = M / BM;
  int cpx = gridDim.x >> 3;
  int id = (blockIdx.x & 7) * cpx + (blockIdx.x >> 3);
  int bm = (id % mt) * BM, bn = (id / mt) * BN;
  int lrow = lane & 15, g = lane >> 4;
  int grow = lane >> 3, gcol = (lane & 7) * 8;  // staging lane -> row, col
  int wr = (w >> 1) * (BM / 2), wc = (w & 1) * (BN / 2);
  f32x4 acc[FM][FN] = {};
  const __bf16* B16 = (const __bf16*)Bv;
  const float* B32 = (const float*)Bv;

  for (int k0 = 0; k0 < K; k0 += 64) {
#pragma unroll
    for (int i = 0; i < AISS; ++i) {
      int rbase = (i * 4 + w) * 8;
      GLOAD16(&A[(size_t)(bm + rbase + grow) * K + k0 + gcol], &As[rbase * 64]);
    }
    if (!BF32) {
#pragma unroll
      for (int i = 0; i < BISS; ++i) {
        int rbase = (i * 4 + w) * 8;
        GLOAD16(&B16[(size_t)(bn + rbase + grow) * K + k0 + gcol], &Bs[rbase * 64]);
      }
    } else {
#pragma unroll
      for (int rrep = 0; rrep < BN / 32; ++rrep) {
        int cid = rrep * 256 + tid;
        int row = cid >> 3, kc = (cid & 7) * 8;
        const float* src = &B32[(size_t)(bn + row) * K + k0 + kc];
        float4 f0 = *reinterpret_cast<const float4*>(src);
        float4 f1 = *reinterpret_cast<const float4*>(src + 4);
        bf16x8 v;
        v[0] = (__bf16)f0.x; v[1] = (__bf16)f0.y;
        v[2] = (__bf16)f0.z; v[3] = (__bf16)f0.w;
        v[4] = (__bf16)f1.x; v[5] = (__bf16)f1.y;
        v[6] = (__bf16)f1.z; v[7] = (__bf16)f1.w;
        *reinterpret_cast<bf16x8*>(&Bs[row * 64 + kc]) = v;
      }
    }
    __syncthreads();
#pragma unroll
    for (int ks = 0; ks < 2; ++ks) {
      bf16x8 af[FM], bg[FN];
#pragma unroll
      for (int i = 0; i < FM; ++i)
        af[i] = *reinterpret_cast<const bf16x8*>(
            &As[(wr + i * 16 + lrow) * 64 + ks * 32 + g * 8]);
#pragma unroll
      for (int j = 0; j < FN; ++j)
        bg[j] = *reinterpret_cast<const bf16x8*>(
            &Bs[(wc + j * 16 + lrow) * 64 + ks * 32 + g * 8]);
#pragma unroll
      for (int i = 0; i < FM; ++i)
#pragma unroll
        for (int j = 0; j < FN; ++j)
          acc[i][j] = __builtin_amdgcn_mfma_f32_16x16x32_bf16(af[i], bg[j],
                                                              acc[i][j], 0, 0, 0);
    }
    __syncthreads();
  }

  int crow0 = bm + wr + g * 4;
  int ccol0 = bn + wc + lrow;
#pragma unroll
  for (int i = 0; i < FM; ++i) {
#pragma unroll
    for (int j = 0; j < FN; ++j) {
#pragma unroll
      for (int r = 0; r < 4; ++r) {
        int row = crow0 + i * 16 + r;
        int col = ccol0 + j * 16;
        size_t idx = (size_t)row * N + col;
        float v = acc[i][j][r];
        if (EPI == 1) v += res[idx];
        if (EPI == 2) {
          float u = v;
          float z = 0.7978845608028654f * (u + 0.044715f * u * u * u);
          float ez = exp2f(z * (2.f * L2E));
          v = u * ez / (1.f + ez);
        }
        if (EPI == 2 || EPI == 3) ((__bf16*)Cv)[idx] = (__bf16)v;
        else ((float*)Cv)[idx] = v;
      }
    }
  }
}

// ---------------------------------------------------------------------------
// Flash attention (causal), bf16 MFMA, swapped QK^T, per-lane online softmax,
// K/V double-buffered with issue-early / write-late staging.
// ---------------------------------------------------------------------------
__global__ __launch_bounds__(256) void fattn_kernel(const __bf16* __restrict__ qkv,
                                                    __bf16* __restrict__ out) {
  __shared__ __bf16 Ks[2][64 * 64];
  __shared__ __bf16 Vt[2][64 * 64];
  __shared__ __bf16 Ps[4 * 16 * 64];
  int tid = threadIdx.x;
  int bq = blockIdx.x * 64;
  int h = blockIdx.y;
  int w = tid >> 6, lane = tid & 63;
  int g = lane >> 4, lr = lane & 15;

  bf16x8 qf[2];
  const __bf16* qbase = qkv + (size_t)(bq + w * 16 + lr) * (3 * kD) + h * 64;
#pragma unroll
  for (int ks = 0; ks < 2; ++ks) {
    bf16x8 v = *reinterpret_cast<const bf16x8*>(qbase + ks * 32 + g * 8);
#pragma unroll
    for (int j = 0; j < 8; ++j) qf[ks][j] = (__bf16)((float)v[j] * 0.125f);
  }

  f32x4 acc[4] = {};
  float m = -1e30f, lsum = 0.f;

  int srow = tid >> 2, sseg = tid & 3;
  int vk = tid & 63, vd0 = (tid >> 6) * 16;
  char* PwB = (char*)(Ps + w * (16 * 64));
  int psw = (lr & 7) << 4;

  bf16x8 ka, kb2, va, vb;
  int ntiles = bq / 64 + 1;

  {
    const __bf16* src = qkv + (size_t)(srow) * (3 * kD) + kD + h * 64 + sseg * 16;
    ka = *reinterpret_cast<const bf16x8*>(src);
    kb2 = *reinterpret_cast<const bf16x8*>(src + 8);
    const __bf16* vsrc = qkv + (size_t)(vk) * (3 * kD) + 2 * kD + h * 64 + vd0;
    va = *reinterpret_cast<const bf16x8*>(vsrc);
    vb = *reinterpret_cast<const bf16x8*>(vsrc + 8);
    char* KsB = (char*)Ks[0];
    char* VtB = (char*)Vt[0];
    int bc = sseg * 32, sw = (srow & 7) << 4;
    *reinterpret_cast<bf16x8*>(KsB + srow * 128 + (bc ^ sw)) = ka;
    *reinterpret_cast<bf16x8*>(KsB + srow * 128 + ((bc + 16) ^ sw)) = kb2;
#pragma unroll
    for (int i = 0; i < 8; ++i) {
      int d = vd0 + i;
      *((__bf16*)(VtB + d * 128 + ((vk * 2) ^ ((d & 7) << 4)))) = va[i];
      d = vd0 + 8 + i;
      *((__bf16*)(VtB + d * 128 + ((vk * 2) ^ ((d & 7) << 4)))) = vb[i];
    }
  }

  int cur = 0;
  for (int kt = 0; kt < ntiles; ++kt) {
    if (kt + 1 < ntiles) {
      const __bf16* src =
          qkv + (size_t)((kt + 1) * 64 + srow) * (3 * kD) + kD + h * 64 + sseg * 16;
      ka = *reinterpret_cast<const bf16x8*>(src);
      kb2 = *reinterpret_cast<const bf16x8*>(src + 8);
      const __bf16* vsrc =
          qkv + (size_t)((kt + 1) * 64 + vk) * (3 * kD) + 2 * kD + h * 64 + vd0;
      va = *reinterpret_cast<const bf16x8*>(vsrc);
      vb = *reinterpret_cast<const bf16x8*>(vsrc + 8);
    }
    __syncthreads();

    char* KsB = (char*)Ks[cur];
    char* VtB = (char*)Vt[cur];
    bool diag = (kt == ntiles - 1);
    int jmax = diag ? w : 3;

    f32x4 s[4];
#pragma unroll
    for (int jj = 0; jj < 4; ++jj) {
      if (jj <= jmax) {
        int krow = jj * 16 + lr;
        int ksw = (lr & 7) << 4;
        bf16x8 k0 = *reinterpret_cast<const bf16x8*>(KsB + krow * 128 + ((g * 16) ^ ksw));
        bf16x8 k1 = *reinterpret_cast<const bf16x8*>(KsB + krow * 128 + ((64 + g * 16) ^ ksw));
        f32x4 z = {};
        z = __builtin_amdgcn_mfma_f32_16x16x32_bf16(k0, qf[0], z, 0, 0, 0);
        s[jj] = __builtin_amdgcn_mfma_f32_16x16x32_bf16(k1, qf[1], z, 0, 0, 0);
      } else {
        s[jj] = f32x4{-1e30f, -1e30f, -1e30f, -1e30f};
      }
    }
    if (diag) {
#pragma unroll
      for (int r = 0; r < 4; ++r)
        if (g * 4 + r > lr) s[w][r] = -1e30f;
    }

    float mt = -1e30f;
#pragma unroll
    for (int jj = 0; jj < 4; ++jj)
#pragma unroll
      for (int r = 0; r < 4; ++r) mt = fmaxf(mt, s[jj][r]);
    mt = fmaxf(mt, __shfl_xor(mt, 16));
    mt = fmaxf(mt, __shfl_xor(mt, 32));
    float mn = fmaxf(m, mt);
    float sc = exp2f((m - mn) * L2E);
    float p[4][4];
    float rs = 0.f;
#pragma unroll
    for (int jj = 0; jj < 4; ++jj)
#pragma unroll
      for (int r = 0; r < 4; ++r) {
        float e = exp2f((s[jj][r] - mn) * L2E);
        p[jj][r] = e;
        rs += e;
      }
    rs += __shfl_xor(rs, 16);
    rs += __shfl_xor(rs, 32);
    lsum = lsum * sc + rs;
    m = mn;
#pragma unroll
    for (int r = 0; r < 4; ++r) {
      float s4 = __shfl(sc, 20 * g + r);
#pragma unroll
      for (int dt = 0; dt < 4; ++dt) acc[dt][r] *= s4;
    }

#pragma unroll
    for (int jj = 0; jj < 4; ++jj) {
      bf16x4 pv;
#pragma unroll
      for (int r = 0; r < 4; ++r) pv[r] = (__bf16)p[jj][r];
      *reinterpret_cast<bf16x4*>(PwB + lr * 128 + ((jj * 32 + g * 8) ^ psw)) = pv;
    }

    {
      bf16x8 pa0 = *reinterpret_cast<const bf16x8*>(PwB + lr * 128 + ((g * 16) ^ psw));
      bf16x8 pa1 = *reinterpret_cast<const bf16x8*>(PwB + lr * 128 + ((64 + g * 16) ^ psw));
#pragma unroll
      for (int dt = 0; dt < 4; ++dt) {
        int vrow = dt * 16 + lr;
        int vsw = (lr & 7) << 4;
        bf16x8 vb0 = *reinterpret_cast<const bf16x8*>(VtB + vrow * 128 + ((g * 16) ^ vsw));
        bf16x8 vb1 = *reinterpret_cast<const bf16x8*>(VtB + vrow * 128 + ((64 + g * 16) ^ vsw));
        acc[dt] = __builtin_amdgcn_mfma_f32_16x16x32_bf16(pa0, vb0, acc[dt], 0, 0, 0);
        acc[dt] = __builtin_amdgcn_mfma_f32_16x16x32_bf16(pa1, vb1, acc[dt], 0, 0, 0);
      }
    }
    __syncthreads();

    if (kt + 1 < ntiles) {
      char* KsN = (char*)Ks[cur ^ 1];
      char* VtN = (char*)Vt[cur ^ 1];
      int bc = sseg * 32, sw = (srow & 7) << 4;
      *reinterpret_cast<bf16x8*>(KsN + srow * 128 + (bc ^ sw)) = ka;
      *reinterpret_cast<bf16x8*>(KsN + srow * 128 + ((bc + 16) ^ sw)) = kb2;
#pragma unroll
      for (int i = 0; i < 8; ++i) {
        int d = vd0 + i;
        *((__bf16*)(VtN + d * 128 + ((vk * 2) ^ ((d & 7) << 4)))) = va[i];
        d = vd0 + 8 + i;
        *((__bf16*)(VtN + d * 128 + ((vk * 2) ^ ((d & 7) << 4)))) = vb[i];
      }
      cur ^= 1;
    }
  }

  float linv = 1.f / lsum;
#pragma unroll
  for (int r = 0; r < 4; ++r) {
    float ir = __shfl(linv, 20 * g + r);
    int row = bq + w * 16 + g * 4 + r;
#pragma unroll
    for (int dt = 0; dt < 4; ++dt)
      out[(size_t)row * kD + h * 64 + dt * 16 + lr] = (__bf16)(acc[dt][r] * ir);
  }
}

// ---------------------------------------------------------------------------
// Fused residual blend + group rotation, blocked (token-chunk, group).
// ---------------------------------------------------------------------------
__global__ __launch_bounds__(256) void blend_rot_kernel(const float* x,
                                                        const float* y,
                                                        const float* iscale,
                                                        int l,
                                                        const float* __restrict__ Rall,
                                                        float* xout) {
  int tc = blockIdx.x, gr = blockIdx.y;
  int tid = threadIdx.x;
  __shared__ float Rs[64 * 64];
  __shared__ float xb[64][65];
  float s = iscale[l];
  const float* Rg = Rall + ((size_t)l * kG + gr) * 4096;
  {
    int off = tid * 16;
#pragma unroll
    for (int q2 = 0; q2 < 4; ++q2) {
      float4 rv = *reinterpret_cast<const float4*>(Rg + off + q2 * 4);
      *reinterpret_cast<float4*>(&Rs[off + q2 * 4]) = rv;
    }
  }
  int tok = tid & 63, seg = (tid >> 6) * 16;
  {
    const float* xr = x + (size_t)(tc * 64 + tok) * kD + gr * 64 + seg;
    const float* yr = y + (size_t)(tc * 64 + tok) * kD + gr * 64 + seg;
#pragma unroll
    for (int q2 = 0; q2 < 4; ++q2) {
      float4 xv = *reinterpret_cast<const float4*>(xr + q2 * 4);
      float4 yv = *reinterpret_cast<const float4*>(yr + q2 * 4);
      xb[tok][seg + q2 * 4 + 0] = xv.x + (yv.x - xv.x) * s;
      xb[tok][seg + q2 * 4 + 1] = xv.y + (yv.y - xv.y) * s;
      xb[tok][seg + q2 * 4 + 2] = xv.z + (yv.z - xv.z) * s;
      xb[tok][seg + q2 * 4 + 3] = xv.w + (yv.w - xv.w) * s;
    }
  }
  __syncthreads();
  float o[16] = {};
  for (int i = 0; i < 64; ++i) {
    float xv = xb[tok][i];
#pragma unroll
    for (int d = 0; d < 16; ++d) o[d] += xv * Rs[i * 64 + seg + d];
  }
  float* outr = xout + (size_t)(tc * 64 + tok) * kD + gr * 64 + seg;
#pragma unroll
  for (int q2 = 0; q2 < 4; ++q2) {
    float4 ov = {o[q2 * 4 + 0], o[q2 * 4 + 1], o[q2 * 4 + 2], o[q2 * 4 + 3]};
    *reinterpret_cast<float4*>(outr + q2 * 4) = ov;
  }
}

// ---------------------------------------------------------------------------
extern "C" void kernel_launch(void* const* d_in, const int* in_sizes, int n_in,
                              void* d_out, int out_size, void* d_ws, size_t ws_size,
                              hipStream_t stream) {
  const int* tokens = (const int*)d_in[0];
  const float* embed_w = (const float*)d_in[1];
  const float* lm_head_w = (const float*)d_in[2];
  const float* norm_w = (const float*)d_in[3];
  const float* layer_gamma = (const float*)d_in[4];
  const float* layer_beta = (const float*)d_in[5];
  const float* iter_scale = (const float*)d_in[6];
  const float* skew_upper = (const float*)d_in[7];
  const float* ln1_w = (const float*)d_in[8];
  const float* ln2_w = (const float*)d_in[9];
  const float* wqkv = (const float*)d_in[10];
  const float* wo = (const float*)d_in[11];
  const float* w1 = (const float*)d_in[12];
  const float* w2 = (const float*)d_in[13];
  float* out = (float*)d_out;

  // ws: x(4MB) y(4MB) hb(2MB) ab(2MB) R(6.3MB)
  float* x = (float*)d_ws;
  float* y = x + (size_t)kT * kD;
  __bf16* hb = (__bf16*)(y + (size_t)kT * kD);
  __bf16* ab = hb + (size_t)kT * kD;
  float* R = (float*)(ab + (size_t)kT * kD);

  // d_out scratch (all dead before final lm_head GEMM writes out):
  __bf16* qkvb = (__bf16*)out;                       // 3.1M bf16
  __bf16* ffb = (__bf16*)(out + 1572864);            // 4.2M bf16
  __bf16* wqkvT = (__bf16*)(out + 3670016);          // [3072][1024]
  __bf16* woT = (__bf16*)(out + 5242880);            // [1024][1024]
  __bf16* w1T = (__bf16*)(out + 5767168);            // [4096][1024]
  __bf16* w2T = (__bf16*)(out + 7864320);            // [1024][4096]

  cayley_kernel<<<kL * kG, 256, 0, stream>>>(skew_upper, R);
  embed_kernel<<<kT * kD / 4 / 256, 256, 0, stream>>>(tokens, embed_w, x);
  convt_kernel<<<dim3(3 * kD / 64, kD / 64), 256, 0, stream>>>(wqkv, wqkvT, kD, 3 * kD);
  convt_kernel<<<dim3(kD / 64, kD / 64), 256, 0, stream>>>(wo, woT, kD, kD);
  convt_kernel<<<dim3(kFF / 64, kD / 64), 256, 0, stream>>>(w1, w1T, kD, kFF);
  convt_kernel<<<dim3(kD / 64, kFF / 64), 256, 0, stream>>>(w2, w2T, kFF, kD);

  for (int l = 0; l < kL; ++l) {
    rms_kernel<true><<<kT, 256, 0, stream>>>(x, ln1_w, layer_gamma + (size_t)l * kD,
                                             layer_beta + (size_t)l * kD, hb);
    gemm_kernel<64, 128, 3, false><<<(kT / 64) * (3 * kD / 128), 256, 0, stream>>>(
        hb, wqkvT, nullptr, qkvb, kT, 3 * kD, kD);
    fattn_kernel<<<dim3(kT / 64, kH), 256, 0, stream>>>(qkvb, ab);
    gemm_kernel<64, 64, 1, false><<<(kT / 64) * (kD / 64), 256, 0, stream>>>(
        ab, woT, x, y, kT, kD, kD);
    rms_kernel<false><<<kT, 256, 0, stream>>>(y, ln2_w, nullptr, nullptr, hb);
    gemm_kernel<64, 128, 2, false><<<(kT / 64) * (kFF / 128), 256, 0, stream>>>(
        hb, w1T, nullptr, ffb, kT, kFF, kD);
    gemm_kernel<64, 64, 1, false><<<(kT / 64) * (kD / 64), 256, 0, stream>>>(
        ffb, w2T, y, y, kT, kD, kFF);
    blend_rot_kernel<<<dim3(kT / 64, kG), 256, 0, stream>>>(x, y, iter_scale, l, R, x);
  }

  rms_kernel<false><<<kT, 256, 0, stream>>>(x, norm_w, nullptr, nullptr, hb);
  gemm_kernel<128, 128, 0, true><<<(kT / 128) * (kV / 128), 256, 0, stream>>>(
      hb, lm_head_w, nullptr, out, kT, kV, kD);
}

// Round 8
// 3216.103 us; speedup vs baseline: 1.8354x; 1.1230x over previous
//
#include <hip/hip_runtime.h>
#include <hip/hip_bf16.h>
#include <math.h>

// Model dims
constexpr int kD = 1024;
constexpr int kH = 16;
constexpr int kV = 32000;
constexpr int kT = 1024;
constexpr int kG = 16;
constexpr int kFF = 4096;
constexpr int kL = 24;
constexpr int kNTRI = 2016;
#define EPSF 1e-6f
#define L2E 1.44269504088896f

typedef __bf16 bf16x8 __attribute__((ext_vector_type(8)));
typedef __bf16 bf16x4 __attribute__((ext_vector_type(4)));
typedef float f32x4 __attribute__((ext_vector_type(4)));

#define GLOAD16(g, l)                                                   \
  __builtin_amdgcn_global_load_lds(                                     \
      (const __attribute__((address_space(1))) void*)(g),               \
      (__attribute__((address_space(3))) void*)(l), 16, 0, 0)

// ---------------------------------------------------------------------------
// Cayley transform: R = (I - A/2)^-1 (I + A/2). One block per (layer,group).
// ---------------------------------------------------------------------------
__global__ __launch_bounds__(256) void cayley_kernel(const float* __restrict__ skew,
                                                     float* __restrict__ R) {
  int lg = blockIdx.x;
  int tid = threadIdx.x;
  int r = tid & 63, q = tid >> 6;
  __shared__ float Ms[64][65];
  __shared__ float Bs[64][65];
  const float* su = skew + (size_t)lg * kNTRI;
#pragma unroll
  for (int cc = 0; cc < 16; ++cc) {
    int c = q * 16 + cc;
    float a = 0.f;
    if (r < c) a = su[r * (127 - r) / 2 + (c - r - 1)];
    else if (r > c) a = -su[c * (127 - c) / 2 + (r - c - 1)];
    Ms[r][c] = (r == c ? 1.f : 0.f) - 0.5f * a;
    Bs[r][c] = (r == c ? 1.f : 0.f) + 0.5f * a;
  }
  __syncthreads();
  for (int k = 0; k < 64; ++k) {
    float ip = 1.f / Ms[k][k];
    float f = Ms[r][k];
    float beta = (r == k) ? (1.f - ip) : (f * ip);
    float mk[16], bk[16];
#pragma unroll
    for (int cc = 0; cc < 16; ++cc) {
      mk[cc] = Ms[k][q * 16 + cc];
      bk[cc] = Bs[k][q * 16 + cc];
    }
    __syncthreads();
#pragma unroll
    for (int cc = 0; cc < 16; ++cc) {
      int c = q * 16 + cc;
      Ms[r][c] -= beta * mk[cc];
      Bs[r][c] -= beta * bk[cc];
    }
    __syncthreads();
  }
  float* Ro = R + ((size_t)lg * 64 + r) * 64;
#pragma unroll
  for (int cc = 0; cc < 16; ++cc) Ro[q * 16 + cc] = Bs[r][q * 16 + cc];
}

// ---------------------------------------------------------------------------
// Embedding gather, float4-vectorized.
// ---------------------------------------------------------------------------
__global__ __launch_bounds__(256) void embed_kernel(const int* __restrict__ tok,
                                                    const float* __restrict__ ew,
                                                    float* __restrict__ x) {
  int i = blockIdx.x * 256 + threadIdx.x;
  int t = i >> 8;
  int d4 = i & 255;
  int v = tok[t];
  reinterpret_cast<float4*>(x)[i] =
      reinterpret_cast<const float4*>(ew + (size_t)v * kD)[d4];
}

// ---------------------------------------------------------------------------
// Weight convert+transpose: W f32 [K][N] -> WT bf16 [N][K]. 64x64 tiles.
// ---------------------------------------------------------------------------
__global__ __launch_bounds__(256) void convt_kernel(const float* __restrict__ W,
                                                    __bf16* __restrict__ WT,
                                                    int K, int N) {
  __shared__ float tile[64][65];
  int t = threadIdx.x;
  int n0 = blockIdx.x * 64, k0 = blockIdx.y * 64;
#pragma unroll
  for (int r = 0; r < 4; ++r) {
    int kr = r * 16 + (t >> 4);
    int nc = (t & 15) * 4;
    float4 v = *reinterpret_cast<const float4*>(&W[(size_t)(k0 + kr) * N + n0 + nc]);
    tile[kr][nc + 0] = v.x;
    tile[kr][nc + 1] = v.y;
    tile[kr][nc + 2] = v.z;
    tile[kr][nc + 3] = v.w;
  }
  __syncthreads();
#pragma unroll
  for (int r = 0; r < 2; ++r) {
    int idx = r * 256 + t;
    int nrow = idx >> 3, kc = (idx & 7) * 8;
    bf16x8 v;
#pragma unroll
    for (int j = 0; j < 8; ++j) v[j] = (__bf16)tile[kc + j][nrow];
    *reinterpret_cast<bf16x8*>(&WT[(size_t)(n0 + nrow) * K + k0 + kc]) = v;
  }
}

// ---------------------------------------------------------------------------
// RMSNorm -> bf16 out (shuffle-based reduction, 1 barrier).
// ---------------------------------------------------------------------------
template <bool AFFINE>
__global__ __launch_bounds__(256) void rms_kernel(const float* __restrict__ x,
                                                  const float* __restrict__ w,
                                                  const float* __restrict__ gamma,
                                                  const float* __restrict__ beta,
                                                  __bf16* __restrict__ out) {
  int t = blockIdx.x, tid = threadIdx.x;
  __shared__ float red4[4];
  float4 xv = reinterpret_cast<const float4*>(x + (size_t)t * kD)[tid];
  float ss = xv.x * xv.x + xv.y * xv.y + xv.z * xv.z + xv.w * xv.w;
#pragma unroll
  for (int o = 1; o < 64; o <<= 1) ss += __shfl_xor(ss, o);
  if ((tid & 63) == 0) red4[tid >> 6] = ss;
  __syncthreads();
  float tot = red4[0] + red4[1] + red4[2] + red4[3];
  float rms = rsqrtf(tot / (float)kD + EPSF);
  float4 wv = reinterpret_cast<const float4*>(w)[tid];
  float o0 = xv.x * rms * wv.x;
  float o1 = xv.y * rms * wv.y;
  float o2 = xv.z * rms * wv.z;
  float o3 = xv.w * rms * wv.w;
  if (AFFINE) {
    float4 gv = reinterpret_cast<const float4*>(gamma)[tid];
    float4 bv = reinterpret_cast<const float4*>(beta)[tid];
    o0 = o0 * gv.x + bv.x;
    o1 = o1 * gv.y + bv.y;
    o2 = o2 * gv.z + bv.z;
    o3 = o3 * gv.w + bv.w;
  }
  bf16x4 ov;
  ov[0] = (__bf16)o0; ov[1] = (__bf16)o1; ov[2] = (__bf16)o2; ov[3] = (__bf16)o3;
  *reinterpret_cast<bf16x4*>(out + (size_t)t * kD + tid * 4) = ov;
}

// ---------------------------------------------------------------------------
// MFMA GEMM, m97 structure + rule-21 swizzle: global_load_lds width=16 with
// PRE-SWIZZLED per-lane global source (granule (l&7)^(l>>3), coalesced:
// permutation within each 128B row), linear LDS dest, XOR-swizzled ds_read
// (slot uniformity 8 lanes/slot -> conflict-free b128). BK=64, 2-barrier
// K-loop, 256 thd = 4 waves 2x2. 1D grid, XCD-chunked swizzle (grid %8==0).
// BF32: B f32 [N][K], reg-staged converted with both-sides swizzle (lm_head).
// EPI: 0=f32, 1=f32 acc+res, 2=gelu->bf16, 3=bf16.
// ---------------------------------------------------------------------------
template <int BM, int BN, int EPI, bool BF32>
__global__ __launch_bounds__(256) void gemm_kernel(
    const __bf16* __restrict__ A, const void* __restrict__ Bv,
    const float* res, void* __restrict__ Cv, int M, int N, int K) {
  constexpr int AISS = BM / 32;  // gload issues per wave (A)
  constexpr int BISS = BN / 32;
  constexpr int FM = BM / 32;    // frags per wave (2x2 wave grid)
  constexpr int FN = BN / 32;
  __shared__ __bf16 As[BM * 64];
  __shared__ __bf16 Bs[BN * 64];
  char* AsB = (char*)As;
  char* BsB = (char*)Bs;
  int tid = threadIdx.x;
  int w = tid >> 6, lane = tid & 63;
  int mt = M / BM;
  int cpx = gridDim.x >> 3;
  int id = (blockIdx.x & 7) * cpx + (blockIdx.x >> 3);
  int bm = (id % mt) * BM, bn = (id / mt) * BN;
  int lrow = lane & 15, g = lane >> 4;
  int grow = lane >> 3;                       // staging: row within 8-row slab
  int gswz = ((lane & 7) ^ grow) * 8;         // pre-swizzled source col (elems)
  int rsw = (lrow & 7) << 4;                  // read-side XOR (bytes)
  int wr = (w >> 1) * (BM / 2), wc = (w & 1) * (BN / 2);
  f32x4 acc[FM][FN] = {};
  const __bf16* B16 = (const __bf16*)Bv;
  const float* B32 = (const float*)Bv;

  for (int k0 = 0; k0 < K; k0 += 64) {
#pragma unroll
    for (int i = 0; i < AISS; ++i) {
      int rbase = (i * 4 + w) * 8;
      GLOAD16(&A[(size_t)(bm + rbase + grow) * K + k0 + gswz], &As[rbase * 64]);
    }
    if (!BF32) {
#pragma unroll
      for (int i = 0; i < BISS; ++i) {
        int rbase = (i * 4 + w) * 8;
        GLOAD16(&B16[(size_t)(bn + rbase + grow) * K + k0 + gswz], &Bs[rbase * 64]);
      }
    } else {
#pragma unroll
      for (int rrep = 0; rrep < BN / 32; ++rrep) {
        int cid = rrep * 256 + tid;
        int row = cid >> 3, kc = (cid & 7) * 8;
        const float* src = &B32[(size_t)(bn + row) * K + k0 + kc];
        float4 f0 = *reinterpret_cast<const float4*>(src);
        float4 f1 = *reinterpret_cast<const float4*>(src + 4);
        bf16x8 v;
        v[0] = (__bf16)f0.x; v[1] = (__bf16)f0.y;
        v[2] = (__bf16)f0.z; v[3] = (__bf16)f0.w;
        v[4] = (__bf16)f1.x; v[5] = (__bf16)f1.y;
        v[6] = (__bf16)f1.z; v[7] = (__bf16)f1.w;
        int swc = ((cid & 7) ^ (row & 7)) * 16;  // both-sides swizzle
        *reinterpret_cast<bf16x8*>(BsB + row * 128 + swc) = v;
      }
    }
    __syncthreads();
#pragma unroll
    for (int ks = 0; ks < 2; ++ks) {
      bf16x8 af[FM], bg[FN];
#pragma unroll
      for (int i = 0; i < FM; ++i)
        af[i] = *reinterpret_cast<const bf16x8*>(
            AsB + (wr + i * 16 + lrow) * 128 + ((ks * 64 + g * 16) ^ rsw));
#pragma unroll
      for (int j = 0; j < FN; ++j)
        bg[j] = *reinterpret_cast<const bf16x8*>(
            BsB + (wc + j * 16 + lrow) * 128 + ((ks * 64 + g * 16) ^ rsw));
#pragma unroll
      for (int i = 0; i < FM; ++i)
#pragma unroll
        for (int j = 0; j < FN; ++j)
          acc[i][j] = __builtin_amdgcn_mfma_f32_16x16x32_bf16(af[i], bg[j],
                                                              acc[i][j], 0, 0, 0);
    }
    __syncthreads();
  }

  int crow0 = bm + wr + g * 4;
  int ccol0 = bn + wc + lrow;
#pragma unroll
  for (int i = 0; i < FM; ++i) {
#pragma unroll
    for (int j = 0; j < FN; ++j) {
#pragma unroll
      for (int r = 0; r < 4; ++r) {
        int row = crow0 + i * 16 + r;
        int col = ccol0 + j * 16;
        size_t idx = (size_t)row * N + col;
        float v = acc[i][j][r];
        if (EPI == 1) v += res[idx];
        if (EPI == 2) {
          float u = v;
          float z = 0.7978845608028654f * (u + 0.044715f * u * u * u);
          float ez = exp2f(z * (2.f * L2E));
          v = u * ez / (1.f + ez);
        }
        if (EPI == 2 || EPI == 3) ((__bf16*)Cv)[idx] = (__bf16)v;
        else ((float*)Cv)[idx] = v;
      }
    }
  }
}

// ---------------------------------------------------------------------------
// Flash attention (causal), bf16 MFMA, swapped QK^T, per-lane online softmax,
// K/V double-buffered with issue-early / write-late staging.
// ---------------------------------------------------------------------------
__global__ __launch_bounds__(256) void fattn_kernel(const __bf16* __restrict__ qkv,
                                                    __bf16* __restrict__ out) {
  __shared__ __bf16 Ks[2][64 * 64];
  __shared__ __bf16 Vt[2][64 * 64];
  __shared__ __bf16 Ps[4 * 16 * 64];
  int tid = threadIdx.x;
  int bq = blockIdx.x * 64;
  int h = blockIdx.y;
  int w = tid >> 6, lane = tid & 63;
  int g = lane >> 4, lr = lane & 15;

  bf16x8 qf[2];
  const __bf16* qbase = qkv + (size_t)(bq + w * 16 + lr) * (3 * kD) + h * 64;
#pragma unroll
  for (int ks = 0; ks < 2; ++ks) {
    bf16x8 v = *reinterpret_cast<const bf16x8*>(qbase + ks * 32 + g * 8);
#pragma unroll
    for (int j = 0; j < 8; ++j) qf[ks][j] = (__bf16)((float)v[j] * 0.125f);
  }

  f32x4 acc[4] = {};
  float m = -1e30f, lsum = 0.f;

  int srow = tid >> 2, sseg = tid & 3;
  int vk = tid & 63, vd0 = (tid >> 6) * 16;
  char* PwB = (char*)(Ps + w * (16 * 64));
  int psw = (lr & 7) << 4;

  bf16x8 ka, kb2, va, vb;
  int ntiles = bq / 64 + 1;

  {
    const __bf16* src = qkv + (size_t)(srow) * (3 * kD) + kD + h * 64 + sseg * 16;
    ka = *reinterpret_cast<const bf16x8*>(src);
    kb2 = *reinterpret_cast<const bf16x8*>(src + 8);
    const __bf16* vsrc = qkv + (size_t)(vk) * (3 * kD) + 2 * kD + h * 64 + vd0;
    va = *reinterpret_cast<const bf16x8*>(vsrc);
    vb = *reinterpret_cast<const bf16x8*>(vsrc + 8);
    char* KsB = (char*)Ks[0];
    char* VtB = (char*)Vt[0];
    int bc = sseg * 32, sw = (srow & 7) << 4;
    *reinterpret_cast<bf16x8*>(KsB + srow * 128 + (bc ^ sw)) = ka;
    *reinterpret_cast<bf16x8*>(KsB + srow * 128 + ((bc + 16) ^ sw)) = kb2;
#pragma unroll
    for (int i = 0; i < 8; ++i) {
      int d = vd0 + i;
      *((__bf16*)(VtB + d * 128 + ((vk * 2) ^ ((d & 7) << 4)))) = va[i];
      d = vd0 + 8 + i;
      *((__bf16*)(VtB + d * 128 + ((vk * 2) ^ ((d & 7) << 4)))) = vb[i];
    }
  }

  int cur = 0;
  for (int kt = 0; kt < ntiles; ++kt) {
    if (kt + 1 < ntiles) {
      const __bf16* src =
          qkv + (size_t)((kt + 1) * 64 + srow) * (3 * kD) + kD + h * 64 + sseg * 16;
      ka = *reinterpret_cast<const bf16x8*>(src);
      kb2 = *reinterpret_cast<const bf16x8*>(src + 8);
      const __bf16* vsrc =
          qkv + (size_t)((kt + 1) * 64 + vk) * (3 * kD) + 2 * kD + h * 64 + vd0;
      va = *reinterpret_cast<const bf16x8*>(vsrc);
      vb = *reinterpret_cast<const bf16x8*>(vsrc + 8);
    }
    __syncthreads();

    char* KsB = (char*)Ks[cur];
    char* VtB = (char*)Vt[cur];
    bool diag = (kt == ntiles - 1);
    int jmax = diag ? w : 3;

    f32x4 s[4];
#pragma unroll
    for (int jj = 0; jj < 4; ++jj) {
      if (jj <= jmax) {
        int krow = jj * 16 + lr;
        int ksw = (lr & 7) << 4;
        bf16x8 k0 = *reinterpret_cast<const bf16x8*>(KsB + krow * 128 + ((g * 16) ^ ksw));
        bf16x8 k1 = *reinterpret_cast<const bf16x8*>(KsB + krow * 128 + ((64 + g * 16) ^ ksw));
        f32x4 z = {};
        z = __builtin_amdgcn_mfma_f32_16x16x32_bf16(k0, qf[0], z, 0, 0, 0);
        s[jj] = __builtin_amdgcn_mfma_f32_16x16x32_bf16(k1, qf[1], z, 0, 0, 0);
      } else {
        s[jj] = f32x4{-1e30f, -1e30f, -1e30f, -1e30f};
      }
    }
    if (diag) {
#pragma unroll
      for (int r = 0; r < 4; ++r)
        if (g * 4 + r > lr) s[w][r] = -1e30f;
    }

    float mt = -1e30f;
#pragma unroll
    for (int jj = 0; jj < 4; ++jj)
#pragma unroll
      for (int r = 0; r < 4; ++r) mt = fmaxf(mt, s[jj][r]);
    mt = fmaxf(mt, __shfl_xor(mt, 16));
    mt = fmaxf(mt, __shfl_xor(mt, 32));
    float mn = fmaxf(m, mt);
    float sc = exp2f((m - mn) * L2E);
    float p[4][4];
    float rs = 0.f;
#pragma unroll
    for (int jj = 0; jj < 4; ++jj)
#pragma unroll
      for (int r = 0; r < 4; ++r) {
        float e = exp2f((s[jj][r] - mn) * L2E);
        p[jj][r] = e;
        rs += e;
      }
    rs += __shfl_xor(rs, 16);
    rs += __shfl_xor(rs, 32);
    lsum = lsum * sc + rs;
    m = mn;
#pragma unroll
    for (int r = 0; r < 4; ++r) {
      float s4 = __shfl(sc, 20 * g + r);
#pragma unroll
      for (int dt = 0; dt < 4; ++dt) acc[dt][r] *= s4;
    }

#pragma unroll
    for (int jj = 0; jj < 4; ++jj) {
      bf16x4 pv;
#pragma unroll
      for (int r = 0; r < 4; ++r) pv[r] = (__bf16)p[jj][r];
      *reinterpret_cast<bf16x4*>(PwB + lr * 128 + ((jj * 32 + g * 8) ^ psw)) = pv;
    }

    {
      bf16x8 pa0 = *reinterpret_cast<const bf16x8*>(PwB + lr * 128 + ((g * 16) ^ psw));
      bf16x8 pa1 = *reinterpret_cast<const bf16x8*>(PwB + lr * 128 + ((64 + g * 16) ^ psw));
#pragma unroll
      for (int dt = 0; dt < 4; ++dt) {
        int vrow = dt * 16 + lr;
        int vsw = (lr & 7) << 4;
        bf16x8 vb0 = *reinterpret_cast<const bf16x8*>(VtB + vrow * 128 + ((g * 16) ^ vsw));
        bf16x8 vb1 = *reinterpret_cast<const bf16x8*>(VtB + vrow * 128 + ((64 + g * 16) ^ vsw));
        acc[dt] = __builtin_amdgcn_mfma_f32_16x16x32_bf16(pa0, vb0, acc[dt], 0, 0, 0);
        acc[dt] = __builtin_amdgcn_mfma_f32_16x16x32_bf16(pa1, vb1, acc[dt], 0, 0, 0);
      }
    }
    __syncthreads();

    if (kt + 1 < ntiles) {
      char* KsN = (char*)Ks[cur ^ 1];
      char* VtN = (char*)Vt[cur ^ 1];
      int bc = sseg * 32, sw = (srow & 7) << 4;
      *reinterpret_cast<bf16x8*>(KsN + srow * 128 + (bc ^ sw)) = ka;
      *reinterpret_cast<bf16x8*>(KsN + srow * 128 + ((bc + 16) ^ sw)) = kb2;
#pragma unroll
      for (int i = 0; i < 8; ++i) {
        int d = vd0 + i;
        *((__bf16*)(VtN + d * 128 + ((vk * 2) ^ ((d & 7) << 4)))) = va[i];
        d = vd0 + 8 + i;
        *((__bf16*)(VtN + d * 128 + ((vk * 2) ^ ((d & 7) << 4)))) = vb[i];
      }
      cur ^= 1;
    }
  }

  float linv = 1.f / lsum;
#pragma unroll
  for (int r = 0; r < 4; ++r) {
    float ir = __shfl(linv, 20 * g + r);
    int row = bq + w * 16 + g * 4 + r;
#pragma unroll
    for (int dt = 0; dt < 4; ++dt)
      out[(size_t)row * kD + h * 64 + dt * 16 + lr] = (__bf16)(acc[dt][r] * ir);
  }
}

// ---------------------------------------------------------------------------
// Fused residual blend + group rotation, blocked (token-chunk, group).
// ---------------------------------------------------------------------------
__global__ __launch_bounds__(256) void blend_rot_kernel(const float* x,
                                                        const float* y,
                                                        const float* iscale,
                                                        int l,
                                                        const float* __restrict__ Rall,
                                                        float* xout) {
  int tc = blockIdx.x, gr = blockIdx.y;
  int tid = threadIdx.x;
  __shared__ float Rs[64 * 64];
  __shared__ float xb[64][65];
  float s = iscale[l];
  const float* Rg = Rall + ((size_t)l * kG + gr) * 4096;
  {
    int off = tid * 16;
#pragma unroll
    for (int q2 = 0; q2 < 4; ++q2) {
      float4 rv = *reinterpret_cast<const float4*>(Rg + off + q2 * 4);
      *reinterpret_cast<float4*>(&Rs[off + q2 * 4]) = rv;
    }
  }
  int tok = tid & 63, seg = (tid >> 6) * 16;
  {
    const float* xr = x + (size_t)(tc * 64 + tok) * kD + gr * 64 + seg;
    const float* yr = y + (size_t)(tc * 64 + tok) * kD + gr * 64 + seg;
#pragma unroll
    for (int q2 = 0; q2 < 4; ++q2) {
      float4 xv = *reinterpret_cast<const float4*>(xr + q2 * 4);
      float4 yv = *reinterpret_cast<const float4*>(yr + q2 * 4);
      xb[tok][seg + q2 * 4 + 0] = xv.x + (yv.x - xv.x) * s;
      xb[tok][seg + q2 * 4 + 1] = xv.y + (yv.y - xv.y) * s;
      xb[tok][seg + q2 * 4 + 2] = xv.z + (yv.z - xv.z) * s;
      xb[tok][seg + q2 * 4 + 3] = xv.w + (yv.w - xv.w) * s;
    }
  }
  __syncthreads();
  float o[16] = {};
  for (int i = 0; i < 64; ++i) {
    float xv = xb[tok][i];
#pragma unroll
    for (int d = 0; d < 16; ++d) o[d] += xv * Rs[i * 64 + seg + d];
  }
  float* outr = xout + (size_t)(tc * 64 + tok) * kD + gr * 64 + seg;
#pragma unroll
  for (int q2 = 0; q2 < 4; ++q2) {
    float4 ov = {o[q2 * 4 + 0], o[q2 * 4 + 1], o[q2 * 4 + 2], o[q2 * 4 + 3]};
    *reinterpret_cast<float4*>(outr + q2 * 4) = ov;
  }
}

// ---------------------------------------------------------------------------
extern "C" void kernel_launch(void* const* d_in, const int* in_sizes, int n_in,
                              void* d_out, int out_size, void* d_ws, size_t ws_size,
                              hipStream_t stream) {
  const int* tokens = (const int*)d_in[0];
  const float* embed_w = (const float*)d_in[1];
  const float* lm_head_w = (const float*)d_in[2];
  const float* norm_w = (const float*)d_in[3];
  const float* layer_gamma = (const float*)d_in[4];
  const float* layer_beta = (const float*)d_in[5];
  const float* iter_scale = (const float*)d_in[6];
  const float* skew_upper = (const float*)d_in[7];
  const float* ln1_w = (const float*)d_in[8];
  const float* ln2_w = (const float*)d_in[9];
  const float* wqkv = (const float*)d_in[10];
  const float* wo = (const float*)d_in[11];
  const float* w1 = (const float*)d_in[12];
  const float* w2 = (const float*)d_in[13];
  float* out = (float*)d_out;

  // ws: x(4MB) y(4MB) hb(2MB) ab(2MB) R(6.3MB)
  float* x = (float*)d_ws;
  float* y = x + (size_t)kT * kD;
  __bf16* hb = (__bf16*)(y + (size_t)kT * kD);
  __bf16* ab = hb + (size_t)kT * kD;
  float* R = (float*)(ab + (size_t)kT * kD);

  // d_out scratch (all dead before final lm_head GEMM writes out):
  __bf16* qkvb = (__bf16*)out;                       // 3.1M bf16
  __bf16* ffb = (__bf16*)(out + 1572864);            // 4.2M bf16
  __bf16* wqkvT = (__bf16*)(out + 3670016);          // [3072][1024]
  __bf16* woT = (__bf16*)(out + 5242880);            // [1024][1024]
  __bf16* w1T = (__bf16*)(out + 5767168);            // [4096][1024]
  __bf16* w2T = (__bf16*)(out + 7864320);            // [1024][4096]

  cayley_kernel<<<kL * kG, 256, 0, stream>>>(skew_upper, R);
  embed_kernel<<<kT * kD / 4 / 256, 256, 0, stream>>>(tokens, embed_w, x);
  convt_kernel<<<dim3(3 * kD / 64, kD / 64), 256, 0, stream>>>(wqkv, wqkvT, kD, 3 * kD);
  convt_kernel<<<dim3(kD / 64, kD / 64), 256, 0, stream>>>(wo, woT, kD, kD);
  convt_kernel<<<dim3(kFF / 64, kD / 64), 256, 0, stream>>>(w1, w1T, kD, kFF);
  convt_kernel<<<dim3(kD / 64, kFF / 64), 256, 0, stream>>>(w2, w2T, kFF, kD);

  for (int l = 0; l < kL; ++l) {
    rms_kernel<true><<<kT, 256, 0, stream>>>(x, ln1_w, layer_gamma + (size_t)l * kD,
                                             layer_beta + (size_t)l * kD, hb);
    gemm_kernel<64, 128, 3, false><<<(kT / 64) * (3 * kD / 128), 256, 0, stream>>>(
        hb, wqkvT, nullptr, qkvb, kT, 3 * kD, kD);
    fattn_kernel<<<dim3(kT / 64, kH), 256, 0, stream>>>(qkvb, ab);
    gemm_kernel<64, 64, 1, false><<<(kT / 64) * (kD / 64), 256, 0, stream>>>(
        ab, woT, x, y, kT, kD, kD);
    rms_kernel<false><<<kT, 256, 0, stream>>>(y, ln2_w, nullptr, nullptr, hb);
    gemm_kernel<64, 128, 2, false><<<(kT / 64) * (kFF / 128), 256, 0, stream>>>(
        hb, w1T, nullptr, ffb, kT, kFF, kD);
    gemm_kernel<64, 64, 1, false><<<(kT / 64) * (kD / 64), 256, 0, stream>>>(
        ffb, w2T, y, y, kT, kD, kFF);
    blend_rot_kernel<<<dim3(kT / 64, kG), 256, 0, stream>>>(x, y, iter_scale, l, R, x);
  }

  rms_kernel<false><<<kT, 256, 0, stream>>>(x, norm_w, nullptr, nullptr, hb);
  gemm_kernel<128, 128, 0, true><<<(kT / 128) * (kV / 128), 256, 0, stream>>>(
      hb, lm_head_w, nullptr, out, kT, kV, kD);
}

// Round 10
// 3087.691 us; speedup vs baseline: 1.9117x; 1.0416x over previous
//
#include <hip/hip_runtime.h>
#include <hip/hip_bf16.h>
#include <math.h>

// Model dims
constexpr int kD = 1024;
constexpr int kH = 16;
constexpr int kV = 32000;
constexpr int kT = 1024;
constexpr int kG = 16;
constexpr int kFF = 4096;
constexpr int kL = 24;
constexpr int kNTRI = 2016;
#define EPSF 1e-6f
#define L2E 1.44269504088896f

typedef __bf16 bf16x8 __attribute__((ext_vector_type(8)));
typedef __bf16 bf16x4 __attribute__((ext_vector_type(4)));
typedef float f32x4 __attribute__((ext_vector_type(4)));

#define GLOAD16(g, l)                                                   \
  __builtin_amdgcn_global_load_lds(                                     \
      (const __attribute__((address_space(1))) void*)(g),               \
      (__attribute__((address_space(3))) void*)(l), 16, 0, 0)

// ---------------------------------------------------------------------------
// Cayley transform: R = (I - A/2)^-1 (I + A/2). One block per (layer,group).
// ---------------------------------------------------------------------------
__global__ __launch_bounds__(256) void cayley_kernel(const float* __restrict__ skew,
                                                     float* __restrict__ R) {
  int lg = blockIdx.x;
  int tid = threadIdx.x;
  int r = tid & 63, q = tid >> 6;
  __shared__ float Ms[64][65];
  __shared__ float Bs[64][65];
  const float* su = skew + (size_t)lg * kNTRI;
#pragma unroll
  for (int cc = 0; cc < 16; ++cc) {
    int c = q * 16 + cc;
    float a = 0.f;
    if (r < c) a = su[r * (127 - r) / 2 + (c - r - 1)];
    else if (r > c) a = -su[c * (127 - c) / 2 + (r - c - 1)];
    Ms[r][c] = (r == c ? 1.f : 0.f) - 0.5f * a;
    Bs[r][c] = (r == c ? 1.f : 0.f) + 0.5f * a;
  }
  __syncthreads();
  for (int k = 0; k < 64; ++k) {
    float ip = 1.f / Ms[k][k];
    float f = Ms[r][k];
    float beta = (r == k) ? (1.f - ip) : (f * ip);
    float mk[16], bk[16];
#pragma unroll
    for (int cc = 0; cc < 16; ++cc) {
      mk[cc] = Ms[k][q * 16 + cc];
      bk[cc] = Bs[k][q * 16 + cc];
    }
    __syncthreads();
#pragma unroll
    for (int cc = 0; cc < 16; ++cc) {
      int c = q * 16 + cc;
      Ms[r][c] -= beta * mk[cc];
      Bs[r][c] -= beta * bk[cc];
    }
    __syncthreads();
  }
  float* Ro = R + ((size_t)lg * 64 + r) * 64;
#pragma unroll
  for (int cc = 0; cc < 16; ++cc) Ro[q * 16 + cc] = Bs[r][q * 16 + cc];
}

// ---------------------------------------------------------------------------
// Embedding gather, float4-vectorized.
// ---------------------------------------------------------------------------
__global__ __launch_bounds__(256) void embed_kernel(const int* __restrict__ tok,
                                                    const float* __restrict__ ew,
                                                    float* __restrict__ x) {
  int i = blockIdx.x * 256 + threadIdx.x;
  int t = i >> 8;
  int d4 = i & 255;
  int v = tok[t];
  reinterpret_cast<float4*>(x)[i] =
      reinterpret_cast<const float4*>(ew + (size_t)v * kD)[d4];
}

// ---------------------------------------------------------------------------
// Elementwise f32 -> bf16 cast (lm_head), 8 elems/thread.
// ---------------------------------------------------------------------------
__global__ __launch_bounds__(256) void cast_kernel(const float* __restrict__ W,
                                                   __bf16* __restrict__ O) {
  size_t i = ((size_t)blockIdx.x * 256 + threadIdx.x) * 8;
  float4 f0 = *reinterpret_cast<const float4*>(W + i);
  float4 f1 = *reinterpret_cast<const float4*>(W + i + 4);
  bf16x8 v;
  v[0] = (__bf16)f0.x; v[1] = (__bf16)f0.y;
  v[2] = (__bf16)f0.z; v[3] = (__bf16)f0.w;
  v[4] = (__bf16)f1.x; v[5] = (__bf16)f1.y;
  v[6] = (__bf16)f1.z; v[7] = (__bf16)f1.w;
  *reinterpret_cast<bf16x8*>(O + i) = v;
}

// ---------------------------------------------------------------------------
// Weight convert+transpose: W f32 [K][N] -> WT bf16 [N][K]. 64x64 tiles.
// ---------------------------------------------------------------------------
__global__ __launch_bounds__(256) void convt_kernel(const float* __restrict__ W,
                                                    __bf16* __restrict__ WT,
                                                    int K, int N) {
  __shared__ float tile[64][65];
  int t = threadIdx.x;
  int n0 = blockIdx.x * 64, k0 = blockIdx.y * 64;
#pragma unroll
  for (int r = 0; r < 4; ++r) {
    int kr = r * 16 + (t >> 4);
    int nc = (t & 15) * 4;
    float4 v = *reinterpret_cast<const float4*>(&W[(size_t)(k0 + kr) * N + n0 + nc]);
    tile[kr][nc + 0] = v.x;
    tile[kr][nc + 1] = v.y;
    tile[kr][nc + 2] = v.z;
    tile[kr][nc + 3] = v.w;
  }
  __syncthreads();
#pragma unroll
  for (int r = 0; r < 2; ++r) {
    int idx = r * 256 + t;
    int nrow = idx >> 3, kc = (idx & 7) * 8;
    bf16x8 v;
#pragma unroll
    for (int j = 0; j < 8; ++j) v[j] = (__bf16)tile[kc + j][nrow];
    *reinterpret_cast<bf16x8*>(&WT[(size_t)(n0 + nrow) * K + k0 + kc]) = v;
  }
}

// ---------------------------------------------------------------------------
// RMSNorm -> bf16 out (shuffle-based reduction, 1 barrier).
// ---------------------------------------------------------------------------
template <bool AFFINE>
__global__ __launch_bounds__(256) void rms_kernel(const float* __restrict__ x,
                                                  const float* __restrict__ w,
                                                  const float* __restrict__ gamma,
                                                  const float* __restrict__ beta,
                                                  __bf16* __restrict__ out) {
  int t = blockIdx.x, tid = threadIdx.x;
  __shared__ float red4[4];
  float4 xv = reinterpret_cast<const float4*>(x + (size_t)t * kD)[tid];
  float ss = xv.x * xv.x + xv.y * xv.y + xv.z * xv.z + xv.w * xv.w;
#pragma unroll
  for (int o = 1; o < 64; o <<= 1) ss += __shfl_xor(ss, o);
  if ((tid & 63) == 0) red4[tid >> 6] = ss;
  __syncthreads();
  float tot = red4[0] + red4[1] + red4[2] + red4[3];
  float rms = rsqrtf(tot / (float)kD + EPSF);
  float4 wv = reinterpret_cast<const float4*>(w)[tid];
  float o0 = xv.x * rms * wv.x;
  float o1 = xv.y * rms * wv.y;
  float o2 = xv.z * rms * wv.z;
  float o3 = xv.w * rms * wv.w;
  if (AFFINE) {
    float4 gv = reinterpret_cast<const float4*>(gamma)[tid];
    float4 bv = reinterpret_cast<const float4*>(beta)[tid];
    o0 = o0 * gv.x + bv.x;
    o1 = o1 * gv.y + bv.y;
    o2 = o2 * gv.z + bv.z;
    o3 = o3 * gv.w + bv.w;
  }
  bf16x4 ov;
  ov[0] = (__bf16)o0; ov[1] = (__bf16)o1; ov[2] = (__bf16)o2; ov[3] = (__bf16)o3;
  *reinterpret_cast<bf16x4*>(out + (size_t)t * kD + tid * 4) = ov;
}

// ---------------------------------------------------------------------------
// MFMA GEMM, m97 structure + rule-21 swizzle, NW waves (4 -> 2x2 wave grid,
// 8 -> 2x4). global_load_lds width=16 with pre-swizzled global source,
// linear LDS dest, XOR-swizzled ds_read. BK=64, 2-barrier K-loop.
// 1D grid, XCD-chunked swizzle (grid %8 == 0).
// BF32: B f32 [N][K], reg-staged converted, both-sides swizzle (head
// fallback when ws too small for the bf16 pre-cast copy).
// EPI: 0=f32, 1=f32 acc+res, 2=gelu->bf16, 3=bf16.
// ---------------------------------------------------------------------------
template <int BM, int BN, int NW, int EPI, bool BF32>
__global__ __launch_bounds__(NW * 64) void gemm_kernel(
    const __bf16* __restrict__ A, const void* __restrict__ Bv,
    const float* res, void* __restrict__ Cv, int M, int N, int K) {
  constexpr int WCOLS = (NW == 4) ? 2 : 4;
  constexpr int FM = (BM / 2) / 16;
  constexpr int FN = (BN / WCOLS) / 16;
  constexpr int AISS = BM / 8 / NW;
  constexpr int BISS = BN / 8 / NW;
  __shared__ __bf16 As[BM * 64];
  __shared__ __bf16 Bs[BN * 64];
  char* AsB = (char*)As;
  char* BsB = (char*)Bs;
  int tid = threadIdx.x;
  int w = tid >> 6, lane = tid & 63;
  int mt = M / BM;
  int cpx = gridDim.x >> 3;
  int id = (blockIdx.x & 7) * cpx + (blockIdx.x >> 3);
  int bm = (id % mt) * BM, bn = (id / mt) * BN;
  int lrow = lane & 15, g = lane >> 4;
  int grow = lane >> 3;                       // staging: row within 8-row slab
  int gswz = ((lane & 7) ^ grow) * 8;         // pre-swizzled source col (elems)
  int rsw = (lrow & 7) << 4;                  // read-side XOR (bytes)
  int wm = (NW == 4) ? (w >> 1) : (w >> 2);
  int wn = (NW == 4) ? (w & 1) : (w & 3);
  int wr = wm * (BM / 2), wc = wn * (BN / WCOLS);
  f32x4 acc[FM][FN] = {};
  const __bf16* B16 = (const __bf16*)Bv;
  const float* B32 = (const float*)Bv;

  for (int k0 = 0; k0 < K; k0 += 64) {
#pragma unroll
    for (int i = 0; i < AISS; ++i) {
      int rbase = (i * NW + w) * 8;
      GLOAD16(&A[(size_t)(bm + rbase + grow) * K + k0 + gswz], &As[rbase * 64]);
    }
    if (!BF32) {
#pragma unroll
      for (int i = 0; i < BISS; ++i) {
        int rbase = (i * NW + w) * 8;
        GLOAD16(&B16[(size_t)(bn + rbase + grow) * K + k0 + gswz], &Bs[rbase * 64]);
      }
    } else {
#pragma unroll
      for (int rrep = 0; rrep < BN * 8 / (NW * 64); ++rrep) {
        int cid = rrep * NW * 64 + tid;
        int row = cid >> 3, kc = (cid & 7) * 8;
        const float* src = &B32[(size_t)(bn + row) * K + k0 + kc];
        float4 f0 = *reinterpret_cast<const float4*>(src);
        float4 f1 = *reinterpret_cast<const float4*>(src + 4);
        bf16x8 v;
        v[0] = (__bf16)f0.x; v[1] = (__bf16)f0.y;
        v[2] = (__bf16)f0.z; v[3] = (__bf16)f0.w;
        v[4] = (__bf16)f1.x; v[5] = (__bf16)f1.y;
        v[6] = (__bf16)f1.z; v[7] = (__bf16)f1.w;
        int swc = ((cid & 7) ^ (row & 7)) * 16;  // both-sides swizzle
        *reinterpret_cast<bf16x8*>(BsB + row * 128 + swc) = v;
      }
    }
    __syncthreads();
#pragma unroll
    for (int ks = 0; ks < 2; ++ks) {
      bf16x8 af[FM], bg[FN];
#pragma unroll
      for (int i = 0; i < FM; ++i)
        af[i] = *reinterpret_cast<const bf16x8*>(
            AsB + (wr + i * 16 + lrow) * 128 + ((ks * 64 + g * 16) ^ rsw));
#pragma unroll
      for (int j = 0; j < FN; ++j)
        bg[j] = *reinterpret_cast<const bf16x8*>(
            BsB + (wc + j * 16 + lrow) * 128 + ((ks * 64 + g * 16) ^ rsw));
#pragma unroll
      for (int i = 0; i < FM; ++i)
#pragma unroll
        for (int j = 0; j < FN; ++j)
          acc[i][j] = __builtin_amdgcn_mfma_f32_16x16x32_bf16(af[i], bg[j],
                                                              acc[i][j], 0, 0, 0);
    }
    __syncthreads();
  }

  int crow0 = bm + wr + g * 4;
  int ccol0 = bn + wc + lrow;
#pragma unroll
  for (int i = 0; i < FM; ++i) {
#pragma unroll
    for (int j = 0; j < FN; ++j) {
#pragma unroll
      for (int r = 0; r < 4; ++r) {
        int row = crow0 + i * 16 + r;
        int col = ccol0 + j * 16;
        size_t idx = (size_t)row * N + col;
        float v = acc[i][j][r];
        if (EPI == 1) v += res[idx];
        if (EPI == 2) {
          float u = v;
          float z = 0.7978845608028654f * (u + 0.044715f * u * u * u);
          float ez = exp2f(z * (2.f * L2E));
          v = u * ez / (1.f + ez);
        }
        if (EPI == 2 || EPI == 3) ((__bf16*)Cv)[idx] = (__bf16)v;
        else ((float*)Cv)[idx] = v;
      }
    }
  }
}

// ---------------------------------------------------------------------------
// Flash attention (causal), bf16 MFMA, swapped QK^T, per-lane online softmax,
// K/V double-buffered with issue-early / write-late staging.
// ---------------------------------------------------------------------------
__global__ __launch_bounds__(256) void fattn_kernel(const __bf16* __restrict__ qkv,
                                                    __bf16* __restrict__ out) {
  __shared__ __bf16 Ks[2][64 * 64];
  __shared__ __bf16 Vt[2][64 * 64];
  __shared__ __bf16 Ps[4 * 16 * 64];
  int tid = threadIdx.x;
  int bq = blockIdx.x * 64;
  int h = blockIdx.y;
  int w = tid >> 6, lane = tid & 63;
  int g = lane >> 4, lr = lane & 15;

  bf16x8 qf[2];
  const __bf16* qbase = qkv + (size_t)(bq + w * 16 + lr) * (3 * kD) + h * 64;
#pragma unroll
  for (int ks = 0; ks < 2; ++ks) {
    bf16x8 v = *reinterpret_cast<const bf16x8*>(qbase + ks * 32 + g * 8);
#pragma unroll
    for (int j = 0; j < 8; ++j) qf[ks][j] = (__bf16)((float)v[j] * 0.125f);
  }

  f32x4 acc[4] = {};
  float m = -1e30f, lsum = 0.f;

  int srow = tid >> 2, sseg = tid & 3;
  int vk = tid & 63, vd0 = (tid >> 6) * 16;
  char* PwB = (char*)(Ps + w * (16 * 64));
  int psw = (lr & 7) << 4;

  bf16x8 ka, kb2, va, vb;
  int ntiles = bq / 64 + 1;

  {
    const __bf16* src = qkv + (size_t)(srow) * (3 * kD) + kD + h * 64 + sseg * 16;
    ka = *reinterpret_cast<const bf16x8*>(src);
    kb2 = *reinterpret_cast<const bf16x8*>(src + 8);
    const __bf16* vsrc = qkv + (size_t)(vk) * (3 * kD) + 2 * kD + h * 64 + vd0;
    va = *reinterpret_cast<const bf16x8*>(vsrc);
    vb = *reinterpret_cast<const bf16x8*>(vsrc + 8);
    char* KsB = (char*)Ks[0];
    char* VtB = (char*)Vt[0];
    int bc = sseg * 32, sw = (srow & 7) << 4;
    *reinterpret_cast<bf16x8*>(KsB + srow * 128 + (bc ^ sw)) = ka;
    *reinterpret_cast<bf16x8*>(KsB + srow * 128 + ((bc + 16) ^ sw)) = kb2;
#pragma unroll
    for (int i = 0; i < 8; ++i) {
      int d = vd0 + i;
      *((__bf16*)(VtB + d * 128 + ((vk * 2) ^ ((d & 7) << 4)))) = va[i];
      d = vd0 + 8 + i;
      *((__bf16*)(VtB + d * 128 + ((vk * 2) ^ ((d & 7) << 4)))) = vb[i];
    }
  }

  int cur = 0;
  for (int kt = 0; kt < ntiles; ++kt) {
    if (kt + 1 < ntiles) {
      const __bf16* src =
          qkv + (size_t)((kt + 1) * 64 + srow) * (3 * kD) + kD + h * 64 + sseg * 16;
      ka = *reinterpret_cast<const bf16x8*>(src);
      kb2 = *reinterpret_cast<const bf16x8*>(src + 8);
      const __bf16* vsrc =
          qkv + (size_t)((kt + 1) * 64 + vk) * (3 * kD) + 2 * kD + h * 64 + vd0;
      va = *reinterpret_cast<const bf16x8*>(vsrc);
      vb = *reinterpret_cast<const bf16x8*>(vsrc + 8);
    }
    __syncthreads();

    char* KsB = (char*)Ks[cur];
    char* VtB = (char*)Vt[cur];
    bool diag = (kt == ntiles - 1);
    int jmax = diag ? w : 3;

    f32x4 s[4];
#pragma unroll
    for (int jj = 0; jj < 4; ++jj) {
      if (jj <= jmax) {
        int krow = jj * 16 + lr;
        int ksw = (lr & 7) << 4;
        bf16x8 k0 = *reinterpret_cast<const bf16x8*>(KsB + krow * 128 + ((g * 16) ^ ksw));
        bf16x8 k1 = *reinterpret_cast<const bf16x8*>(KsB + krow * 128 + ((64 + g * 16) ^ ksw));
        f32x4 z = {};
        z = __builtin_amdgcn_mfma_f32_16x16x32_bf16(k0, qf[0], z, 0, 0, 0);
        s[jj] = __builtin_amdgcn_mfma_f32_16x16x32_bf16(k1, qf[1], z, 0, 0, 0);
      } else {
        s[jj] = f32x4{-1e30f, -1e30f, -1e30f, -1e30f};
      }
    }
    if (diag) {
#pragma unroll
      for (int r = 0; r < 4; ++r)
        if (g * 4 + r > lr) s[w][r] = -1e30f;
    }

    float mt = -1e30f;
#pragma unroll
    for (int jj = 0; jj < 4; ++jj)
#pragma unroll
      for (int r = 0; r < 4; ++r) mt = fmaxf(mt, s[jj][r]);
    mt = fmaxf(mt, __shfl_xor(mt, 16));
    mt = fmaxf(mt, __shfl_xor(mt, 32));
    float mn = fmaxf(m, mt);
    float sc = exp2f((m - mn) * L2E);
    float p[4][4];
    float rs = 0.f;
#pragma unroll
    for (int jj = 0; jj < 4; ++jj)
#pragma unroll
      for (int r = 0; r < 4; ++r) {
        float e = exp2f((s[jj][r] - mn) * L2E);
        p[jj][r] = e;
        rs += e;
      }
    rs += __shfl_xor(rs, 16);
    rs += __shfl_xor(rs, 32);
    lsum = lsum * sc + rs;
    m = mn;
#pragma unroll
    for (int r = 0; r < 4; ++r) {
      float s4 = __shfl(sc, 20 * g + r);
#pragma unroll
      for (int dt = 0; dt < 4; ++dt) acc[dt][r] *= s4;
    }

#pragma unroll
    for (int jj = 0; jj < 4; ++jj) {
      bf16x4 pv;
#pragma unroll
      for (int r = 0; r < 4; ++r) pv[r] = (__bf16)p[jj][r];
      *reinterpret_cast<bf16x4*>(PwB + lr * 128 + ((jj * 32 + g * 8) ^ psw)) = pv;
    }

    {
      bf16x8 pa0 = *reinterpret_cast<const bf16x8*>(PwB + lr * 128 + ((g * 16) ^ psw));
      bf16x8 pa1 = *reinterpret_cast<const bf16x8*>(PwB + lr * 128 + ((64 + g * 16) ^ psw));
#pragma unroll
      for (int dt = 0; dt < 4; ++dt) {
        int vrow = dt * 16 + lr;
        int vsw = (lr & 7) << 4;
        bf16x8 vb0 = *reinterpret_cast<const bf16x8*>(VtB + vrow * 128 + ((g * 16) ^ vsw));
        bf16x8 vb1 = *reinterpret_cast<const bf16x8*>(VtB + vrow * 128 + ((64 + g * 16) ^ vsw));
        acc[dt] = __builtin_amdgcn_mfma_f32_16x16x32_bf16(pa0, vb0, acc[dt], 0, 0, 0);
        acc[dt] = __builtin_amdgcn_mfma_f32_16x16x32_bf16(pa1, vb1, acc[dt], 0, 0, 0);
      }
    }
    __syncthreads();

    if (kt + 1 < ntiles) {
      char* KsN = (char*)Ks[cur ^ 1];
      char* VtN = (char*)Vt[cur ^ 1];
      int bc = sseg * 32, sw = (srow & 7) << 4;
      *reinterpret_cast<bf16x8*>(KsN + srow * 128 + (bc ^ sw)) = ka;
      *reinterpret_cast<bf16x8*>(KsN + srow * 128 + ((bc + 16) ^ sw)) = kb2;
#pragma unroll
      for (int i = 0; i < 8; ++i) {
        int d = vd0 + i;
        *((__bf16*)(VtN + d * 128 + ((vk * 2) ^ ((d & 7) << 4)))) = va[i];
        d = vd0 + 8 + i;
        *((__bf16*)(VtN + d * 128 + ((vk * 2) ^ ((d & 7) << 4)))) = vb[i];
      }
      cur ^= 1;
    }
  }

  float linv = 1.f / lsum;
#pragma unroll
  for (int r = 0; r < 4; ++r) {
    float ir = __shfl(linv, 20 * g + r);
    int row = bq + w * 16 + g * 4 + r;
#pragma unroll
    for (int dt = 0; dt < 4; ++dt)
      out[(size_t)row * kD + h * 64 + dt * 16 + lr] = (__bf16)(acc[dt][r] * ir);
  }
}

// ---------------------------------------------------------------------------
// Fused residual blend + group rotation, blocked (token-chunk, group).
// ---------------------------------------------------------------------------
__global__ __launch_bounds__(256) void blend_rot_kernel(const float* x,
                                                        const float* y,
                                                        const float* iscale,
                                                        int l,
                                                        const float* __restrict__ Rall,
                                                        float* xout) {
  int tc = blockIdx.x, gr = blockIdx.y;
  int tid = threadIdx.x;
  __shared__ float Rs[64 * 64];
  __shared__ float xb[64][65];
  float s = iscale[l];
  const float* Rg = Rall + ((size_t)l * kG + gr) * 4096;
  {
    int off = tid * 16;
#pragma unroll
    for (int q2 = 0; q2 < 4; ++q2) {
      float4 rv = *reinterpret_cast<const float4*>(Rg + off + q2 * 4);
      *reinterpret_cast<float4*>(&Rs[off + q2 * 4]) = rv;
    }
  }
  int tok = tid & 63, seg = (tid >> 6) * 16;
  {
    const float* xr = x + (size_t)(tc * 64 + tok) * kD + gr * 64 + seg;
    const float* yr = y + (size_t)(tc * 64 + tok) * kD + gr * 64 + seg;
#pragma unroll
    for (int q2 = 0; q2 < 4; ++q2) {
      float4 xv = *reinterpret_cast<const float4*>(xr + q2 * 4);
      float4 yv = *reinterpret_cast<const float4*>(yr + q2 * 4);
      xb[tok][seg + q2 * 4 + 0] = xv.x + (yv.x - xv.x) * s;
      xb[tok][seg + q2 * 4 + 1] = xv.y + (yv.y - xv.y) * s;
      xb[tok][seg + q2 * 4 + 2] = xv.z + (yv.z - xv.z) * s;
      xb[tok][seg + q2 * 4 + 3] = xv.w + (yv.w - xv.w) * s;
    }
  }
  __syncthreads();
  float o[16] = {};
  for (int i = 0; i < 64; ++i) {
    float xv = xb[tok][i];
#pragma unroll
    for (int d = 0; d < 16; ++d) o[d] += xv * Rs[i * 64 + seg + d];
  }
  float* outr = xout + (size_t)(tc * 64 + tok) * kD + gr * 64 + seg;
#pragma unroll
  for (int q2 = 0; q2 < 4; ++q2) {
    float4 ov = {o[q2 * 4 + 0], o[q2 * 4 + 1], o[q2 * 4 + 2], o[q2 * 4 + 3]};
    *reinterpret_cast<float4*>(outr + q2 * 4) = ov;
  }
}

// ---------------------------------------------------------------------------
extern "C" void kernel_launch(void* const* d_in, const int* in_sizes, int n_in,
                              void* d_out, int out_size, void* d_ws, size_t ws_size,
                              hipStream_t stream) {
  const int* tokens = (const int*)d_in[0];
  const float* embed_w = (const float*)d_in[1];
  const float* lm_head_w = (const float*)d_in[2];
  const float* norm_w = (const float*)d_in[3];
  const float* layer_gamma = (const float*)d_in[4];
  const float* layer_beta = (const float*)d_in[5];
  const float* iter_scale = (const float*)d_in[6];
  const float* skew_upper = (const float*)d_in[7];
  const float* ln1_w = (const float*)d_in[8];
  const float* ln2_w = (const float*)d_in[9];
  const float* wqkv = (const float*)d_in[10];
  const float* wo = (const float*)d_in[11];
  const float* w1 = (const float*)d_in[12];
  const float* w2 = (const float*)d_in[13];
  float* out = (float*)d_out;

  // ws: x(4MB) y(4MB) hb(2MB) ab(2MB) R(6.3MB) [+ lmhb 65.5MB if room]
  float* x = (float*)d_ws;
  float* y = x + (size_t)kT * kD;
  __bf16* hb = (__bf16*)(y + (size_t)kT * kD);
  __bf16* ab = hb + (size_t)kT * kD;
  float* R = (float*)(ab + (size_t)kT * kD);
  __bf16* lmhb = (__bf16*)(R + (size_t)kL * kG * 4096);
  // base ws usage: 4,670,464 f32; bf16 head copy needs +16,384,000 f32-equiv
  bool ws_big = ws_size >= (size_t)(4670464 + 16384000) * 4;

  // d_out scratch (all dead before final lm_head GEMM writes out):
  __bf16* qkvb = (__bf16*)out;                       // 3.1M bf16
  __bf16* ffb = (__bf16*)(out + 1572864);            // 4.2M bf16
  __bf16* wqkvT = (__bf16*)(out + 3670016);          // [3072][1024]
  __bf16* woT = (__bf16*)(out + 5242880);            // [1024][1024]
  __bf16* w1T = (__bf16*)(out + 5767168);            // [4096][1024]
  __bf16* w2T = (__bf16*)(out + 7864320);            // [1024][4096]

  cayley_kernel<<<kL * kG, 256, 0, stream>>>(skew_upper, R);
  embed_kernel<<<kT * kD / 4 / 256, 256, 0, stream>>>(tokens, embed_w, x);
  convt_kernel<<<dim3(3 * kD / 64, kD / 64), 256, 0, stream>>>(wqkv, wqkvT, kD, 3 * kD);
  convt_kernel<<<dim3(kD / 64, kD / 64), 256, 0, stream>>>(wo, woT, kD, kD);
  convt_kernel<<<dim3(kFF / 64, kD / 64), 256, 0, stream>>>(w1, w1T, kD, kFF);
  convt_kernel<<<dim3(kD / 64, kFF / 64), 256, 0, stream>>>(w2, w2T, kFF, kD);
  if (ws_big)
    cast_kernel<<<kV * kD / 8 / 256, 256, 0, stream>>>(lm_head_w, lmhb);

  for (int l = 0; l < kL; ++l) {
    rms_kernel<true><<<kT, 256, 0, stream>>>(x, ln1_w, layer_gamma + (size_t)l * kD,
                                             layer_beta + (size_t)l * kD, hb);
    gemm_kernel<64, 128, 8, 3, false><<<(kT / 64) * (3 * kD / 128), 512, 0, stream>>>(
        hb, wqkvT, nullptr, qkvb, kT, 3 * kD, kD);
    fattn_kernel<<<dim3(kT / 64, kH), 256, 0, stream>>>(qkvb, ab);
    gemm_kernel<64, 64, 8, 1, false><<<(kT / 64) * (kD / 64), 512, 0, stream>>>(
        ab, woT, x, y, kT, kD, kD);
    rms_kernel<false><<<kT, 256, 0, stream>>>(y, ln2_w, nullptr, nullptr, hb);
    gemm_kernel<64, 128, 8, 2, false><<<(kT / 64) * (kFF / 128), 512, 0, stream>>>(
        hb, w1T, nullptr, ffb, kT, kFF, kD);
    gemm_kernel<64, 64, 8, 1, false><<<(kT / 64) * (kD / 64), 512, 0, stream>>>(
        ffb, w2T, y, y, kT, kD, kFF);
    blend_rot_kernel<<<dim3(kT / 64, kG), 256, 0, stream>>>(x, y, iter_scale, l, R, x);
  }

  rms_kernel<false><<<kT, 256, 0, stream>>>(x, norm_w, nullptr, nullptr, hb);
  if (ws_big)
    gemm_kernel<128, 128, 4, 0, false><<<(kT / 128) * (kV / 128), 256, 0, stream>>>(
        hb, lmhb, nullptr, out, kT, kV, kD);
  else
    gemm_kernel<128, 128, 4, 0, true><<<(kT / 128) * (kV / 128), 256, 0, stream>>>(
        hb, lm_head_w, nullptr, out, kT, kV, kD);
}

// Round 11
// 2650.681 us; speedup vs baseline: 2.2269x; 1.1649x over previous
//
#include <hip/hip_runtime.h>
#include <hip/hip_bf16.h>
#include <math.h>

// Model dims
constexpr int kD = 1024;
constexpr int kH = 16;
constexpr int kV = 32000;
constexpr int kT = 1024;
constexpr int kG = 16;
constexpr int kFF = 4096;
constexpr int kL = 24;
constexpr int kNTRI = 2016;
#define EPSF 1e-6f
#define L2E 1.44269504088896f

typedef __bf16 bf16x8 __attribute__((ext_vector_type(8)));
typedef __bf16 bf16x4 __attribute__((ext_vector_type(4)));
typedef float f32x4 __attribute__((ext_vector_type(4)));

#define GLOAD16(g, l)                                                   \
  __builtin_amdgcn_global_load_lds(                                     \
      (const __attribute__((address_space(1))) void*)(g),               \
      (__attribute__((address_space(3))) void*)(l), 16, 0, 0)

// ---------------------------------------------------------------------------
// Cayley transform: R = (I - A/2)^-1 (I + A/2). One block per (layer,group).
// ---------------------------------------------------------------------------
__global__ __launch_bounds__(256) void cayley_kernel(const float* __restrict__ skew,
                                                     float* __restrict__ R) {
  int lg = blockIdx.x;
  int tid = threadIdx.x;
  int r = tid & 63, q = tid >> 6;
  __shared__ float Ms[64][65];
  __shared__ float Bs[64][65];
  const float* su = skew + (size_t)lg * kNTRI;
#pragma unroll
  for (int cc = 0; cc < 16; ++cc) {
    int c = q * 16 + cc;
    float a = 0.f;
    if (r < c) a = su[r * (127 - r) / 2 + (c - r - 1)];
    else if (r > c) a = -su[c * (127 - c) / 2 + (r - c - 1)];
    Ms[r][c] = (r == c ? 1.f : 0.f) - 0.5f * a;
    Bs[r][c] = (r == c ? 1.f : 0.f) + 0.5f * a;
  }
  __syncthreads();
  for (int k = 0; k < 64; ++k) {
    float ip = 1.f / Ms[k][k];
    float f = Ms[r][k];
    float beta = (r == k) ? (1.f - ip) : (f * ip);
    float mk[16], bk[16];
#pragma unroll
    for (int cc = 0; cc < 16; ++cc) {
      mk[cc] = Ms[k][q * 16 + cc];
      bk[cc] = Bs[k][q * 16 + cc];
    }
    __syncthreads();
#pragma unroll
    for (int cc = 0; cc < 16; ++cc) {
      int c = q * 16 + cc;
      Ms[r][c] -= beta * mk[cc];
      Bs[r][c] -= beta * bk[cc];
    }
    __syncthreads();
  }
  float* Ro = R + ((size_t)lg * 64 + r) * 64;
#pragma unroll
  for (int cc = 0; cc < 16; ++cc) Ro[q * 16 + cc] = Bs[r][q * 16 + cc];
}

// ---------------------------------------------------------------------------
// Embedding gather, float4-vectorized.
// ---------------------------------------------------------------------------
__global__ __launch_bounds__(256) void embed_kernel(const int* __restrict__ tok,
                                                    const float* __restrict__ ew,
                                                    float* __restrict__ x) {
  int i = blockIdx.x * 256 + threadIdx.x;
  int t = i >> 8;
  int d4 = i & 255;
  int v = tok[t];
  reinterpret_cast<float4*>(x)[i] =
      reinterpret_cast<const float4*>(ew + (size_t)v * kD)[d4];
}

// ---------------------------------------------------------------------------
// Elementwise f32 -> bf16 cast (lm_head), 8 elems/thread.
// ---------------------------------------------------------------------------
__global__ __launch_bounds__(256) void cast_kernel(const float* __restrict__ W,
                                                   __bf16* __restrict__ O) {
  size_t i = ((size_t)blockIdx.x * 256 + threadIdx.x) * 8;
  float4 f0 = *reinterpret_cast<const float4*>(W + i);
  float4 f1 = *reinterpret_cast<const float4*>(W + i + 4);
  bf16x8 v;
  v[0] = (__bf16)f0.x; v[1] = (__bf16)f0.y;
  v[2] = (__bf16)f0.z; v[3] = (__bf16)f0.w;
  v[4] = (__bf16)f1.x; v[5] = (__bf16)f1.y;
  v[6] = (__bf16)f1.z; v[7] = (__bf16)f1.w;
  *reinterpret_cast<bf16x8*>(O + i) = v;
}

// ---------------------------------------------------------------------------
// Weight convert+transpose: W f32 [K][N] -> WT bf16 [N][K]. 64x64 tiles.
// ---------------------------------------------------------------------------
__global__ __launch_bounds__(256) void convt_kernel(const float* __restrict__ W,
                                                    __bf16* __restrict__ WT,
                                                    int K, int N) {
  __shared__ float tile[64][65];
  int t = threadIdx.x;
  int n0 = blockIdx.x * 64, k0 = blockIdx.y * 64;
#pragma unroll
  for (int r = 0; r < 4; ++r) {
    int kr = r * 16 + (t >> 4);
    int nc = (t & 15) * 4;
    float4 v = *reinterpret_cast<const float4*>(&W[(size_t)(k0 + kr) * N + n0 + nc]);
    tile[kr][nc + 0] = v.x;
    tile[kr][nc + 1] = v.y;
    tile[kr][nc + 2] = v.z;
    tile[kr][nc + 3] = v.w;
  }
  __syncthreads();
#pragma unroll
  for (int r = 0; r < 2; ++r) {
    int idx = r * 256 + t;
    int nrow = idx >> 3, kc = (idx & 7) * 8;
    bf16x8 v;
#pragma unroll
    for (int j = 0; j < 8; ++j) v[j] = (__bf16)tile[kc + j][nrow];
    *reinterpret_cast<bf16x8*>(&WT[(size_t)(n0 + nrow) * K + k0 + kc]) = v;
  }
}

// ---------------------------------------------------------------------------
// RMSNorm -> bf16 out (shuffle-based reduction, 1 barrier).
// ---------------------------------------------------------------------------
template <bool AFFINE>
__global__ __launch_bounds__(256) void rms_kernel(const float* __restrict__ x,
                                                  const float* __restrict__ w,
                                                  const float* __restrict__ gamma,
                                                  const float* __restrict__ beta,
                                                  __bf16* __restrict__ out) {
  int t = blockIdx.x, tid = threadIdx.x;
  __shared__ float red4[4];
  float4 xv = reinterpret_cast<const float4*>(x + (size_t)t * kD)[tid];
  float ss = xv.x * xv.x + xv.y * xv.y + xv.z * xv.z + xv.w * xv.w;
#pragma unroll
  for (int o = 1; o < 64; o <<= 1) ss += __shfl_xor(ss, o);
  if ((tid & 63) == 0) red4[tid >> 6] = ss;
  __syncthreads();
  float tot = red4[0] + red4[1] + red4[2] + red4[3];
  float rms = rsqrtf(tot / (float)kD + EPSF);
  float4 wv = reinterpret_cast<const float4*>(w)[tid];
  float o0 = xv.x * rms * wv.x;
  float o1 = xv.y * rms * wv.y;
  float o2 = xv.z * rms * wv.z;
  float o3 = xv.w * rms * wv.w;
  if (AFFINE) {
    float4 gv = reinterpret_cast<const float4*>(gamma)[tid];
    float4 bv = reinterpret_cast<const float4*>(beta)[tid];
    o0 = o0 * gv.x + bv.x;
    o1 = o1 * gv.y + bv.y;
    o2 = o2 * gv.z + bv.z;
    o3 = o3 * gv.w + bv.w;
  }
  bf16x4 ov;
  ov[0] = (__bf16)o0; ov[1] = (__bf16)o1; ov[2] = (__bf16)o2; ov[3] = (__bf16)o3;
  *reinterpret_cast<bf16x4*>(out + (size_t)t * kD + tid * 4) = ov;
}

// ---------------------------------------------------------------------------
// Fused split-K reduce + residual + RMSNorm: y = x + p0 + p1 (f32 store),
// hb = rms(y) * w (bf16 store).
// ---------------------------------------------------------------------------
__global__ __launch_bounds__(256) void rms_red_kernel(const float* __restrict__ x,
                                                      const float* __restrict__ p0,
                                                      const float* __restrict__ p1,
                                                      const float* __restrict__ w,
                                                      float* __restrict__ y,
                                                      __bf16* __restrict__ hb) {
  int t = blockIdx.x, tid = threadIdx.x;
  __shared__ float red4[4];
  size_t base = (size_t)t * kD;
  float4 xv = reinterpret_cast<const float4*>(x + base)[tid];
  float4 a = reinterpret_cast<const float4*>(p0 + base)[tid];
  float4 b = reinterpret_cast<const float4*>(p1 + base)[tid];
  float4 yv;
  yv.x = xv.x + a.x + b.x;
  yv.y = xv.y + a.y + b.y;
  yv.z = xv.z + a.z + b.z;
  yv.w = xv.w + a.w + b.w;
  reinterpret_cast<float4*>(y + base)[tid] = yv;
  float ss = yv.x * yv.x + yv.y * yv.y + yv.z * yv.z + yv.w * yv.w;
#pragma unroll
  for (int o = 1; o < 64; o <<= 1) ss += __shfl_xor(ss, o);
  if ((tid & 63) == 0) red4[tid >> 6] = ss;
  __syncthreads();
  float tot = red4[0] + red4[1] + red4[2] + red4[3];
  float rms = rsqrtf(tot / (float)kD + EPSF);
  float4 wv = reinterpret_cast<const float4*>(w)[tid];
  bf16x4 ov;
  ov[0] = (__bf16)(yv.x * rms * wv.x);
  ov[1] = (__bf16)(yv.y * rms * wv.y);
  ov[2] = (__bf16)(yv.z * rms * wv.z);
  ov[3] = (__bf16)(yv.w * rms * wv.w);
  *reinterpret_cast<bf16x4*>(hb + base + tid * 4) = ov;
}

// ---------------------------------------------------------------------------
// MFMA GEMM, m97 structure + rule-21 swizzle, NW waves (4 -> 2x2 wave grid,
// 8 -> 2x4). global_load_lds width=16 with pre-swizzled global source,
// linear LDS dest, XOR-swizzled ds_read. BK=64, 2-barrier K-loop.
// 1D grid, XCD-chunked swizzle (grid %8 == 0).
// KSPLIT: grid also covers K-splits; partial C (f32) at Cv + ks*M*N (EPI=0).
// BF32: B f32 [N][K], reg-staged converted (head fallback).
// EPI: 0=f32, 1=f32 acc+res, 2=gelu->bf16, 3=bf16.
// ---------------------------------------------------------------------------
template <int BM, int BN, int NW, int EPI, bool BF32, int KSPLIT = 1>
__global__ __launch_bounds__(NW * 64) void gemm_kernel(
    const __bf16* __restrict__ A, const void* __restrict__ Bv,
    const float* res, void* __restrict__ Cv, int M, int N, int K) {
  constexpr int WCOLS = (NW == 4) ? 2 : 4;
  constexpr int FM = (BM / 2) / 16;
  constexpr int FN = (BN / WCOLS) / 16;
  constexpr int AISS = BM / 8 / NW;
  constexpr int BISS = BN / 8 / NW;
  __shared__ __bf16 As[BM * 64];
  __shared__ __bf16 Bs[BN * 64];
  char* AsB = (char*)As;
  char* BsB = (char*)Bs;
  int tid = threadIdx.x;
  int w = tid >> 6, lane = tid & 63;
  int mt = M / BM, nt = N / BN;
  int cpx = gridDim.x >> 3;
  int id = (blockIdx.x & 7) * cpx + (blockIdx.x >> 3);
  int ks_id = id / (mt * nt);
  int rem = id % (mt * nt);
  int bm = (rem % mt) * BM, bn = (rem / mt) * BN;
  int kbeg = ks_id * (K / KSPLIT), kend = kbeg + K / KSPLIT;
  int lrow = lane & 15, g = lane >> 4;
  int grow = lane >> 3;                       // staging: row within 8-row slab
  int gswz = ((lane & 7) ^ grow) * 8;         // pre-swizzled source col (elems)
  int rsw = (lrow & 7) << 4;                  // read-side XOR (bytes)
  int wm = (NW == 4) ? (w >> 1) : (w >> 2);
  int wn = (NW == 4) ? (w & 1) : (w & 3);
  int wr = wm * (BM / 2), wc = wn * (BN / WCOLS);
  f32x4 acc[FM][FN] = {};
  const __bf16* B16 = (const __bf16*)Bv;
  const float* B32 = (const float*)Bv;

  for (int k0 = kbeg; k0 < kend; k0 += 64) {
#pragma unroll
    for (int i = 0; i < AISS; ++i) {
      int rbase = (i * NW + w) * 8;
      GLOAD16(&A[(size_t)(bm + rbase + grow) * K + k0 + gswz], &As[rbase * 64]);
    }
    if (!BF32) {
#pragma unroll
      for (int i = 0; i < BISS; ++i) {
        int rbase = (i * NW + w) * 8;
        GLOAD16(&B16[(size_t)(bn + rbase + grow) * K + k0 + gswz], &Bs[rbase * 64]);
      }
    } else {
#pragma unroll
      for (int rrep = 0; rrep < BN * 8 / (NW * 64); ++rrep) {
        int cid = rrep * NW * 64 + tid;
        int row = cid >> 3, kc = (cid & 7) * 8;
        const float* src = &B32[(size_t)(bn + row) * K + k0 + kc];
        float4 f0 = *reinterpret_cast<const float4*>(src);
        float4 f1 = *reinterpret_cast<const float4*>(src + 4);
        bf16x8 v;
        v[0] = (__bf16)f0.x; v[1] = (__bf16)f0.y;
        v[2] = (__bf16)f0.z; v[3] = (__bf16)f0.w;
        v[4] = (__bf16)f1.x; v[5] = (__bf16)f1.y;
        v[6] = (__bf16)f1.z; v[7] = (__bf16)f1.w;
        int swc = ((cid & 7) ^ (row & 7)) * 16;  // both-sides swizzle
        *reinterpret_cast<bf16x8*>(BsB + row * 128 + swc) = v;
      }
    }
    __syncthreads();
#pragma unroll
    for (int ks = 0; ks < 2; ++ks) {
      bf16x8 af[FM], bg[FN];
#pragma unroll
      for (int i = 0; i < FM; ++i)
        af[i] = *reinterpret_cast<const bf16x8*>(
            AsB + (wr + i * 16 + lrow) * 128 + ((ks * 64 + g * 16) ^ rsw));
#pragma unroll
      for (int j = 0; j < FN; ++j)
        bg[j] = *reinterpret_cast<const bf16x8*>(
            BsB + (wc + j * 16 + lrow) * 128 + ((ks * 64 + g * 16) ^ rsw));
#pragma unroll
      for (int i = 0; i < FM; ++i)
#pragma unroll
        for (int j = 0; j < FN; ++j)
          acc[i][j] = __builtin_amdgcn_mfma_f32_16x16x32_bf16(af[i], bg[j],
                                                              acc[i][j], 0, 0, 0);
    }
    __syncthreads();
  }

  float* Cp = (float*)Cv + (size_t)ks_id * M * N;
  int crow0 = bm + wr + g * 4;
  int ccol0 = bn + wc + lrow;
#pragma unroll
  for (int i = 0; i < FM; ++i) {
#pragma unroll
    for (int j = 0; j < FN; ++j) {
#pragma unroll
      for (int r = 0; r < 4; ++r) {
        int row = crow0 + i * 16 + r;
        int col = ccol0 + j * 16;
        size_t idx = (size_t)row * N + col;
        float v = acc[i][j][r];
        if (EPI == 1) v += res[idx];
        if (EPI == 2) {
          float u = v;
          float z = 0.7978845608028654f * (u + 0.044715f * u * u * u);
          float ez = exp2f(z * (2.f * L2E));
          v = u * ez / (1.f + ez);
        }
        if (EPI == 2 || EPI == 3) ((__bf16*)Cv)[idx] = (__bf16)v;
        else Cp[idx] = v;
      }
    }
  }
}

// ---------------------------------------------------------------------------
// Flash attention (causal), bf16 MFMA, swapped QK^T, per-lane online softmax,
// K/V double-buffered with issue-early / write-late staging.
// ---------------------------------------------------------------------------
__global__ __launch_bounds__(256) void fattn_kernel(const __bf16* __restrict__ qkv,
                                                    __bf16* __restrict__ out) {
  __shared__ __bf16 Ks[2][64 * 64];
  __shared__ __bf16 Vt[2][64 * 64];
  __shared__ __bf16 Ps[4 * 16 * 64];
  int tid = threadIdx.x;
  int bq = blockIdx.x * 64;
  int h = blockIdx.y;
  int w = tid >> 6, lane = tid & 63;
  int g = lane >> 4, lr = lane & 15;

  bf16x8 qf[2];
  const __bf16* qbase = qkv + (size_t)(bq + w * 16 + lr) * (3 * kD) + h * 64;
#pragma unroll
  for (int ks = 0; ks < 2; ++ks) {
    bf16x8 v = *reinterpret_cast<const bf16x8*>(qbase + ks * 32 + g * 8);
#pragma unroll
    for (int j = 0; j < 8; ++j) qf[ks][j] = (__bf16)((float)v[j] * 0.125f);
  }

  f32x4 acc[4] = {};
  float m = -1e30f, lsum = 0.f;

  int srow = tid >> 2, sseg = tid & 3;
  int vk = tid & 63, vd0 = (tid >> 6) * 16;
  char* PwB = (char*)(Ps + w * (16 * 64));
  int psw = (lr & 7) << 4;

  bf16x8 ka, kb2, va, vb;
  int ntiles = bq / 64 + 1;

  {
    const __bf16* src = qkv + (size_t)(srow) * (3 * kD) + kD + h * 64 + sseg * 16;
    ka = *reinterpret_cast<const bf16x8*>(src);
    kb2 = *reinterpret_cast<const bf16x8*>(src + 8);
    const __bf16* vsrc = qkv + (size_t)(vk) * (3 * kD) + 2 * kD + h * 64 + vd0;
    va = *reinterpret_cast<const bf16x8*>(vsrc);
    vb = *reinterpret_cast<const bf16x8*>(vsrc + 8);
    char* KsB = (char*)Ks[0];
    char* VtB = (char*)Vt[0];
    int bc = sseg * 32, sw = (srow & 7) << 4;
    *reinterpret_cast<bf16x8*>(KsB + srow * 128 + (bc ^ sw)) = ka;
    *reinterpret_cast<bf16x8*>(KsB + srow * 128 + ((bc + 16) ^ sw)) = kb2;
#pragma unroll
    for (int i = 0; i < 8; ++i) {
      int d = vd0 + i;
      *((__bf16*)(VtB + d * 128 + ((vk * 2) ^ ((d & 7) << 4)))) = va[i];
      d = vd0 + 8 + i;
      *((__bf16*)(VtB + d * 128 + ((vk * 2) ^ ((d & 7) << 4)))) = vb[i];
    }
  }

  int cur = 0;
  for (int kt = 0; kt < ntiles; ++kt) {
    if (kt + 1 < ntiles) {
      const __bf16* src =
          qkv + (size_t)((kt + 1) * 64 + srow) * (3 * kD) + kD + h * 64 + sseg * 16;
      ka = *reinterpret_cast<const bf16x8*>(src);
      kb2 = *reinterpret_cast<const bf16x8*>(src + 8);
      const __bf16* vsrc =
          qkv + (size_t)((kt + 1) * 64 + vk) * (3 * kD) + 2 * kD + h * 64 + vd0;
      va = *reinterpret_cast<const bf16x8*>(vsrc);
      vb = *reinterpret_cast<const bf16x8*>(vsrc + 8);
    }
    __syncthreads();

    char* KsB = (char*)Ks[cur];
    char* VtB = (char*)Vt[cur];
    bool diag = (kt == ntiles - 1);
    int jmax = diag ? w : 3;

    f32x4 s[4];
#pragma unroll
    for (int jj = 0; jj < 4; ++jj) {
      if (jj <= jmax) {
        int krow = jj * 16 + lr;
        int ksw = (lr & 7) << 4;
        bf16x8 k0 = *reinterpret_cast<const bf16x8*>(KsB + krow * 128 + ((g * 16) ^ ksw));
        bf16x8 k1 = *reinterpret_cast<const bf16x8*>(KsB + krow * 128 + ((64 + g * 16) ^ ksw));
        f32x4 z = {};
        z = __builtin_amdgcn_mfma_f32_16x16x32_bf16(k0, qf[0], z, 0, 0, 0);
        s[jj] = __builtin_amdgcn_mfma_f32_16x16x32_bf16(k1, qf[1], z, 0, 0, 0);
      } else {
        s[jj] = f32x4{-1e30f, -1e30f, -1e30f, -1e30f};
      }
    }
    if (diag) {
#pragma unroll
      for (int r = 0; r < 4; ++r)
        if (g * 4 + r > lr) s[w][r] = -1e30f;
    }

    float mt = -1e30f;
#pragma unroll
    for (int jj = 0; jj < 4; ++jj)
#pragma unroll
      for (int r = 0; r < 4; ++r) mt = fmaxf(mt, s[jj][r]);
    mt = fmaxf(mt, __shfl_xor(mt, 16));
    mt = fmaxf(mt, __shfl_xor(mt, 32));
    float mn = fmaxf(m, mt);
    float sc = exp2f((m - mn) * L2E);
    float p[4][4];
    float rs = 0.f;
#pragma unroll
    for (int jj = 0; jj < 4; ++jj)
#pragma unroll
      for (int r = 0; r < 4; ++r) {
        float e = exp2f((s[jj][r] - mn) * L2E);
        p[jj][r] = e;
        rs += e;
      }
    rs += __shfl_xor(rs, 16);
    rs += __shfl_xor(rs, 32);
    lsum = lsum * sc + rs;
    m = mn;
#pragma unroll
    for (int r = 0; r < 4; ++r) {
      float s4 = __shfl(sc, 20 * g + r);
#pragma unroll
      for (int dt = 0; dt < 4; ++dt) acc[dt][r] *= s4;
    }

#pragma unroll
    for (int jj = 0; jj < 4; ++jj) {
      bf16x4 pv;
#pragma unroll
      for (int r = 0; r < 4; ++r) pv[r] = (__bf16)p[jj][r];
      *reinterpret_cast<bf16x4*>(PwB + lr * 128 + ((jj * 32 + g * 8) ^ psw)) = pv;
    }

    {
      bf16x8 pa0 = *reinterpret_cast<const bf16x8*>(PwB + lr * 128 + ((g * 16) ^ psw));
      bf16x8 pa1 = *reinterpret_cast<const bf16x8*>(PwB + lr * 128 + ((64 + g * 16) ^ psw));
#pragma unroll
      for (int dt = 0; dt < 4; ++dt) {
        int vrow = dt * 16 + lr;
        int vsw = (lr & 7) << 4;
        bf16x8 vb0 = *reinterpret_cast<const bf16x8*>(VtB + vrow * 128 + ((g * 16) ^ vsw));
        bf16x8 vb1 = *reinterpret_cast<const bf16x8*>(VtB + vrow * 128 + ((64 + g * 16) ^ vsw));
        acc[dt] = __builtin_amdgcn_mfma_f32_16x16x32_bf16(pa0, vb0, acc[dt], 0, 0, 0);
        acc[dt] = __builtin_amdgcn_mfma_f32_16x16x32_bf16(pa1, vb1, acc[dt], 0, 0, 0);
      }
    }
    __syncthreads();

    if (kt + 1 < ntiles) {
      char* KsN = (char*)Ks[cur ^ 1];
      char* VtN = (char*)Vt[cur ^ 1];
      int bc = sseg * 32, sw = (srow & 7) << 4;
      *reinterpret_cast<bf16x8*>(KsN + srow * 128 + (bc ^ sw)) = ka;
      *reinterpret_cast<bf16x8*>(KsN + srow * 128 + ((bc + 16) ^ sw)) = kb2;
#pragma unroll
      for (int i = 0; i < 8; ++i) {
        int d = vd0 + i;
        *((__bf16*)(VtN + d * 128 + ((vk * 2) ^ ((d & 7) << 4)))) = va[i];
        d = vd0 + 8 + i;
        *((__bf16*)(VtN + d * 128 + ((vk * 2) ^ ((d & 7) << 4)))) = vb[i];
      }
      cur ^= 1;
    }
  }

  float linv = 1.f / lsum;
#pragma unroll
  for (int r = 0; r < 4; ++r) {
    float ir = __shfl(linv, 20 * g + r);
    int row = bq + w * 16 + g * 4 + r;
#pragma unroll
    for (int dt = 0; dt < 4; ++dt)
      out[(size_t)row * kD + h * 64 + dt * 16 + lr] = (__bf16)(acc[dt][r] * ir);
  }
}

// ---------------------------------------------------------------------------
// Fused w2 split-K reduce + residual blend + group rotation, (tc, gr) blocks.
// y2 = y + q0 + q1;  xb = x + (y2 - x)*s;  xout = xb @ R[g].
// ---------------------------------------------------------------------------
__global__ __launch_bounds__(256) void blend_rot_kernel(const float* x,
                                                        const float* y,
                                                        const float* q0,
                                                        const float* q1,
                                                        const float* iscale,
                                                        int l,
                                                        const float* __restrict__ Rall,
                                                        float* xout) {
  int tc = blockIdx.x, gr = blockIdx.y;
  int tid = threadIdx.x;
  __shared__ float Rs[64 * 64];
  __shared__ float xb[64][65];
  float s = iscale[l];
  const float* Rg = Rall + ((size_t)l * kG + gr) * 4096;
  {
    int off = tid * 16;
#pragma unroll
    for (int q2 = 0; q2 < 4; ++q2) {
      float4 rv = *reinterpret_cast<const float4*>(Rg + off + q2 * 4);
      *reinterpret_cast<float4*>(&Rs[off + q2 * 4]) = rv;
    }
  }
  int tok = tid & 63, seg = (tid >> 6) * 16;
  {
    size_t base = (size_t)(tc * 64 + tok) * kD + gr * 64 + seg;
#pragma unroll
    for (int q2 = 0; q2 < 4; ++q2) {
      float4 xv = *reinterpret_cast<const float4*>(x + base + q2 * 4);
      float4 yv = *reinterpret_cast<const float4*>(y + base + q2 * 4);
      float4 a = *reinterpret_cast<const float4*>(q0 + base + q2 * 4);
      float4 b = *reinterpret_cast<const float4*>(q1 + base + q2 * 4);
      float y0 = yv.x + a.x + b.x;
      float y1 = yv.y + a.y + b.y;
      float y2 = yv.z + a.z + b.z;
      float y3 = yv.w + a.w + b.w;
      xb[tok][seg + q2 * 4 + 0] = xv.x + (y0 - xv.x) * s;
      xb[tok][seg + q2 * 4 + 1] = xv.y + (y1 - xv.y) * s;
      xb[tok][seg + q2 * 4 + 2] = xv.z + (y2 - xv.z) * s;
      xb[tok][seg + q2 * 4 + 3] = xv.w + (y3 - xv.w) * s;
    }
  }
  __syncthreads();
  float o[16] = {};
  for (int i = 0; i < 64; ++i) {
    float xv = xb[tok][i];
#pragma unroll
    for (int d = 0; d < 16; ++d) o[d] += xv * Rs[i * 64 + seg + d];
  }
  float* outr = xout + (size_t)(tc * 64 + tok) * kD + gr * 64 + seg;
#pragma unroll
  for (int q2 = 0; q2 < 4; ++q2) {
    float4 ov = {o[q2 * 4 + 0], o[q2 * 4 + 1], o[q2 * 4 + 2], o[q2 * 4 + 3]};
    *reinterpret_cast<float4*>(outr + q2 * 4) = ov;
  }
}

// ---------------------------------------------------------------------------
extern "C" void kernel_launch(void* const* d_in, const int* in_sizes, int n_in,
                              void* d_out, int out_size, void* d_ws, size_t ws_size,
                              hipStream_t stream) {
  const int* tokens = (const int*)d_in[0];
  const float* embed_w = (const float*)d_in[1];
  const float* lm_head_w = (const float*)d_in[2];
  const float* norm_w = (const float*)d_in[3];
  const float* layer_gamma = (const float*)d_in[4];
  const float* layer_beta = (const float*)d_in[5];
  const float* iter_scale = (const float*)d_in[6];
  const float* skew_upper = (const float*)d_in[7];
  const float* ln1_w = (const float*)d_in[8];
  const float* ln2_w = (const float*)d_in[9];
  const float* wqkv = (const float*)d_in[10];
  const float* wo = (const float*)d_in[11];
  const float* w1 = (const float*)d_in[12];
  const float* w2 = (const float*)d_in[13];
  float* out = (float*)d_out;

  // ws: x(4MB) y(4MB) hb(2MB) ab(2MB) R(6.3MB) [+ lmhb 65.5MB if room]
  float* x = (float*)d_ws;
  float* y = x + (size_t)kT * kD;
  __bf16* hb = (__bf16*)(y + (size_t)kT * kD);
  __bf16* ab = hb + (size_t)kT * kD;
  float* R = (float*)(ab + (size_t)kT * kD);
  __bf16* lmhb = (__bf16*)(R + (size_t)kL * kG * 4096);
  bool ws_big = ws_size >= (size_t)(4670464 + 16384000) * 4;

  // d_out scratch (all dead before final lm_head GEMM writes out):
  __bf16* qkvb = (__bf16*)out;                       // 3.1M bf16
  __bf16* ffb = (__bf16*)(out + 1572864);            // 4.2M bf16
  __bf16* wqkvT = (__bf16*)(out + 3670016);          // [3072][1024]
  __bf16* woT = (__bf16*)(out + 5242880);            // [1024][1024]
  __bf16* w1T = (__bf16*)(out + 5767168);            // [4096][1024]
  __bf16* w2T = (__bf16*)(out + 7864320);            // [1024][4096]
  float* wop = out + 9961472;                        // wo partials 2x 1M f32
  float* w2p = out + 12058624;                       // w2 partials 2x 1M f32

  cayley_kernel<<<kL * kG, 256, 0, stream>>>(skew_upper, R);
  embed_kernel<<<kT * kD / 4 / 256, 256, 0, stream>>>(tokens, embed_w, x);
  convt_kernel<<<dim3(3 * kD / 64, kD / 64), 256, 0, stream>>>(wqkv, wqkvT, kD, 3 * kD);
  convt_kernel<<<dim3(kD / 64, kD / 64), 256, 0, stream>>>(wo, woT, kD, kD);
  convt_kernel<<<dim3(kFF / 64, kD / 64), 256, 0, stream>>>(w1, w1T, kD, kFF);
  convt_kernel<<<dim3(kD / 64, kFF / 64), 256, 0, stream>>>(w2, w2T, kFF, kD);
  if (ws_big)
    cast_kernel<<<kV * kD / 8 / 256, 256, 0, stream>>>(lm_head_w, lmhb);

  for (int l = 0; l < kL; ++l) {
    rms_kernel<true><<<kT, 256, 0, stream>>>(x, ln1_w, layer_gamma + (size_t)l * kD,
                                             layer_beta + (size_t)l * kD, hb);
    gemm_kernel<64, 128, 8, 3, false><<<(kT / 64) * (3 * kD / 128), 512, 0, stream>>>(
        hb, wqkvT, nullptr, qkvb, kT, 3 * kD, kD);
    fattn_kernel<<<dim3(kT / 64, kH), 256, 0, stream>>>(qkvb, ab);
    gemm_kernel<64, 64, 8, 0, false, 2><<<2 * (kT / 64) * (kD / 64), 512, 0, stream>>>(
        ab, woT, nullptr, wop, kT, kD, kD);
    rms_red_kernel<<<kT, 256, 0, stream>>>(x, wop, wop + (size_t)kT * kD, ln2_w, y, hb);
    gemm_kernel<64, 128, 8, 2, false><<<(kT / 64) * (kFF / 128), 512, 0, stream>>>(
        hb, w1T, nullptr, ffb, kT, kFF, kD);
    gemm_kernel<64, 64, 8, 0, false, 2><<<2 * (kT / 64) * (kD / 64), 512, 0, stream>>>(
        ffb, w2T, nullptr, w2p, kT, kD, kFF);
    blend_rot_kernel<<<dim3(kT / 64, kG), 256, 0, stream>>>(
        x, y, w2p, w2p + (size_t)kT * kD, iter_scale, l, R, x);
  }

  rms_kernel<false><<<kT, 256, 0, stream>>>(x, norm_w, nullptr, nullptr, hb);
  if (ws_big)
    gemm_kernel<256, 128, 8, 0, false><<<(kT / 256) * (kV / 128), 512, 0, stream>>>(
        hb, lmhb, nullptr, out, kT, kV, kD);
  else
    gemm_kernel<128, 128, 4, 0, true><<<(kT / 128) * (kV / 128), 256, 0, stream>>>(
        hb, lm_head_w, nullptr, out, kT, kV, kD);
}

// Round 12
// 2578.396 us; speedup vs baseline: 2.2893x; 1.0280x over previous
//
#include <hip/hip_runtime.h>
#include <hip/hip_bf16.h>
#include <math.h>

// Model dims
constexpr int kD = 1024;
constexpr int kH = 16;
constexpr int kV = 32000;
constexpr int kT = 1024;
constexpr int kG = 16;
constexpr int kFF = 4096;
constexpr int kL = 24;
constexpr int kNTRI = 2016;
#define EPSF 1e-6f
#define L2E 1.44269504088896f

typedef __bf16 bf16x8 __attribute__((ext_vector_type(8)));
typedef __bf16 bf16x4 __attribute__((ext_vector_type(4)));
typedef float f32x4 __attribute__((ext_vector_type(4)));

#define GLOAD16(g, l)                                                   \
  __builtin_amdgcn_global_load_lds(                                     \
      (const __attribute__((address_space(1))) void*)(g),               \
      (__attribute__((address_space(3))) void*)(l), 16, 0, 0)

// ---------------------------------------------------------------------------
// Cayley transform: R = (I - A/2)^-1 (I + A/2). One block per (layer,group).
// ---------------------------------------------------------------------------
__global__ __launch_bounds__(256) void cayley_kernel(const float* __restrict__ skew,
                                                     float* __restrict__ R) {
  int lg = blockIdx.x;
  int tid = threadIdx.x;
  int r = tid & 63, q = tid >> 6;
  __shared__ float Ms[64][65];
  __shared__ float Bs[64][65];
  const float* su = skew + (size_t)lg * kNTRI;
#pragma unroll
  for (int cc = 0; cc < 16; ++cc) {
    int c = q * 16 + cc;
    float a = 0.f;
    if (r < c) a = su[r * (127 - r) / 2 + (c - r - 1)];
    else if (r > c) a = -su[c * (127 - c) / 2 + (r - c - 1)];
    Ms[r][c] = (r == c ? 1.f : 0.f) - 0.5f * a;
    Bs[r][c] = (r == c ? 1.f : 0.f) + 0.5f * a;
  }
  __syncthreads();
  for (int k = 0; k < 64; ++k) {
    float ip = 1.f / Ms[k][k];
    float f = Ms[r][k];
    float beta = (r == k) ? (1.f - ip) : (f * ip);
    float mk[16], bk[16];
#pragma unroll
    for (int cc = 0; cc < 16; ++cc) {
      mk[cc] = Ms[k][q * 16 + cc];
      bk[cc] = Bs[k][q * 16 + cc];
    }
    __syncthreads();
#pragma unroll
    for (int cc = 0; cc < 16; ++cc) {
      int c = q * 16 + cc;
      Ms[r][c] -= beta * mk[cc];
      Bs[r][c] -= beta * bk[cc];
    }
    __syncthreads();
  }
  float* Ro = R + ((size_t)lg * 64 + r) * 64;
#pragma unroll
  for (int cc = 0; cc < 16; ++cc) Ro[q * 16 + cc] = Bs[r][q * 16 + cc];
}

// ---------------------------------------------------------------------------
// Embedding gather, float4-vectorized.
// ---------------------------------------------------------------------------
__global__ __launch_bounds__(256) void embed_kernel(const int* __restrict__ tok,
                                                    const float* __restrict__ ew,
                                                    float* __restrict__ x) {
  int i = blockIdx.x * 256 + threadIdx.x;
  int t = i >> 8;
  int d4 = i & 255;
  int v = tok[t];
  reinterpret_cast<float4*>(x)[i] =
      reinterpret_cast<const float4*>(ew + (size_t)v * kD)[d4];
}

// ---------------------------------------------------------------------------
// Elementwise f32 -> bf16 cast (lm_head), 8 elems/thread.
// ---------------------------------------------------------------------------
__global__ __launch_bounds__(256) void cast_kernel(const float* __restrict__ W,
                                                   __bf16* __restrict__ O) {
  size_t i = ((size_t)blockIdx.x * 256 + threadIdx.x) * 8;
  float4 f0 = *reinterpret_cast<const float4*>(W + i);
  float4 f1 = *reinterpret_cast<const float4*>(W + i + 4);
  bf16x8 v;
  v[0] = (__bf16)f0.x; v[1] = (__bf16)f0.y;
  v[2] = (__bf16)f0.z; v[3] = (__bf16)f0.w;
  v[4] = (__bf16)f1.x; v[5] = (__bf16)f1.y;
  v[6] = (__bf16)f1.z; v[7] = (__bf16)f1.w;
  *reinterpret_cast<bf16x8*>(O + i) = v;
}

// ---------------------------------------------------------------------------
// Weight convert+transpose: W f32 [K][N] -> WT bf16 [N][K]. 64x64 tiles.
// ---------------------------------------------------------------------------
__global__ __launch_bounds__(256) void convt_kernel(const float* __restrict__ W,
                                                    __bf16* __restrict__ WT,
                                                    int K, int N) {
  __shared__ float tile[64][65];
  int t = threadIdx.x;
  int n0 = blockIdx.x * 64, k0 = blockIdx.y * 64;
#pragma unroll
  for (int r = 0; r < 4; ++r) {
    int kr = r * 16 + (t >> 4);
    int nc = (t & 15) * 4;
    float4 v = *reinterpret_cast<const float4*>(&W[(size_t)(k0 + kr) * N + n0 + nc]);
    tile[kr][nc + 0] = v.x;
    tile[kr][nc + 1] = v.y;
    tile[kr][nc + 2] = v.z;
    tile[kr][nc + 3] = v.w;
  }
  __syncthreads();
#pragma unroll
  for (int r = 0; r < 2; ++r) {
    int idx = r * 256 + t;
    int nrow = idx >> 3, kc = (idx & 7) * 8;
    bf16x8 v;
#pragma unroll
    for (int j = 0; j < 8; ++j) v[j] = (__bf16)tile[kc + j][nrow];
    *reinterpret_cast<bf16x8*>(&WT[(size_t)(n0 + nrow) * K + k0 + kc]) = v;
  }
}

// ---------------------------------------------------------------------------
// RMSNorm -> bf16 out (shuffle-based reduction, 1 barrier).
// ---------------------------------------------------------------------------
template <bool AFFINE>
__global__ __launch_bounds__(256) void rms_kernel(const float* __restrict__ x,
                                                  const float* __restrict__ w,
                                                  const float* __restrict__ gamma,
                                                  const float* __restrict__ beta,
                                                  __bf16* __restrict__ out) {
  int t = blockIdx.x, tid = threadIdx.x;
  __shared__ float red4[4];
  float4 xv = reinterpret_cast<const float4*>(x + (size_t)t * kD)[tid];
  float ss = xv.x * xv.x + xv.y * xv.y + xv.z * xv.z + xv.w * xv.w;
#pragma unroll
  for (int o = 1; o < 64; o <<= 1) ss += __shfl_xor(ss, o);
  if ((tid & 63) == 0) red4[tid >> 6] = ss;
  __syncthreads();
  float tot = red4[0] + red4[1] + red4[2] + red4[3];
  float rms = rsqrtf(tot / (float)kD + EPSF);
  float4 wv = reinterpret_cast<const float4*>(w)[tid];
  float o0 = xv.x * rms * wv.x;
  float o1 = xv.y * rms * wv.y;
  float o2 = xv.z * rms * wv.z;
  float o3 = xv.w * rms * wv.w;
  if (AFFINE) {
    float4 gv = reinterpret_cast<const float4*>(gamma)[tid];
    float4 bv = reinterpret_cast<const float4*>(beta)[tid];
    o0 = o0 * gv.x + bv.x;
    o1 = o1 * gv.y + bv.y;
    o2 = o2 * gv.z + bv.z;
    o3 = o3 * gv.w + bv.w;
  }
  bf16x4 ov;
  ov[0] = (__bf16)o0; ov[1] = (__bf16)o1; ov[2] = (__bf16)o2; ov[3] = (__bf16)o3;
  *reinterpret_cast<bf16x4*>(out + (size_t)t * kD + tid * 4) = ov;
}

// ---------------------------------------------------------------------------
// Fused split-K reduce + residual + RMSNorm: y = x + p0 + p1 (f32 store),
// hb = rms(y) * w (bf16 store).
// ---------------------------------------------------------------------------
__global__ __launch_bounds__(256) void rms_red_kernel(const float* __restrict__ x,
                                                      const float* __restrict__ p0,
                                                      const float* __restrict__ p1,
                                                      const float* __restrict__ w,
                                                      float* __restrict__ y,
                                                      __bf16* __restrict__ hb) {
  int t = blockIdx.x, tid = threadIdx.x;
  __shared__ float red4[4];
  size_t base = (size_t)t * kD;
  float4 xv = reinterpret_cast<const float4*>(x + base)[tid];
  float4 a = reinterpret_cast<const float4*>(p0 + base)[tid];
  float4 b = reinterpret_cast<const float4*>(p1 + base)[tid];
  float4 yv;
  yv.x = xv.x + a.x + b.x;
  yv.y = xv.y + a.y + b.y;
  yv.z = xv.z + a.z + b.z;
  yv.w = xv.w + a.w + b.w;
  reinterpret_cast<float4*>(y + base)[tid] = yv;
  float ss = yv.x * yv.x + yv.y * yv.y + yv.z * yv.z + yv.w * yv.w;
#pragma unroll
  for (int o = 1; o < 64; o <<= 1) ss += __shfl_xor(ss, o);
  if ((tid & 63) == 0) red4[tid >> 6] = ss;
  __syncthreads();
  float tot = red4[0] + red4[1] + red4[2] + red4[3];
  float rms = rsqrtf(tot / (float)kD + EPSF);
  float4 wv = reinterpret_cast<const float4*>(w)[tid];
  bf16x4 ov;
  ov[0] = (__bf16)(yv.x * rms * wv.x);
  ov[1] = (__bf16)(yv.y * rms * wv.y);
  ov[2] = (__bf16)(yv.z * rms * wv.z);
  ov[3] = (__bf16)(yv.w * rms * wv.w);
  *reinterpret_cast<bf16x4*>(hb + base + tid * 4) = ov;
}

// ---------------------------------------------------------------------------
// MFMA GEMM, m97 structure + rule-21 swizzle, NW waves (4 -> 2x2 wave grid,
// 8 -> 2x4). global_load_lds width=16 with pre-swizzled global source,
// linear LDS dest, XOR-swizzled ds_read. BK=64. 1D grid, XCD-chunked swizzle.
// DBUF: double-buffered LDS + counted vmcnt (never 0 mid-loop) + raw
// s_barrier (T3/T4 "minimum 2-phase", m201 pattern) — for the K-short
// latency-bound per-layer GEMMs. KSPLIT: partial C (f32) at Cv + ks*M*N.
// BF32: B f32 [N][K], reg-staged converted (head fallback).
// EPI: 0=f32, 1=f32 acc+res, 2=gelu->bf16, 3=bf16.
// ---------------------------------------------------------------------------
template <int BM, int BN, int NW, int EPI, bool BF32, int KSPLIT = 1, bool DBUF = false>
__global__ __launch_bounds__(NW * 64) void gemm_kernel(
    const __bf16* __restrict__ A, const void* __restrict__ Bv,
    const float* res, void* __restrict__ Cv, int M, int N, int K) {
  constexpr int WCOLS = (NW == 4) ? 2 : 4;
  constexpr int FM = (BM / 2) / 16;
  constexpr int FN = (BN / WCOLS) / 16;
  constexpr int AISS = BM / 8 / NW;
  constexpr int BISS = BN / 8 / NW;
  constexpr int NI = AISS + BISS;  // per-wave gloads per K-step
  __shared__ __bf16 As[(DBUF ? 2 : 1) * BM * 64];
  __shared__ __bf16 Bs[(DBUF ? 2 : 1) * BN * 64];
  char* AsB = (char*)As;
  char* BsB = (char*)Bs;
  int tid = threadIdx.x;
  int w = tid >> 6, lane = tid & 63;
  int mt = M / BM, nt = N / BN;
  int cpx = gridDim.x >> 3;
  int id = (blockIdx.x & 7) * cpx + (blockIdx.x >> 3);
  int ks_id = id / (mt * nt);
  int rem = id % (mt * nt);
  int bm = (rem % mt) * BM, bn = (rem / mt) * BN;
  int kbeg = ks_id * (K / KSPLIT), kend = kbeg + K / KSPLIT;
  int lrow = lane & 15, g = lane >> 4;
  int grow = lane >> 3;                       // staging: row within 8-row slab
  int gswz = ((lane & 7) ^ grow) * 8;         // pre-swizzled source col (elems)
  int rsw = (lrow & 7) << 4;                  // read-side XOR (bytes)
  int wm = (NW == 4) ? (w >> 1) : (w >> 2);
  int wn = (NW == 4) ? (w & 1) : (w & 3);
  int wr = wm * (BM / 2), wc = wn * (BN / WCOLS);
  f32x4 acc[FM][FN] = {};
  const __bf16* B16 = (const __bf16*)Bv;
  const float* B32 = (const float*)Bv;

  auto stage = [&](int buf, int k0) {
#pragma unroll
    for (int i = 0; i < AISS; ++i) {
      int rbase = (i * NW + w) * 8;
      GLOAD16(&A[(size_t)(bm + rbase + grow) * K + k0 + gswz],
              &As[buf * BM * 64 + rbase * 64]);
    }
#pragma unroll
    for (int i = 0; i < BISS; ++i) {
      int rbase = (i * NW + w) * 8;
      GLOAD16(&B16[(size_t)(bn + rbase + grow) * K + k0 + gswz],
              &Bs[buf * BN * 64 + rbase * 64]);
    }
  };

  auto compute = [&](int buf) {
    int offA = buf * BM * 128, offB = buf * BN * 128;
#pragma unroll
    for (int ks = 0; ks < 2; ++ks) {
      bf16x8 af[FM], bg[FN];
#pragma unroll
      for (int i = 0; i < FM; ++i)
        af[i] = *reinterpret_cast<const bf16x8*>(
            AsB + offA + (wr + i * 16 + lrow) * 128 + ((ks * 64 + g * 16) ^ rsw));
#pragma unroll
      for (int j = 0; j < FN; ++j)
        bg[j] = *reinterpret_cast<const bf16x8*>(
            BsB + offB + (wc + j * 16 + lrow) * 128 + ((ks * 64 + g * 16) ^ rsw));
#pragma unroll
      for (int i = 0; i < FM; ++i)
#pragma unroll
        for (int j = 0; j < FN; ++j)
          acc[i][j] = __builtin_amdgcn_mfma_f32_16x16x32_bf16(af[i], bg[j],
                                                              acc[i][j], 0, 0, 0);
    }
  };

  if constexpr (DBUF && !BF32) {
    stage(0, kbeg);
    int cur = 0;
    for (int k0 = kbeg; k0 < kend; k0 += 64) {
      bool more = (k0 + 64 < kend);
      if (more) stage(cur ^ 1, k0 + 64);
      if (more) {
        if constexpr (NI == 2) asm volatile("s_waitcnt vmcnt(2)" ::: "memory");
        else if constexpr (NI == 3) asm volatile("s_waitcnt vmcnt(3)" ::: "memory");
        else if constexpr (NI == 4) asm volatile("s_waitcnt vmcnt(4)" ::: "memory");
        else if constexpr (NI == 6) asm volatile("s_waitcnt vmcnt(6)" ::: "memory");
        else asm volatile("s_waitcnt vmcnt(0)" ::: "memory");
      } else {
        asm volatile("s_waitcnt vmcnt(0)" ::: "memory");
      }
      __builtin_amdgcn_sched_barrier(0);
      __builtin_amdgcn_s_barrier();
      compute(cur);
      __builtin_amdgcn_s_barrier();
      cur ^= 1;
    }
  } else {
    for (int k0 = kbeg; k0 < kend; k0 += 64) {
      if (!BF32) {
        stage(0, k0);
      } else {
#pragma unroll
        for (int rrep = 0; rrep < BN * 8 / (NW * 64); ++rrep) {
          int cid = rrep * NW * 64 + tid;
          int row = cid >> 3, kc = (cid & 7) * 8;
          const float* src = &B32[(size_t)(bn + row) * K + k0 + kc];
          float4 f0 = *reinterpret_cast<const float4*>(src);
          float4 f1 = *reinterpret_cast<const float4*>(src + 4);
          bf16x8 v;
          v[0] = (__bf16)f0.x; v[1] = (__bf16)f0.y;
          v[2] = (__bf16)f0.z; v[3] = (__bf16)f0.w;
          v[4] = (__bf16)f1.x; v[5] = (__bf16)f1.y;
          v[6] = (__bf16)f1.z; v[7] = (__bf16)f1.w;
          int swc = ((cid & 7) ^ (row & 7)) * 16;
          *reinterpret_cast<bf16x8*>(BsB + row * 128 + swc) = v;
        }
#pragma unroll
        for (int i = 0; i < AISS; ++i) {
          int rbase = (i * NW + w) * 8;
          GLOAD16(&A[(size_t)(bm + rbase + grow) * K + k0 + gswz], &As[rbase * 64]);
        }
      }
      __syncthreads();
      compute(0);
      __syncthreads();
    }
  }

  float* Cp = (float*)Cv + (size_t)ks_id * M * N;
  int crow0 = bm + wr + g * 4;
  int ccol0 = bn + wc + lrow;
#pragma unroll
  for (int i = 0; i < FM; ++i) {
#pragma unroll
    for (int j = 0; j < FN; ++j) {
#pragma unroll
      for (int r = 0; r < 4; ++r) {
        int row = crow0 + i * 16 + r;
        int col = ccol0 + j * 16;
        size_t idx = (size_t)row * N + col;
        float v = acc[i][j][r];
        if (EPI == 1) v += res[idx];
        if (EPI == 2) {
          float u = v;
          float z = 0.7978845608028654f * (u + 0.044715f * u * u * u);
          float ez = exp2f(z * (2.f * L2E));
          v = u * ez / (1.f + ez);
        }
        if (EPI == 2 || EPI == 3) ((__bf16*)Cv)[idx] = (__bf16)v;
        else Cp[idx] = v;
      }
    }
  }
}

// ---------------------------------------------------------------------------
// Flash attention (causal), bf16 MFMA, swapped QK^T, per-lane online softmax,
// K/V double-buffered with issue-early / write-late staging.
// ---------------------------------------------------------------------------
__global__ __launch_bounds__(256) void fattn_kernel(const __bf16* __restrict__ qkv,
                                                    __bf16* __restrict__ out) {
  __shared__ __bf16 Ks[2][64 * 64];
  __shared__ __bf16 Vt[2][64 * 64];
  __shared__ __bf16 Ps[4 * 16 * 64];
  int tid = threadIdx.x;
  int bq = blockIdx.x * 64;
  int h = blockIdx.y;
  int w = tid >> 6, lane = tid & 63;
  int g = lane >> 4, lr = lane & 15;

  bf16x8 qf[2];
  const __bf16* qbase = qkv + (size_t)(bq + w * 16 + lr) * (3 * kD) + h * 64;
#pragma unroll
  for (int ks = 0; ks < 2; ++ks) {
    bf16x8 v = *reinterpret_cast<const bf16x8*>(qbase + ks * 32 + g * 8);
#pragma unroll
    for (int j = 0; j < 8; ++j) qf[ks][j] = (__bf16)((float)v[j] * 0.125f);
  }

  f32x4 acc[4] = {};
  float m = -1e30f, lsum = 0.f;

  int srow = tid >> 2, sseg = tid & 3;
  int vk = tid & 63, vd0 = (tid >> 6) * 16;
  char* PwB = (char*)(Ps + w * (16 * 64));
  int psw = (lr & 7) << 4;

  bf16x8 ka, kb2, va, vb;
  int ntiles = bq / 64 + 1;

  {
    const __bf16* src = qkv + (size_t)(srow) * (3 * kD) + kD + h * 64 + sseg * 16;
    ka = *reinterpret_cast<const bf16x8*>(src);
    kb2 = *reinterpret_cast<const bf16x8*>(src + 8);
    const __bf16* vsrc = qkv + (size_t)(vk) * (3 * kD) + 2 * kD + h * 64 + vd0;
    va = *reinterpret_cast<const bf16x8*>(vsrc);
    vb = *reinterpret_cast<const bf16x8*>(vsrc + 8);
    char* KsB = (char*)Ks[0];
    char* VtB = (char*)Vt[0];
    int bc = sseg * 32, sw = (srow & 7) << 4;
    *reinterpret_cast<bf16x8*>(KsB + srow * 128 + (bc ^ sw)) = ka;
    *reinterpret_cast<bf16x8*>(KsB + srow * 128 + ((bc + 16) ^ sw)) = kb2;
#pragma unroll
    for (int i = 0; i < 8; ++i) {
      int d = vd0 + i;
      *((__bf16*)(VtB + d * 128 + ((vk * 2) ^ ((d & 7) << 4)))) = va[i];
      d = vd0 + 8 + i;
      *((__bf16*)(VtB + d * 128 + ((vk * 2) ^ ((d & 7) << 4)))) = vb[i];
    }
  }

  int cur = 0;
  for (int kt = 0; kt < ntiles; ++kt) {
    if (kt + 1 < ntiles) {
      const __bf16* src =
          qkv + (size_t)((kt + 1) * 64 + srow) * (3 * kD) + kD + h * 64 + sseg * 16;
      ka = *reinterpret_cast<const bf16x8*>(src);
      kb2 = *reinterpret_cast<const bf16x8*>(src + 8);
      const __bf16* vsrc =
          qkv + (size_t)((kt + 1) * 64 + vk) * (3 * kD) + 2 * kD + h * 64 + vd0;
      va = *reinterpret_cast<const bf16x8*>(vsrc);
      vb = *reinterpret_cast<const bf16x8*>(vsrc + 8);
    }
    __syncthreads();

    char* KsB = (char*)Ks[cur];
    char* VtB = (char*)Vt[cur];
    bool diag = (kt == ntiles - 1);
    int jmax = diag ? w : 3;

    f32x4 s[4];
#pragma unroll
    for (int jj = 0; jj < 4; ++jj) {
      if (jj <= jmax) {
        int krow = jj * 16 + lr;
        int ksw = (lr & 7) << 4;
        bf16x8 k0 = *reinterpret_cast<const bf16x8*>(KsB + krow * 128 + ((g * 16) ^ ksw));
        bf16x8 k1 = *reinterpret_cast<const bf16x8*>(KsB + krow * 128 + ((64 + g * 16) ^ ksw));
        f32x4 z = {};
        z = __builtin_amdgcn_mfma_f32_16x16x32_bf16(k0, qf[0], z, 0, 0, 0);
        s[jj] = __builtin_amdgcn_mfma_f32_16x16x32_bf16(k1, qf[1], z, 0, 0, 0);
      } else {
        s[jj] = f32x4{-1e30f, -1e30f, -1e30f, -1e30f};
      }
    }
    if (diag) {
#pragma unroll
      for (int r = 0; r < 4; ++r)
        if (g * 4 + r > lr) s[w][r] = -1e30f;
    }

    float mt = -1e30f;
#pragma unroll
    for (int jj = 0; jj < 4; ++jj)
#pragma unroll
      for (int r = 0; r < 4; ++r) mt = fmaxf(mt, s[jj][r]);
    mt = fmaxf(mt, __shfl_xor(mt, 16));
    mt = fmaxf(mt, __shfl_xor(mt, 32));
    float mn = fmaxf(m, mt);
    float sc = exp2f((m - mn) * L2E);
    float p[4][4];
    float rs = 0.f;
#pragma unroll
    for (int jj = 0; jj < 4; ++jj)
#pragma unroll
      for (int r = 0; r < 4; ++r) {
        float e = exp2f((s[jj][r] - mn) * L2E);
        p[jj][r] = e;
        rs += e;
      }
    rs += __shfl_xor(rs, 16);
    rs += __shfl_xor(rs, 32);
    lsum = lsum * sc + rs;
    m = mn;
#pragma unroll
    for (int r = 0; r < 4; ++r) {
      float s4 = __shfl(sc, 20 * g + r);
#pragma unroll
      for (int dt = 0; dt < 4; ++dt) acc[dt][r] *= s4;
    }

#pragma unroll
    for (int jj = 0; jj < 4; ++jj) {
      bf16x4 pv;
#pragma unroll
      for (int r = 0; r < 4; ++r) pv[r] = (__bf16)p[jj][r];
      *reinterpret_cast<bf16x4*>(PwB + lr * 128 + ((jj * 32 + g * 8) ^ psw)) = pv;
    }

    {
      bf16x8 pa0 = *reinterpret_cast<const bf16x8*>(PwB + lr * 128 + ((g * 16) ^ psw));
      bf16x8 pa1 = *reinterpret_cast<const bf16x8*>(PwB + lr * 128 + ((64 + g * 16) ^ psw));
#pragma unroll
      for (int dt = 0; dt < 4; ++dt) {
        int vrow = dt * 16 + lr;
        int vsw = (lr & 7) << 4;
        bf16x8 vb0 = *reinterpret_cast<const bf16x8*>(VtB + vrow * 128 + ((g * 16) ^ vsw));
        bf16x8 vb1 = *reinterpret_cast<const bf16x8*>(VtB + vrow * 128 + ((64 + g * 16) ^ vsw));
        acc[dt] = __builtin_amdgcn_mfma_f32_16x16x32_bf16(pa0, vb0, acc[dt], 0, 0, 0);
        acc[dt] = __builtin_amdgcn_mfma_f32_16x16x32_bf16(pa1, vb1, acc[dt], 0, 0, 0);
      }
    }
    __syncthreads();

    if (kt + 1 < ntiles) {
      char* KsN = (char*)Ks[cur ^ 1];
      char* VtN = (char*)Vt[cur ^ 1];
      int bc = sseg * 32, sw = (srow & 7) << 4;
      *reinterpret_cast<bf16x8*>(KsN + srow * 128 + (bc ^ sw)) = ka;
      *reinterpret_cast<bf16x8*>(KsN + srow * 128 + ((bc + 16) ^ sw)) = kb2;
#pragma unroll
      for (int i = 0; i < 8; ++i) {
        int d = vd0 + i;
        *((__bf16*)(VtN + d * 128 + ((vk * 2) ^ ((d & 7) << 4)))) = va[i];
        d = vd0 + 8 + i;
        *((__bf16*)(VtN + d * 128 + ((vk * 2) ^ ((d & 7) << 4)))) = vb[i];
      }
      cur ^= 1;
    }
  }

  float linv = 1.f / lsum;
#pragma unroll
  for (int r = 0; r < 4; ++r) {
    float ir = __shfl(linv, 20 * g + r);
    int row = bq + w * 16 + g * 4 + r;
#pragma unroll
    for (int dt = 0; dt < 4; ++dt)
      out[(size_t)row * kD + h * 64 + dt * 16 + lr] = (__bf16)(acc[dt][r] * ir);
  }
}

// ---------------------------------------------------------------------------
// Fused w2 split-K reduce + residual blend + group rotation, (tc, gr) blocks.
// ---------------------------------------------------------------------------
__global__ __launch_bounds__(256) void blend_rot_kernel(const float* x,
                                                        const float* y,
                                                        const float* q0,
                                                        const float* q1,
                                                        const float* iscale,
                                                        int l,
                                                        const float* __restrict__ Rall,
                                                        float* xout) {
  int tc = blockIdx.x, gr = blockIdx.y;
  int tid = threadIdx.x;
  __shared__ float Rs[64 * 64];
  __shared__ float xb[64][65];
  float s = iscale[l];
  const float* Rg = Rall + ((size_t)l * kG + gr) * 4096;
  {
    int off = tid * 16;
#pragma unroll
    for (int q2 = 0; q2 < 4; ++q2) {
      float4 rv = *reinterpret_cast<const float4*>(Rg + off + q2 * 4);
      *reinterpret_cast<float4*>(&Rs[off + q2 * 4]) = rv;
    }
  }
  int tok = tid & 63, seg = (tid >> 6) * 16;
  {
    size_t base = (size_t)(tc * 64 + tok) * kD + gr * 64 + seg;
#pragma unroll
    for (int q2 = 0; q2 < 4; ++q2) {
      float4 xv = *reinterpret_cast<const float4*>(x + base + q2 * 4);
      float4 yv = *reinterpret_cast<const float4*>(y + base + q2 * 4);
      float4 a = *reinterpret_cast<const float4*>(q0 + base + q2 * 4);
      float4 b = *reinterpret_cast<const float4*>(q1 + base + q2 * 4);
      float y0 = yv.x + a.x + b.x;
      float y1 = yv.y + a.y + b.y;
      float y2 = yv.z + a.z + b.z;
      float y3 = yv.w + a.w + b.w;
      xb[tok][seg + q2 * 4 + 0] = xv.x + (y0 - xv.x) * s;
      xb[tok][seg + q2 * 4 + 1] = xv.y + (y1 - xv.y) * s;
      xb[tok][seg + q2 * 4 + 2] = xv.z + (y2 - xv.z) * s;
      xb[tok][seg + q2 * 4 + 3] = xv.w + (y3 - xv.w) * s;
    }
  }
  __syncthreads();
  float o[16] = {};
  for (int i = 0; i < 64; ++i) {
    float xv = xb[tok][i];
#pragma unroll
    for (int d = 0; d < 16; ++d) o[d] += xv * Rs[i * 64 + seg + d];
  }
  float* outr = xout + (size_t)(tc * 64 + tok) * kD + gr * 64 + seg;
#pragma unroll
  for (int q2 = 0; q2 < 4; ++q2) {
    float4 ov = {o[q2 * 4 + 0], o[q2 * 4 + 1], o[q2 * 4 + 2], o[q2 * 4 + 3]};
    *reinterpret_cast<float4*>(outr + q2 * 4) = ov;
  }
}

// ---------------------------------------------------------------------------
extern "C" void kernel_launch(void* const* d_in, const int* in_sizes, int n_in,
                              void* d_out, int out_size, void* d_ws, size_t ws_size,
                              hipStream_t stream) {
  const int* tokens = (const int*)d_in[0];
  const float* embed_w = (const float*)d_in[1];
  const float* lm_head_w = (const float*)d_in[2];
  const float* norm_w = (const float*)d_in[3];
  const float* layer_gamma = (const float*)d_in[4];
  const float* layer_beta = (const float*)d_in[5];
  const float* iter_scale = (const float*)d_in[6];
  const float* skew_upper = (const float*)d_in[7];
  const float* ln1_w = (const float*)d_in[8];
  const float* ln2_w = (const float*)d_in[9];
  const float* wqkv = (const float*)d_in[10];
  const float* wo = (const float*)d_in[11];
  const float* w1 = (const float*)d_in[12];
  const float* w2 = (const float*)d_in[13];
  float* out = (float*)d_out;

  // ws: x(4MB) y(4MB) hb(2MB) ab(2MB) R(6.3MB) [+ lmhb 65.5MB if room]
  float* x = (float*)d_ws;
  float* y = x + (size_t)kT * kD;
  __bf16* hb = (__bf16*)(y + (size_t)kT * kD);
  __bf16* ab = hb + (size_t)kT * kD;
  float* R = (float*)(ab + (size_t)kT * kD);
  __bf16* lmhb = (__bf16*)(R + (size_t)kL * kG * 4096);
  bool ws_big = ws_size >= (size_t)(4670464 + 16384000) * 4;

  // d_out scratch (all dead before final lm_head GEMM writes out):
  __bf16* qkvb = (__bf16*)out;                       // 3.1M bf16
  __bf16* ffb = (__bf16*)(out + 1572864);            // 4.2M bf16
  __bf16* wqkvT = (__bf16*)(out + 3670016);          // [3072][1024]
  __bf16* woT = (__bf16*)(out + 5242880);            // [1024][1024]
  __bf16* w1T = (__bf16*)(out + 5767168);            // [4096][1024]
  __bf16* w2T = (__bf16*)(out + 7864320);            // [1024][4096]
  float* wop = out + 9961472;                        // wo partials 2x 1M f32
  float* w2p = out + 12058624;                       // w2 partials 2x 1M f32

  cayley_kernel<<<kL * kG, 256, 0, stream>>>(skew_upper, R);
  embed_kernel<<<kT * kD / 4 / 256, 256, 0, stream>>>(tokens, embed_w, x);
  convt_kernel<<<dim3(3 * kD / 64, kD / 64), 256, 0, stream>>>(wqkv, wqkvT, kD, 3 * kD);
  convt_kernel<<<dim3(kD / 64, kD / 64), 256, 0, stream>>>(wo, woT, kD, kD);
  convt_kernel<<<dim3(kFF / 64, kD / 64), 256, 0, stream>>>(w1, w1T, kD, kFF);
  convt_kernel<<<dim3(kD / 64, kFF / 64), 256, 0, stream>>>(w2, w2T, kFF, kD);
  if (ws_big)
    cast_kernel<<<kV * kD / 8 / 256, 256, 0, stream>>>(lm_head_w, lmhb);

  for (int l = 0; l < kL; ++l) {
    rms_kernel<true><<<kT, 256, 0, stream>>>(x, ln1_w, layer_gamma + (size_t)l * kD,
                                             layer_beta + (size_t)l * kD, hb);
    gemm_kernel<64, 128, 8, 3, false, 1, true>
        <<<(kT / 64) * (3 * kD / 128), 512, 0, stream>>>(
        hb, wqkvT, nullptr, qkvb, kT, 3 * kD, kD);
    fattn_kernel<<<dim3(kT / 64, kH), 256, 0, stream>>>(qkvb, ab);
    gemm_kernel<64, 64, 8, 0, false, 2, true>
        <<<2 * (kT / 64) * (kD / 64), 512, 0, stream>>>(
        ab, woT, nullptr, wop, kT, kD, kD);
    rms_red_kernel<<<kT, 256, 0, stream>>>(x, wop, wop + (size_t)kT * kD, ln2_w, y, hb);
    gemm_kernel<64, 128, 8, 2, false, 1, true>
        <<<(kT / 64) * (kFF / 128), 512, 0, stream>>>(
        hb, w1T, nullptr, ffb, kT, kFF, kD);
    gemm_kernel<64, 64, 8, 0, false, 2, true>
        <<<2 * (kT / 64) * (kD / 64), 512, 0, stream>>>(
        ffb, w2T, nullptr, w2p, kT, kD, kFF);
    blend_rot_kernel<<<dim3(kT / 64, kG), 256, 0, stream>>>(
        x, y, w2p, w2p + (size_t)kT * kD, iter_scale, l, R, x);
  }

  rms_kernel<false><<<kT, 256, 0, stream>>>(x, norm_w, nullptr, nullptr, hb);
  if (ws_big)
    gemm_kernel<256, 128, 8, 0, false><<<(kT / 256) * (kV / 128), 512, 0, stream>>>(
        hb, lmhb, nullptr, out, kT, kV, kD);
  else
    gemm_kernel<128, 128, 4, 0, true><<<(kT / 128) * (kV / 128), 256, 0, stream>>>(
        hb, lm_head_w, nullptr, out, kT, kV, kD);
}

// Round 13
// 2561.927 us; speedup vs baseline: 2.3040x; 1.0064x over previous
//
#include <hip/hip_runtime.h>
#include <hip/hip_bf16.h>
#include <math.h>

// Model dims
constexpr int kD = 1024;
constexpr int kH = 16;
constexpr int kV = 32000;
constexpr int kT = 1024;
constexpr int kG = 16;
constexpr int kFF = 4096;
constexpr int kL = 24;
constexpr int kNTRI = 2016;
#define EPSF 1e-6f
#define L2E 1.44269504088896f

typedef __bf16 bf16x8 __attribute__((ext_vector_type(8)));
typedef __bf16 bf16x4 __attribute__((ext_vector_type(4)));
typedef float f32x4 __attribute__((ext_vector_type(4)));

#define GLOAD16(g, l)                                                   \
  __builtin_amdgcn_global_load_lds(                                     \
      (const __attribute__((address_space(1))) void*)(g),               \
      (__attribute__((address_space(3))) void*)(l), 16, 0, 0)

// ---------------------------------------------------------------------------
// Cayley transform: R = (I - A/2)^-1 (I + A/2). One block per (layer,group).
// ---------------------------------------------------------------------------
__global__ __launch_bounds__(256) void cayley_kernel(const float* __restrict__ skew,
                                                     float* __restrict__ R) {
  int lg = blockIdx.x;
  int tid = threadIdx.x;
  int r = tid & 63, q = tid >> 6;
  __shared__ float Ms[64][65];
  __shared__ float Bs[64][65];
  const float* su = skew + (size_t)lg * kNTRI;
#pragma unroll
  for (int cc = 0; cc < 16; ++cc) {
    int c = q * 16 + cc;
    float a = 0.f;
    if (r < c) a = su[r * (127 - r) / 2 + (c - r - 1)];
    else if (r > c) a = -su[c * (127 - c) / 2 + (r - c - 1)];
    Ms[r][c] = (r == c ? 1.f : 0.f) - 0.5f * a;
    Bs[r][c] = (r == c ? 1.f : 0.f) + 0.5f * a;
  }
  __syncthreads();
  for (int k = 0; k < 64; ++k) {
    float ip = 1.f / Ms[k][k];
    float f = Ms[r][k];
    float beta = (r == k) ? (1.f - ip) : (f * ip);
    float mk[16], bk[16];
#pragma unroll
    for (int cc = 0; cc < 16; ++cc) {
      mk[cc] = Ms[k][q * 16 + cc];
      bk[cc] = Bs[k][q * 16 + cc];
    }
    __syncthreads();
#pragma unroll
    for (int cc = 0; cc < 16; ++cc) {
      int c = q * 16 + cc;
      Ms[r][c] -= beta * mk[cc];
      Bs[r][c] -= beta * bk[cc];
    }
    __syncthreads();
  }
  float* Ro = R + ((size_t)lg * 64 + r) * 64;
#pragma unroll
  for (int cc = 0; cc < 16; ++cc) Ro[q * 16 + cc] = Bs[r][q * 16 + cc];
}

// ---------------------------------------------------------------------------
// Embedding gather, float4-vectorized.
// ---------------------------------------------------------------------------
__global__ __launch_bounds__(256) void embed_kernel(const int* __restrict__ tok,
                                                    const float* __restrict__ ew,
                                                    float* __restrict__ x) {
  int i = blockIdx.x * 256 + threadIdx.x;
  int t = i >> 8;
  int d4 = i & 255;
  int v = tok[t];
  reinterpret_cast<float4*>(x)[i] =
      reinterpret_cast<const float4*>(ew + (size_t)v * kD)[d4];
}

// ---------------------------------------------------------------------------
// Elementwise f32 -> bf16 cast (lm_head), 8 elems/thread.
// ---------------------------------------------------------------------------
__global__ __launch_bounds__(256) void cast_kernel(const float* __restrict__ W,
                                                   __bf16* __restrict__ O) {
  size_t i = ((size_t)blockIdx.x * 256 + threadIdx.x) * 8;
  float4 f0 = *reinterpret_cast<const float4*>(W + i);
  float4 f1 = *reinterpret_cast<const float4*>(W + i + 4);
  bf16x8 v;
  v[0] = (__bf16)f0.x; v[1] = (__bf16)f0.y;
  v[2] = (__bf16)f0.z; v[3] = (__bf16)f0.w;
  v[4] = (__bf16)f1.x; v[5] = (__bf16)f1.y;
  v[6] = (__bf16)f1.z; v[7] = (__bf16)f1.w;
  *reinterpret_cast<bf16x8*>(O + i) = v;
}

// ---------------------------------------------------------------------------
// Weight convert+transpose: W f32 [K][N] -> WT bf16 [N][K]. 64x64 tiles.
// ---------------------------------------------------------------------------
__global__ __launch_bounds__(256) void convt_kernel(const float* __restrict__ W,
                                                    __bf16* __restrict__ WT,
                                                    int K, int N) {
  __shared__ float tile[64][65];
  int t = threadIdx.x;
  int n0 = blockIdx.x * 64, k0 = blockIdx.y * 64;
#pragma unroll
  for (int r = 0; r < 4; ++r) {
    int kr = r * 16 + (t >> 4);
    int nc = (t & 15) * 4;
    float4 v = *reinterpret_cast<const float4*>(&W[(size_t)(k0 + kr) * N + n0 + nc]);
    tile[kr][nc + 0] = v.x;
    tile[kr][nc + 1] = v.y;
    tile[kr][nc + 2] = v.z;
    tile[kr][nc + 3] = v.w;
  }
  __syncthreads();
#pragma unroll
  for (int r = 0; r < 2; ++r) {
    int idx = r * 256 + t;
    int nrow = idx >> 3, kc = (idx & 7) * 8;
    bf16x8 v;
#pragma unroll
    for (int j = 0; j < 8; ++j) v[j] = (__bf16)tile[kc + j][nrow];
    *reinterpret_cast<bf16x8*>(&WT[(size_t)(n0 + nrow) * K + k0 + kc]) = v;
  }
}

// ---------------------------------------------------------------------------
// RMSNorm -> bf16 out (shuffle-based reduction, 1 barrier).
// ---------------------------------------------------------------------------
template <bool AFFINE>
__global__ __launch_bounds__(256) void rms_kernel(const float* __restrict__ x,
                                                  const float* __restrict__ w,
                                                  const float* __restrict__ gamma,
                                                  const float* __restrict__ beta,
                                                  __bf16* __restrict__ out) {
  int t = blockIdx.x, tid = threadIdx.x;
  __shared__ float red4[4];
  float4 xv = reinterpret_cast<const float4*>(x + (size_t)t * kD)[tid];
  float ss = xv.x * xv.x + xv.y * xv.y + xv.z * xv.z + xv.w * xv.w;
#pragma unroll
  for (int o = 1; o < 64; o <<= 1) ss += __shfl_xor(ss, o);
  if ((tid & 63) == 0) red4[tid >> 6] = ss;
  __syncthreads();
  float tot = red4[0] + red4[1] + red4[2] + red4[3];
  float rms = rsqrtf(tot / (float)kD + EPSF);
  float4 wv = reinterpret_cast<const float4*>(w)[tid];
  float o0 = xv.x * rms * wv.x;
  float o1 = xv.y * rms * wv.y;
  float o2 = xv.z * rms * wv.z;
  float o3 = xv.w * rms * wv.w;
  if (AFFINE) {
    float4 gv = reinterpret_cast<const float4*>(gamma)[tid];
    float4 bv = reinterpret_cast<const float4*>(beta)[tid];
    o0 = o0 * gv.x + bv.x;
    o1 = o1 * gv.y + bv.y;
    o2 = o2 * gv.z + bv.z;
    o3 = o3 * gv.w + bv.w;
  }
  bf16x4 ov;
  ov[0] = (__bf16)o0; ov[1] = (__bf16)o1; ov[2] = (__bf16)o2; ov[3] = (__bf16)o3;
  *reinterpret_cast<bf16x4*>(out + (size_t)t * kD + tid * 4) = ov;
}

// ---------------------------------------------------------------------------
// Fused split-K reduce + residual + RMSNorm: y = x + p0 + p1 (f32 store),
// hb = rms(y) * w (bf16 store).
// ---------------------------------------------------------------------------
__global__ __launch_bounds__(256) void rms_red_kernel(const float* __restrict__ x,
                                                      const float* __restrict__ p0,
                                                      const float* __restrict__ p1,
                                                      const float* __restrict__ w,
                                                      float* __restrict__ y,
                                                      __bf16* __restrict__ hb) {
  int t = blockIdx.x, tid = threadIdx.x;
  __shared__ float red4[4];
  size_t base = (size_t)t * kD;
  float4 xv = reinterpret_cast<const float4*>(x + base)[tid];
  float4 a = reinterpret_cast<const float4*>(p0 + base)[tid];
  float4 b = reinterpret_cast<const float4*>(p1 + base)[tid];
  float4 yv;
  yv.x = xv.x + a.x + b.x;
  yv.y = xv.y + a.y + b.y;
  yv.z = xv.z + a.z + b.z;
  yv.w = xv.w + a.w + b.w;
  reinterpret_cast<float4*>(y + base)[tid] = yv;
  float ss = yv.x * yv.x + yv.y * yv.y + yv.z * yv.z + yv.w * yv.w;
#pragma unroll
  for (int o = 1; o < 64; o <<= 1) ss += __shfl_xor(ss, o);
  if ((tid & 63) == 0) red4[tid >> 6] = ss;
  __syncthreads();
  float tot = red4[0] + red4[1] + red4[2] + red4[3];
  float rms = rsqrtf(tot / (float)kD + EPSF);
  float4 wv = reinterpret_cast<const float4*>(w)[tid];
  bf16x4 ov;
  ov[0] = (__bf16)(yv.x * rms * wv.x);
  ov[1] = (__bf16)(yv.y * rms * wv.y);
  ov[2] = (__bf16)(yv.z * rms * wv.z);
  ov[3] = (__bf16)(yv.w * rms * wv.w);
  *reinterpret_cast<bf16x4*>(hb + base + tid * 4) = ov;
}

// ---------------------------------------------------------------------------
// MFMA GEMM, m97 structure + rule-21 swizzle, NW waves.
// DBUF: double-buffered LDS + counted vmcnt + raw s_barrier.
// KSPLIT: partial C (f32) at Cv + ks*M*N. BF32: head fallback.
// EPI: 0=f32, 1=f32 acc+res, 2=gelu->bf16, 3=bf16.
// ---------------------------------------------------------------------------
template <int BM, int BN, int NW, int EPI, bool BF32, int KSPLIT = 1, bool DBUF = false>
__global__ __launch_bounds__(NW * 64) void gemm_kernel(
    const __bf16* __restrict__ A, const void* __restrict__ Bv,
    const float* res, void* __restrict__ Cv, int M, int N, int K) {
  constexpr int WCOLS = (NW == 4) ? 2 : 4;
  constexpr int FM = (BM / 2) / 16;
  constexpr int FN = (BN / WCOLS) / 16;
  constexpr int AISS = BM / 8 / NW;
  constexpr int BISS = BN / 8 / NW;
  constexpr int NI = AISS + BISS;
  __shared__ __bf16 As[(DBUF ? 2 : 1) * BM * 64];
  __shared__ __bf16 Bs[(DBUF ? 2 : 1) * BN * 64];
  char* AsB = (char*)As;
  char* BsB = (char*)Bs;
  int tid = threadIdx.x;
  int w = tid >> 6, lane = tid & 63;
  int mt = M / BM, nt = N / BN;
  int cpx = gridDim.x >> 3;
  int id = (blockIdx.x & 7) * cpx + (blockIdx.x >> 3);
  int ks_id = id / (mt * nt);
  int rem = id % (mt * nt);
  int bm = (rem % mt) * BM, bn = (rem / mt) * BN;
  int kbeg = ks_id * (K / KSPLIT), kend = kbeg + K / KSPLIT;
  int lrow = lane & 15, g = lane >> 4;
  int grow = lane >> 3;
  int gswz = ((lane & 7) ^ grow) * 8;
  int rsw = (lrow & 7) << 4;
  int wm = (NW == 4) ? (w >> 1) : (w >> 2);
  int wn = (NW == 4) ? (w & 1) : (w & 3);
  int wr = wm * (BM / 2), wc = wn * (BN / WCOLS);
  f32x4 acc[FM][FN] = {};
  const __bf16* B16 = (const __bf16*)Bv;
  const float* B32 = (const float*)Bv;

  auto stage = [&](int buf, int k0) {
#pragma unroll
    for (int i = 0; i < AISS; ++i) {
      int rbase = (i * NW + w) * 8;
      GLOAD16(&A[(size_t)(bm + rbase + grow) * K + k0 + gswz],
              &As[buf * BM * 64 + rbase * 64]);
    }
#pragma unroll
    for (int i = 0; i < BISS; ++i) {
      int rbase = (i * NW + w) * 8;
      GLOAD16(&B16[(size_t)(bn + rbase + grow) * K + k0 + gswz],
              &Bs[buf * BN * 64 + rbase * 64]);
    }
  };

  auto compute = [&](int buf) {
    int offA = buf * BM * 128, offB = buf * BN * 128;
#pragma unroll
    for (int ks = 0; ks < 2; ++ks) {
      bf16x8 af[FM], bg[FN];
#pragma unroll
      for (int i = 0; i < FM; ++i)
        af[i] = *reinterpret_cast<const bf16x8*>(
            AsB + offA + (wr + i * 16 + lrow) * 128 + ((ks * 64 + g * 16) ^ rsw));
#pragma unroll
      for (int j = 0; j < FN; ++j)
        bg[j] = *reinterpret_cast<const bf16x8*>(
            BsB + offB + (wc + j * 16 + lrow) * 128 + ((ks * 64 + g * 16) ^ rsw));
#pragma unroll
      for (int i = 0; i < FM; ++i)
#pragma unroll
        for (int j = 0; j < FN; ++j)
          acc[i][j] = __builtin_amdgcn_mfma_f32_16x16x32_bf16(af[i], bg[j],
                                                              acc[i][j], 0, 0, 0);
    }
  };

  if constexpr (DBUF && !BF32) {
    stage(0, kbeg);
    int cur = 0;
    for (int k0 = kbeg; k0 < kend; k0 += 64) {
      bool more = (k0 + 64 < kend);
      if (more) stage(cur ^ 1, k0 + 64);
      if (more) {
        if constexpr (NI == 2) asm volatile("s_waitcnt vmcnt(2)" ::: "memory");
        else if constexpr (NI == 3) asm volatile("s_waitcnt vmcnt(3)" ::: "memory");
        else if constexpr (NI == 4) asm volatile("s_waitcnt vmcnt(4)" ::: "memory");
        else if constexpr (NI == 6) asm volatile("s_waitcnt vmcnt(6)" ::: "memory");
        else asm volatile("s_waitcnt vmcnt(0)" ::: "memory");
      } else {
        asm volatile("s_waitcnt vmcnt(0)" ::: "memory");
      }
      __builtin_amdgcn_sched_barrier(0);
      __builtin_amdgcn_s_barrier();
      compute(cur);
      __builtin_amdgcn_s_barrier();
      cur ^= 1;
    }
  } else {
    for (int k0 = kbeg; k0 < kend; k0 += 64) {
      if (!BF32) {
        stage(0, k0);
      } else {
#pragma unroll
        for (int rrep = 0; rrep < BN * 8 / (NW * 64); ++rrep) {
          int cid = rrep * NW * 64 + tid;
          int row = cid >> 3, kc = (cid & 7) * 8;
          const float* src = &B32[(size_t)(bn + row) * K + k0 + kc];
          float4 f0 = *reinterpret_cast<const float4*>(src);
          float4 f1 = *reinterpret_cast<const float4*>(src + 4);
          bf16x8 v;
          v[0] = (__bf16)f0.x; v[1] = (__bf16)f0.y;
          v[2] = (__bf16)f0.z; v[3] = (__bf16)f0.w;
          v[4] = (__bf16)f1.x; v[5] = (__bf16)f1.y;
          v[6] = (__bf16)f1.z; v[7] = (__bf16)f1.w;
          int swc = ((cid & 7) ^ (row & 7)) * 16;
          *reinterpret_cast<bf16x8*>(BsB + row * 128 + swc) = v;
        }
#pragma unroll
        for (int i = 0; i < AISS; ++i) {
          int rbase = (i * NW + w) * 8;
          GLOAD16(&A[(size_t)(bm + rbase + grow) * K + k0 + gswz], &As[rbase * 64]);
        }
      }
      __syncthreads();
      compute(0);
      __syncthreads();
    }
  }

  float* Cp = (float*)Cv + (size_t)ks_id * M * N;
  int crow0 = bm + wr + g * 4;
  int ccol0 = bn + wc + lrow;
#pragma unroll
  for (int i = 0; i < FM; ++i) {
#pragma unroll
    for (int j = 0; j < FN; ++j) {
#pragma unroll
      for (int r = 0; r < 4; ++r) {
        int row = crow0 + i * 16 + r;
        int col = ccol0 + j * 16;
        size_t idx = (size_t)row * N + col;
        float v = acc[i][j][r];
        if (EPI == 1) v += res[idx];
        if (EPI == 2) {
          float u = v;
          float z = 0.7978845608028654f * (u + 0.044715f * u * u * u);
          float ez = exp2f(z * (2.f * L2E));
          v = u * ez / (1.f + ez);
        }
        if (EPI == 2 || EPI == 3) ((__bf16*)Cv)[idx] = (__bf16)v;
        else Cp[idx] = v;
      }
    }
  }
}

// ---------------------------------------------------------------------------
// Flash attention (causal), flash-decode 2-way KV split. Each block =
// (qt, h, half); emits raw partial (acc, m, lsum) for its KV range.
// Block-id swizzle co-locates each head's 32 blocks on one XCD (KV L2 reuse).
// ---------------------------------------------------------------------------
__global__ __launch_bounds__(256) void fattn_kernel(const __bf16* __restrict__ qkv,
                                                    float* __restrict__ pacc,
                                                    float* __restrict__ pm,
                                                    float* __restrict__ pl) {
  __shared__ __bf16 Ks[2][64 * 64];
  __shared__ __bf16 Vt[2][64 * 64];
  __shared__ __bf16 Ps[4 * 16 * 64];
  int b = blockIdx.x;
  int xcd = b & 7, idx = b >> 3;
  int h = xcd * 2 + (idx >> 5);
  int rem2 = idx & 31;
  int qt = rem2 >> 1, half = rem2 & 1;
  int bq = qt * 64;
  int ntk = qt + 1;
  int kb = half ? (ntk >> 1) : 0;
  int ke = half ? ntk : (ntk >> 1);
  int tix = (qt * 16 + h) * 2 + half;
  int tid = threadIdx.x;
  int w = tid >> 6, lane = tid & 63;
  int g = lane >> 4, lr = lane & 15;

  if (kb >= ke) {  // empty range: neutral partial (block-uniform return)
    float* pa = pacc + (size_t)tix * 4096;
#pragma unroll
    for (int i = 0; i < 16; ++i) pa[tid * 16 + i] = 0.f;
    if (tid < 64) {
      pm[tix * 64 + tid] = -1e30f;
      pl[tix * 64 + tid] = 0.f;
    }
    return;
  }

  bf16x8 qf[2];
  const __bf16* qbase = qkv + (size_t)(bq + w * 16 + lr) * (3 * kD) + h * 64;
#pragma unroll
  for (int ks = 0; ks < 2; ++ks) {
    bf16x8 v = *reinterpret_cast<const bf16x8*>(qbase + ks * 32 + g * 8);
#pragma unroll
    for (int j = 0; j < 8; ++j) qf[ks][j] = (__bf16)((float)v[j] * 0.125f);
  }

  f32x4 acc[4] = {};
  float m = -1e30f, lsum = 0.f;

  int srow = tid >> 2, sseg = tid & 3;
  int vk = tid & 63, vd0 = (tid >> 6) * 16;
  char* PwB = (char*)(Ps + w * (16 * 64));
  int psw = (lr & 7) << 4;

  bf16x8 ka, kb2, va, vb;

  {
    const __bf16* src = qkv + (size_t)(kb * 64 + srow) * (3 * kD) + kD + h * 64 + sseg * 16;
    ka = *reinterpret_cast<const bf16x8*>(src);
    kb2 = *reinterpret_cast<const bf16x8*>(src + 8);
    const __bf16* vsrc = qkv + (size_t)(kb * 64 + vk) * (3 * kD) + 2 * kD + h * 64 + vd0;
    va = *reinterpret_cast<const bf16x8*>(vsrc);
    vb = *reinterpret_cast<const bf16x8*>(vsrc + 8);
    char* KsB = (char*)Ks[0];
    char* VtB = (char*)Vt[0];
    int bc = sseg * 32, sw = (srow & 7) << 4;
    *reinterpret_cast<bf16x8*>(KsB + srow * 128 + (bc ^ sw)) = ka;
    *reinterpret_cast<bf16x8*>(KsB + srow * 128 + ((bc + 16) ^ sw)) = kb2;
#pragma unroll
    for (int i = 0; i < 8; ++i) {
      int d = vd0 + i;
      *((__bf16*)(VtB + d * 128 + ((vk * 2) ^ ((d & 7) << 4)))) = va[i];
      d = vd0 + 8 + i;
      *((__bf16*)(VtB + d * 128 + ((vk * 2) ^ ((d & 7) << 4)))) = vb[i];
    }
  }

  int cur = 0;
  for (int kt = kb; kt < ke; ++kt) {
    if (kt + 1 < ke) {
      const __bf16* src =
          qkv + (size_t)((kt + 1) * 64 + srow) * (3 * kD) + kD + h * 64 + sseg * 16;
      ka = *reinterpret_cast<const bf16x8*>(src);
      kb2 = *reinterpret_cast<const bf16x8*>(src + 8);
      const __bf16* vsrc =
          qkv + (size_t)((kt + 1) * 64 + vk) * (3 * kD) + 2 * kD + h * 64 + vd0;
      va = *reinterpret_cast<const bf16x8*>(vsrc);
      vb = *reinterpret_cast<const bf16x8*>(vsrc + 8);
    }
    __syncthreads();

    char* KsB = (char*)Ks[cur];
    char* VtB = (char*)Vt[cur];
    bool diag = (kt == qt);
    int jmax = diag ? w : 3;

    f32x4 s[4];
#pragma unroll
    for (int jj = 0; jj < 4; ++jj) {
      if (jj <= jmax) {
        int krow = jj * 16 + lr;
        int ksw = (lr & 7) << 4;
        bf16x8 k0 = *reinterpret_cast<const bf16x8*>(KsB + krow * 128 + ((g * 16) ^ ksw));
        bf16x8 k1 = *reinterpret_cast<const bf16x8*>(KsB + krow * 128 + ((64 + g * 16) ^ ksw));
        f32x4 z = {};
        z = __builtin_amdgcn_mfma_f32_16x16x32_bf16(k0, qf[0], z, 0, 0, 0);
        s[jj] = __builtin_amdgcn_mfma_f32_16x16x32_bf16(k1, qf[1], z, 0, 0, 0);
      } else {
        s[jj] = f32x4{-1e30f, -1e30f, -1e30f, -1e30f};
      }
    }
    if (diag) {
#pragma unroll
      for (int r = 0; r < 4; ++r)
        if (g * 4 + r > lr) s[w][r] = -1e30f;
    }

    float mt = -1e30f;
#pragma unroll
    for (int jj = 0; jj < 4; ++jj)
#pragma unroll
      for (int r = 0; r < 4; ++r) mt = fmaxf(mt, s[jj][r]);
    mt = fmaxf(mt, __shfl_xor(mt, 16));
    mt = fmaxf(mt, __shfl_xor(mt, 32));
    float mn = fmaxf(m, mt);
    float sc = exp2f((m - mn) * L2E);
    float p[4][4];
    float rs = 0.f;
#pragma unroll
    for (int jj = 0; jj < 4; ++jj)
#pragma unroll
      for (int r = 0; r < 4; ++r) {
        float e = exp2f((s[jj][r] - mn) * L2E);
        p[jj][r] = e;
        rs += e;
      }
    rs += __shfl_xor(rs, 16);
    rs += __shfl_xor(rs, 32);
    lsum = lsum * sc + rs;
    m = mn;
#pragma unroll
    for (int r = 0; r < 4; ++r) {
      float s4 = __shfl(sc, 20 * g + r);
#pragma unroll
      for (int dt = 0; dt < 4; ++dt) acc[dt][r] *= s4;
    }

#pragma unroll
    for (int jj = 0; jj < 4; ++jj) {
      bf16x4 pv;
#pragma unroll
      for (int r = 0; r < 4; ++r) pv[r] = (__bf16)p[jj][r];
      *reinterpret_cast<bf16x4*>(PwB + lr * 128 + ((jj * 32 + g * 8) ^ psw)) = pv;
    }

    {
      bf16x8 pa0 = *reinterpret_cast<const bf16x8*>(PwB + lr * 128 + ((g * 16) ^ psw));
      bf16x8 pa1 = *reinterpret_cast<const bf16x8*>(PwB + lr * 128 + ((64 + g * 16) ^ psw));
#pragma unroll
      for (int dt = 0; dt < 4; ++dt) {
        int vrow = dt * 16 + lr;
        int vsw = (lr & 7) << 4;
        bf16x8 vb0 = *reinterpret_cast<const bf16x8*>(VtB + vrow * 128 + ((g * 16) ^ vsw));
        bf16x8 vb1 = *reinterpret_cast<const bf16x8*>(VtB + vrow * 128 + ((64 + g * 16) ^ vsw));
        acc[dt] = __builtin_amdgcn_mfma_f32_16x16x32_bf16(pa0, vb0, acc[dt], 0, 0, 0);
        acc[dt] = __builtin_amdgcn_mfma_f32_16x16x32_bf16(pa1, vb1, acc[dt], 0, 0, 0);
      }
    }
    __syncthreads();

    if (kt + 1 < ke) {
      char* KsN = (char*)Ks[cur ^ 1];
      char* VtN = (char*)Vt[cur ^ 1];
      int bc = sseg * 32, sw = (srow & 7) << 4;
      *reinterpret_cast<bf16x8*>(KsN + srow * 128 + (bc ^ sw)) = ka;
      *reinterpret_cast<bf16x8*>(KsN + srow * 128 + ((bc + 16) ^ sw)) = kb2;
#pragma unroll
      for (int i = 0; i < 8; ++i) {
        int d = vd0 + i;
        *((__bf16*)(VtN + d * 128 + ((vk * 2) ^ ((d & 7) << 4)))) = va[i];
        d = vd0 + 8 + i;
        *((__bf16*)(VtN + d * 128 + ((vk * 2) ^ ((d & 7) << 4)))) = vb[i];
      }
      cur ^= 1;
    }
  }

  // raw partial out
  float* pa = pacc + (size_t)tix * 4096;
#pragma unroll
  for (int r = 0; r < 4; ++r) {
    int row = w * 16 + g * 4 + r;
#pragma unroll
    for (int dt = 0; dt < 4; ++dt)
      pa[row * 64 + dt * 16 + lr] = acc[dt][r];
  }
  if (g == 0) {
    pm[tix * 64 + w * 16 + lr] = m;
    pl[tix * 64 + w * 16 + lr] = lsum;
  }
}

// ---------------------------------------------------------------------------
// Combine the two KV-half partials -> ab (bf16).
// ---------------------------------------------------------------------------
__global__ __launch_bounds__(256) void fattn_combine_kernel(
    const float* __restrict__ pacc, const float* __restrict__ pm,
    const float* __restrict__ pl, __bf16* __restrict__ ab) {
  int qt = blockIdx.x, h = blockIdx.y;
  int tid = threadIdx.x;
  int row = tid >> 2, c0 = (tid & 3) * 16;
  int t0 = (qt * 16 + h) * 2, t1 = t0 + 1;
  float m0 = pm[t0 * 64 + row], m1 = pm[t1 * 64 + row];
  float l0 = pl[t0 * 64 + row], l1 = pl[t1 * 64 + row];
  float mm = fmaxf(m0, m1);
  float e0 = exp2f((m0 - mm) * L2E), e1 = exp2f((m1 - mm) * L2E);
  float inv = 1.f / (e0 * l0 + e1 * l1);
  const float* a0 = pacc + (size_t)t0 * 4096 + row * 64 + c0;
  const float* a1 = pacc + (size_t)t1 * 4096 + row * 64 + c0;
  __bf16* o = ab + (size_t)(qt * 64 + row) * kD + h * 64 + c0;
#pragma unroll
  for (int c = 0; c < 16; c += 4) {
    float4 v0 = *reinterpret_cast<const float4*>(a0 + c);
    float4 v1 = *reinterpret_cast<const float4*>(a1 + c);
    bf16x4 ov;
    ov[0] = (__bf16)((e0 * v0.x + e1 * v1.x) * inv);
    ov[1] = (__bf16)((e0 * v0.y + e1 * v1.y) * inv);
    ov[2] = (__bf16)((e0 * v0.z + e1 * v1.z) * inv);
    ov[3] = (__bf16)((e0 * v0.w + e1 * v1.w) * inv);
    *reinterpret_cast<bf16x4*>(o + c) = ov;
  }
}

// ---------------------------------------------------------------------------
// Fused w2 split-K reduce + residual blend + group rotation, (tc, gr) blocks.
// ---------------------------------------------------------------------------
__global__ __launch_bounds__(256) void blend_rot_kernel(const float* x,
                                                        const float* y,
                                                        const float* q0,
                                                        const float* q1,
                                                        const float* iscale,
                                                        int l,
                                                        const float* __restrict__ Rall,
                                                        float* xout) {
  int tc = blockIdx.x, gr = blockIdx.y;
  int tid = threadIdx.x;
  __shared__ float Rs[64 * 64];
  __shared__ float xb[64][65];
  float s = iscale[l];
  const float* Rg = Rall + ((size_t)l * kG + gr) * 4096;
  {
    int off = tid * 16;
#pragma unroll
    for (int q2 = 0; q2 < 4; ++q2) {
      float4 rv = *reinterpret_cast<const float4*>(Rg + off + q2 * 4);
      *reinterpret_cast<float4*>(&Rs[off + q2 * 4]) = rv;
    }
  }
  int tok = tid & 63, seg = (tid >> 6) * 16;
  {
    size_t base = (size_t)(tc * 64 + tok) * kD + gr * 64 + seg;
#pragma unroll
    for (int q2 = 0; q2 < 4; ++q2) {
      float4 xv = *reinterpret_cast<const float4*>(x + base + q2 * 4);
      float4 yv = *reinterpret_cast<const float4*>(y + base + q2 * 4);
      float4 a = *reinterpret_cast<const float4*>(q0 + base + q2 * 4);
      float4 b = *reinterpret_cast<const float4*>(q1 + base + q2 * 4);
      float y0 = yv.x + a.x + b.x;
      float y1 = yv.y + a.y + b.y;
      float y2 = yv.z + a.z + b.z;
      float y3 = yv.w + a.w + b.w;
      xb[tok][seg + q2 * 4 + 0] = xv.x + (y0 - xv.x) * s;
      xb[tok][seg + q2 * 4 + 1] = xv.y + (y1 - xv.y) * s;
      xb[tok][seg + q2 * 4 + 2] = xv.z + (y2 - xv.z) * s;
      xb[tok][seg + q2 * 4 + 3] = xv.w + (y3 - xv.w) * s;
    }
  }
  __syncthreads();
  float o[16] = {};
  for (int i = 0; i < 64; ++i) {
    float xv = xb[tok][i];
#pragma unroll
    for (int d = 0; d < 16; ++d) o[d] += xv * Rs[i * 64 + seg + d];
  }
  float* outr = xout + (size_t)(tc * 64 + tok) * kD + gr * 64 + seg;
#pragma unroll
  for (int q2 = 0; q2 < 4; ++q2) {
    float4 ov = {o[q2 * 4 + 0], o[q2 * 4 + 1], o[q2 * 4 + 2], o[q2 * 4 + 3]};
    *reinterpret_cast<float4*>(outr + q2 * 4) = ov;
  }
}

// ---------------------------------------------------------------------------
extern "C" void kernel_launch(void* const* d_in, const int* in_sizes, int n_in,
                              void* d_out, int out_size, void* d_ws, size_t ws_size,
                              hipStream_t stream) {
  const int* tokens = (const int*)d_in[0];
  const float* embed_w = (const float*)d_in[1];
  const float* lm_head_w = (const float*)d_in[2];
  const float* norm_w = (const float*)d_in[3];
  const float* layer_gamma = (const float*)d_in[4];
  const float* layer_beta = (const float*)d_in[5];
  const float* iter_scale = (const float*)d_in[6];
  const float* skew_upper = (const float*)d_in[7];
  const float* ln1_w = (const float*)d_in[8];
  const float* ln2_w = (const float*)d_in[9];
  const float* wqkv = (const float*)d_in[10];
  const float* wo = (const float*)d_in[11];
  const float* w1 = (const float*)d_in[12];
  const float* w2 = (const float*)d_in[13];
  float* out = (float*)d_out;

  // ws: x(4MB) y(4MB) hb(2MB) ab(2MB) R(6.3MB) [+ lmhb 65.5MB if room]
  float* x = (float*)d_ws;
  float* y = x + (size_t)kT * kD;
  __bf16* hb = (__bf16*)(y + (size_t)kT * kD);
  __bf16* ab = hb + (size_t)kT * kD;
  float* R = (float*)(ab + (size_t)kT * kD);
  __bf16* lmhb = (__bf16*)(R + (size_t)kL * kG * 4096);
  bool ws_big = ws_size >= (size_t)(4670464 + 16384000) * 4;

  // d_out scratch (all dead before final lm_head GEMM writes out):
  __bf16* qkvb = (__bf16*)out;                       // 3.1M bf16
  __bf16* ffb = (__bf16*)(out + 1572864);            // 4.2M bf16
  __bf16* wqkvT = (__bf16*)(out + 3670016);          // [3072][1024]
  __bf16* woT = (__bf16*)(out + 5242880);            // [1024][1024]
  __bf16* w1T = (__bf16*)(out + 5767168);            // [4096][1024]
  __bf16* w2T = (__bf16*)(out + 7864320);            // [1024][4096]
  float* wop = out + 9961472;                        // wo partials 2x 1M f32
  float* w2p = out + 12058624;                       // w2 partials 2x 1M f32
  float* pacc = out + 14155776;                      // attn partials 2M f32
  float* pm = out + 16252928;                        // 32K f32
  float* pl = out + 16285696;                        // 32K f32

  cayley_kernel<<<kL * kG, 256, 0, stream>>>(skew_upper, R);
  embed_kernel<<<kT * kD / 4 / 256, 256, 0, stream>>>(tokens, embed_w, x);
  convt_kernel<<<dim3(3 * kD / 64, kD / 64), 256, 0, stream>>>(wqkv, wqkvT, kD, 3 * kD);
  convt_kernel<<<dim3(kD / 64, kD / 64), 256, 0, stream>>>(wo, woT, kD, kD);
  convt_kernel<<<dim3(kFF / 64, kD / 64), 256, 0, stream>>>(w1, w1T, kD, kFF);
  convt_kernel<<<dim3(kD / 64, kFF / 64), 256, 0, stream>>>(w2, w2T, kFF, kD);
  if (ws_big)
    cast_kernel<<<kV * kD / 8 / 256, 256, 0, stream>>>(lm_head_w, lmhb);

  for (int l = 0; l < kL; ++l) {
    rms_kernel<true><<<kT, 256, 0, stream>>>(x, ln1_w, layer_gamma + (size_t)l * kD,
                                             layer_beta + (size_t)l * kD, hb);
    gemm_kernel<64, 128, 8, 3, false, 1, true>
        <<<(kT / 64) * (3 * kD / 128), 512, 0, stream>>>(
        hb, wqkvT, nullptr, qkvb, kT, 3 * kD, kD);
    fattn_kernel<<<512, 256, 0, stream>>>(qkvb, pacc, pm, pl);
    fattn_combine_kernel<<<dim3(kT / 64, kH), 256, 0, stream>>>(pacc, pm, pl, ab);
    gemm_kernel<64, 64, 8, 0, false, 2, true>
        <<<2 * (kT / 64) * (kD / 64), 512, 0, stream>>>(
        ab, woT, nullptr, wop, kT, kD, kD);
    rms_red_kernel<<<kT, 256, 0, stream>>>(x, wop, wop + (size_t)kT * kD, ln2_w, y, hb);
    gemm_kernel<64, 128, 8, 2, false, 1, true>
        <<<(kT / 64) * (kFF / 128), 512, 0, stream>>>(
        hb, w1T, nullptr, ffb, kT, kFF, kD);
    gemm_kernel<64, 64, 8, 0, false, 2, true>
        <<<2 * (kT / 64) * (kD / 64), 512, 0, stream>>>(
        ffb, w2T, nullptr, w2p, kT, kD, kFF);
    blend_rot_kernel<<<dim3(kT / 64, kG), 256, 0, stream>>>(
        x, y, w2p, w2p + (size_t)kT * kD, iter_scale, l, R, x);
  }

  rms_kernel<false><<<kT, 256, 0, stream>>>(x, norm_w, nullptr, nullptr, hb);
  if (ws_big)
    gemm_kernel<256, 128, 8, 0, false><<<(kT / 256) * (kV / 128), 512, 0, stream>>>(
        hb, lmhb, nullptr, out, kT, kV, kD);
  else
    gemm_kernel<128, 128, 4, 0, true><<<(kT / 128) * (kV / 128), 256, 0, stream>>>(
        hb, lm_head_w, nullptr, out, kT, kV, kD);
}